// Round 2
// baseline (898.075 us; speedup 1.0000x reference)
//
#include <hip/hip_runtime.h>

typedef unsigned short u16;
typedef __attribute__((ext_vector_type(8))) short bh8;
typedef __attribute__((ext_vector_type(4))) float f4;

__device__ __forceinline__ u16 f2b(float f){
  unsigned int u = __float_as_uint(f);
  u += 0x7fffu + ((u >> 16) & 1u);
  return (u16)(u >> 16);
}
__device__ __forceinline__ float b2f(u16 h){
  return __uint_as_float(((unsigned int)h) << 16);
}
__device__ __forceinline__ void gl16(const u16* g, u16* l){
  __builtin_amdgcn_global_load_lds((const __attribute__((address_space(1))) void*)g,
                                   (__attribute__((address_space(3))) void*)l, 16, 0, 0);
}

// ---------------- packing ----------------
__global__ void pack_plain(const float* __restrict__ src, u16* __restrict__ dst, int count){
  int i = blockIdx.x*256 + threadIdx.x;
  if (i < count) dst[i] = f2b(src[i]);
}
// c_kv_w (600,300) -> padded [640][320]: n = t*320+h*80+dd, k = kh*80+kd
__global__ void pack_ckv_k(const float* __restrict__ src, u16* __restrict__ dst){
  int i = blockIdx.x*256 + threadIdx.x; // 640*320
  int nn = i / 320, kk = i - (i/320)*320;
  int t_ = (nn >= 320) ? 1 : 0;
  int rem = nn - t_*320;
  int hh = rem / 80, dd = rem - hh*80;
  int kh = kk / 80, kd = kk - kh*80;
  float v = 0.f;
  if (dd < 75 && kd < 75)
    v = src[(size_t)(t_*300 + hh*75 + dd)*300 + (kh*75 + kd)];
  dst[i] = f2b(v);
}
// zero the never-written pad stripes of cT1/cT2 (cols h*80+75..79) and the
// 4KiB slack after cT2 that ch_out's tail k-chunk over-reads (x0, but must be finite)
__global__ void pad_zero(u16* __restrict__ cT1, u16* __restrict__ cT2, u16* __restrict__ slack){
  const int idx = blockIdx.x*256 + threadIdx.x;
  if (idx < 262144){
    const int t = idx >> 17;
    const int rem = idx & 131071;
    const int rc = rem >> 2, h = rem & 3;
    u16* p = (t ? cT2 : cT1) + (size_t)rc*320 + h*80 + 75;
    p[0]=0; p[1]=0; p[2]=0; p[3]=0; p[4]=0;
  } else {
    const int j = idx - 262144;
    if (j < 2048) slack[j] = 0;
  }
}

// ---------------- x (B,C,H,W) f32 -> t (B,N,C) bf16 ----------------
__global__ __launch_bounds__(256)
void transpose_k(const float* __restrict__ x, u16* __restrict__ t)
{
  __shared__ float tile[32][33];
  const int n0 = blockIdx.x * 32, c0 = blockIdx.y * 32, b = blockIdx.z;
  const int ln = threadIdx.x & 31, lr = threadIdx.x >> 5;
  #pragma unroll
  for (int q = 0; q < 4; q++) {
    const int c = c0 + lr + q*8, n = n0 + ln;
    tile[lr + q*8][ln] = (n < 300) ? x[((long)b*512 + c)*300 + n] : 0.f;
  }
  __syncthreads();
  #pragma unroll
  for (int q = 0; q < 4; q++) {
    const int n = n0 + lr + q*8;
    if (n < 300) t[((long)b*300 + n)*512 + c0 + ln] = f2b(tile[ln][lr + q*8]);
  }
}

// ---------------- generic 128x128 MFMA GEMM: C = A(M,K) @ Bw(N,K)^T ----------------
template<int OUTF, int HASB>
__global__ __launch_bounds__(256)
void gemm_k(const u16* __restrict__ A, int lda,
            const u16* __restrict__ Bw, int ldb,
            u16* __restrict__ Cb, float* __restrict__ Cf, int ldc,
            const float* __restrict__ bias, int K)
{
  __shared__ u16 As[128*32];
  __shared__ u16 Bs[128*32];
  const int tid = threadIdx.x;
  const long m0 = (long)blockIdx.x * 128;
  const long n0 = (long)blockIdx.y * 128;
  const int wave = tid >> 6, lane = tid & 63;
  const int l15 = lane & 15, lg = lane >> 4;
  const int wr = (wave >> 1) * 64, wc = (wave & 1) * 64;
  const int arow = tid >> 2, aseg = (tid & 3) * 8;
  const u16* Ag0 = A + (m0 + arow) * (long)lda + aseg;
  const u16* Ag1 = Ag0 + 64L * lda;
  const u16* Bg0 = Bw + (n0 + arow) * (long)ldb + aseg;
  const u16* Bg1 = Bg0 + 64L * ldb;
  u16* lA0 = &As[tid * 8];
  u16* lA1 = &As[2048 + tid * 8];
  u16* lB0 = &Bs[tid * 8];
  u16* lB1 = &Bs[2048 + tid * 8];
  f4 acc[4][4] = {};
  for (int kt = 0; kt < K; kt += 32) {
    gl16(Ag0 + kt, lA0);
    gl16(Ag1 + kt, lA1);
    gl16(Bg0 + kt, lB0);
    gl16(Bg1 + kt, lB1);
    __syncthreads();
    bh8 af[4], bf[4];
    #pragma unroll
    for (int mi = 0; mi < 4; mi++)
      af[mi] = *(const bh8*)&As[(wr + mi*16 + l15)*32 + lg*8];
    #pragma unroll
    for (int ni = 0; ni < 4; ni++)
      bf[ni] = *(const bh8*)&Bs[(wc + ni*16 + l15)*32 + lg*8];
    #pragma unroll
    for (int mi = 0; mi < 4; mi++)
      #pragma unroll
      for (int ni = 0; ni < 4; ni++)
        acc[mi][ni] = __builtin_amdgcn_mfma_f32_16x16x32_bf16(af[mi], bf[ni], acc[mi][ni], 0, 0, 0);
    __syncthreads();
  }
  #pragma unroll
  for (int ni = 0; ni < 4; ni++) {
    const long cn = n0 + wc + ni*16 + l15;
    const float bv = HASB ? bias[cn] : 0.0f;
    #pragma unroll
    for (int mi = 0; mi < 4; mi++) {
      #pragma unroll
      for (int r = 0; r < 4; r++) {
        const long cm = m0 + wr + mi*16 + lg*4 + r;
        const float v = acc[mi][ni][r] + bv;
        if (OUTF) Cf[cm * ldc + cn] = v;
        else      Cb[cm * ldc + cn] = f2b(v);
      }
    }
  }
}

// ---------------- LayerNorm(1024) + relu; split into s (B,N,512) and cT (B,512,320pad) ----------------
__global__ __launch_bounds__(256)
void ln_kernel(const u16* __restrict__ apre, const float* __restrict__ lw, const float* __restrict__ lb,
               u16* __restrict__ s, u16* __restrict__ cT)
{
  __shared__ float rS[4], rQ[4];
  const int r = blockIdx.x;           // b*300 + n
  const int b = r / 300, n = r - b*300;
  const int tid = threadIdx.x, lane = tid & 63, w = tid >> 6;
  const u16* row = apre + (size_t)r*1024 + tid*4;
  float v[4];
  {
    const uint2 u = *(const uint2*)row;
    v[0] = b2f((u16)(u.x & 0xffff)); v[1] = b2f((u16)(u.x >> 16));
    v[2] = b2f((u16)(u.y & 0xffff)); v[3] = b2f((u16)(u.y >> 16));
  }
  float sm = v[0]+v[1]+v[2]+v[3];
  float sq = v[0]*v[0]+v[1]*v[1]+v[2]*v[2]+v[3]*v[3];
  #pragma unroll
  for (int o = 32; o; o >>= 1){ sm += __shfl_xor(sm, o); sq += __shfl_xor(sq, o); }
  if (lane == 0){ rS[w] = sm; rQ[w] = sq; }
  __syncthreads();
  sm = rS[0]+rS[1]+rS[2]+rS[3]; sq = rQ[0]+rQ[1]+rQ[2]+rQ[3];
  const float mean = sm * (1.f/1024.f);
  const float rstd = rsqrtf(sq*(1.f/1024.f) - mean*mean + 1e-5f);
  const int col0 = tid*4;
  const int nn = (n/75)*80 + (n - (n/75)*75);
  #pragma unroll
  for (int j = 0; j < 4; j++){
    const int c = col0 + j;
    float y = (v[j]-mean)*rstd*lw[c] + lb[c];
    y = fmaxf(y, 0.f);
    const u16 hb = f2b(y);
    if (c < 512) cT[((size_t)b*512 + c)*320 + nn] = hb;
    else         s[(size_t)r*512 + (c-512)] = hb;
  }
}

// ---------------- attn ctx: out[e][d] = softmax_d( scale * sum_n k[n,d] v[n,e] ), stored transposed ----------------
template<int D, int DREAL, int OS>
__global__ __launch_bounds__(256)
void ctx_kernel(const u16* __restrict__ kva, const u16* __restrict__ kvb,
                u16* __restrict__ outp, int K, int RS, int VOFF, float scale)
{
  constexpr int NT = D/16, MT = D/16, MTL = (MT+3)/4, SEG = D/8;
  __shared__ u16 vT[D][40];
  __shared__ u16 kT[D][40];
  const int h = blockIdx.x, b = blockIdx.y, iq = blockIdx.z;
  const int Hn = gridDim.x;
  const u16* base = (iq ? kvb : kva) + (size_t)b*K*RS + h*D;
  u16* out = outp + (((size_t)iq*64 + b)*Hn + h)*(size_t)(D*OS);
  const int tid = threadIdx.x, w = tid >> 6, lane = tid & 63, l15 = lane & 15, lg = lane >> 4;
  f4 acc[MTL][NT] = {};
  for (int k0 = 0; k0 < K; k0 += 32) {
    __syncthreads();
    for (int sI = tid; sI < 32*SEG; sI += 256) {
      const int nn = sI / SEG, dseg = sI - (sI/SEG)*SEG;
      bh8 kk = {}, vv = {};
      const int krow = k0 + nn;
      if (krow < K) {
        const u16* p = base + (size_t)krow*RS + dseg*8;
        kk = *(const bh8*)p;
        vv = *(const bh8*)(p + VOFF);
      }
      #pragma unroll
      for (int j = 0; j < 8; j++){
        kT[dseg*8+j][nn] = (u16)kk[j];
        vT[dseg*8+j][nn] = (u16)vv[j];
      }
    }
    __syncthreads();
    #pragma unroll
    for (int ii = 0; ii < MTL; ii++){
      const int mt = w + ii*4;
      if (MT % 4 != 0 && mt >= MT) break;
      const bh8 a = *(const bh8*)&vT[mt*16 + l15][lg*8];
      #pragma unroll
      for (int nt = 0; nt < NT; nt++){
        const bh8 bb = *(const bh8*)&kT[nt*16 + l15][lg*8];
        acc[ii][nt] = __builtin_amdgcn_mfma_f32_16x16x32_bf16(a, bb, acc[ii][nt], 0, 0, 0);
      }
    }
  }
  #pragma unroll
  for (int ii = 0; ii < MTL; ii++){
    const int mt = w + ii*4;
    if (MT % 4 != 0 && mt >= MT) continue;
    #pragma unroll
    for (int r = 0; r < 4; r++){
      const int e = mt*16 + lg*4 + r;
      float xs[NT]; float mx = -1e30f;
      #pragma unroll
      for (int nt = 0; nt < NT; nt++){
        float x = acc[ii][nt][r] * scale;
        if (DREAL != D && (nt*16 + l15) >= DREAL) x = -1e30f;
        xs[nt] = x; mx = fmaxf(mx, x);
      }
      mx = fmaxf(mx, __shfl_xor(mx,1)); mx = fmaxf(mx, __shfl_xor(mx,2));
      mx = fmaxf(mx, __shfl_xor(mx,4)); mx = fmaxf(mx, __shfl_xor(mx,8));
      float smv = 0.f;
      #pragma unroll
      for (int nt = 0; nt < NT; nt++){
        const float p = (xs[nt] > -1e29f) ? __expf(xs[nt]-mx) : 0.f;
        xs[nt] = p; smv += p;
      }
      smv += __shfl_xor(smv,1); smv += __shfl_xor(smv,2);
      smv += __shfl_xor(smv,4); smv += __shfl_xor(smv,8);
      const float inv = 1.f / smv;
      #pragma unroll
      for (int nt = 0; nt < NT; nt++)
        out[(size_t)e*OS + nt*16 + l15] = f2b(xs[nt]*inv);
      if (OS > D) out[(size_t)e*OS + D + l15] = 0;
    }
  }
}

// ---------------- spatial out: merge[:, :512] = q1@c2 + q2@c1 ----------------
__global__ __launch_bounds__(256)
void sp_out_kernel(const u16* __restrict__ s1, const u16* __restrict__ s2,
                   const u16* __restrict__ csT, u16* __restrict__ merge)
{
  const int h = blockIdx.x, b = blockIdx.y;
  const int tid = threadIdx.x, w = tid >> 6, lane = tid & 63, l15 = lane & 15, lg = lane >> 4;
  const u16* c1 = csT + (((size_t)b)*8 + h)*4096;
  const u16* c2 = csT + (((size_t)64 + b)*8 + h)*4096;
  for (int mt = w; mt < 19; mt += 4) {
    const int m = mt*16 + l15;
    const bool mv = (m < 300);
    const u16* q1 = s1 + ((size_t)b*300 + m)*512 + h*64;
    const u16* q2 = s2 + ((size_t)b*300 + m)*512 + h*64;
    f4 acc[4] = {};
    #pragma unroll
    for (int kc = 0; kc < 2; kc++){
      bh8 a1 = {}, a2 = {};
      if (mv){ a1 = *(const bh8*)(q1 + kc*32 + lg*8); a2 = *(const bh8*)(q2 + kc*32 + lg*8); }
      #pragma unroll
      for (int nt = 0; nt < 4; nt++){
        const bh8 b2v = *(const bh8*)&c2[(size_t)(nt*16+l15)*64 + kc*32 + lg*8];
        acc[nt] = __builtin_amdgcn_mfma_f32_16x16x32_bf16(a1, b2v, acc[nt], 0, 0, 0);
        const bh8 b1v = *(const bh8*)&c1[(size_t)(nt*16+l15)*64 + kc*32 + lg*8];
        acc[nt] = __builtin_amdgcn_mfma_f32_16x16x32_bf16(a2, b1v, acc[nt], 0, 0, 0);
      }
    }
    #pragma unroll
    for (int nt = 0; nt < 4; nt++)
      #pragma unroll
      for (int r = 0; r < 4; r++){
        const int mm = mt*16 + lg*4 + r;
        if (mm < 300)
          merge[((size_t)b*300 + mm)*1024 + h*64 + nt*16 + l15] = f2b(acc[nt][r]);
      }
  }
}

// ---------------- channel out (transposed): merge[:, 512:] = (q1c@c2c + q2c@c1c)^T ----------------
__global__ __launch_bounds__(256)
void ch_out_kernel(const u16* __restrict__ cT1, const u16* __restrict__ cT2,
                   const u16* __restrict__ ccT, u16* __restrict__ merge)
{
  const int cb = blockIdx.x, h = blockIdx.y, b = blockIdx.z;
  const int tid = threadIdx.x, w = tid >> 6, lane = tid & 63, l15 = lane & 15, lg = lane >> 4;
  const int chbase = cb*128 + w*32;
  f4 acc[5][2] = {};
  #pragma unroll
  for (int oi = 0; oi < 2; oi++){
    const u16* Am = ccT + (((size_t)((oi==0)?1:0)*64 + b)*4 + h)*(size_t)(80*96);
    const u16* qb = (oi==0) ? cT1 : cT2;
    #pragma unroll
    for (int kc = 0; kc < 3; kc++){
      bh8 bf[2];
      #pragma unroll
      for (int nf = 0; nf < 2; nf++){
        const int ch = chbase + nf*16 + l15;
        bf[nf] = *(const bh8*)&qb[((size_t)b*512 + ch)*320 + h*80 + kc*32 + lg*8];
      }
      #pragma unroll
      for (int mt = 0; mt < 5; mt++){
        const bh8 a = *(const bh8*)&Am[(size_t)(mt*16+l15)*96 + kc*32 + lg*8];
        #pragma unroll
        for (int nf = 0; nf < 2; nf++)
          acc[mt][nf] = __builtin_amdgcn_mfma_f32_16x16x32_bf16(a, bf[nf], acc[mt][nf], 0, 0, 0);
      }
    }
  }
  #pragma unroll
  for (int mt = 0; mt < 5; mt++)
    #pragma unroll
    for (int nf = 0; nf < 2; nf++)
      #pragma unroll
      for (int r = 0; r < 4; r++){
        const int e = mt*16 + lg*4 + r;
        if (e < 75)
          merge[((size_t)b*300 + h*75 + e)*1024 + 512 + chbase + nf*16 + l15] = f2b(acc[mt][nf][r]);
      }
}

// ---------------- depthwise 3x3 + bias + leaky(0.01), channels-last ----------------
__global__ __launch_bounds__(256)
void dw_kernel(const u16* __restrict__ e1, const float* __restrict__ wgt,
               const float* __restrict__ bias, u16* __restrict__ d1)
{
  const int idx = blockIdx.x*256 + threadIdx.x;
  const int cg = idx & 63;
  const int sp = (idx >> 6) % 300;
  const int b  = idx / (64*300);
  const int c0 = cg*8;
  const int hh = sp / 15, ww = sp - hh*15;
  float acc[8];
  #pragma unroll
  for (int j = 0; j < 8; j++) acc[j] = bias[c0+j];
  #pragma unroll
  for (int dy = -1; dy <= 1; dy++){
    const int h2 = hh + dy; if (h2 < 0 || h2 >= 20) continue;
    #pragma unroll
    for (int dx = -1; dx <= 1; dx++){
      const int w2 = ww + dx; if (w2 < 0 || w2 >= 15) continue;
      const bh8 vv = *(const bh8*)&e1[((size_t)b*300 + h2*15 + w2)*512 + c0];
      const int t = (dy+1)*3 + (dx+1);
      #pragma unroll
      for (int j = 0; j < 8; j++)
        acc[j] += b2f((u16)vv[j]) * wgt[(c0+j)*9 + t];
    }
  }
  bh8 ov;
  #pragma unroll
  for (int j = 0; j < 8; j++){
    float y = acc[j];
    y = (y >= 0.f) ? y : 0.01f*y;
    ov[j] = (short)f2b(y);
  }
  *(bh8*)&d1[((size_t)b*300 + sp)*512 + c0] = ov;
}

// ---------------- BN stats / finalize / final write ----------------
__global__ __launch_bounds__(256)
void stats_e(const float* __restrict__ e3, float* __restrict__ st){
  const int tid = threadIdx.x;
  const int c0 = tid*2;
  const size_t r0 = (size_t)blockIdx.x * 128;
  float s0=0,s1=0,q0=0,q1=0;
  for (int rr = 0; rr < 128; rr++){
    const float2 v = *(const float2*)&e3[(r0+rr)*512 + c0];
    s0 += v.x; s1 += v.y; q0 += v.x*v.x; q1 += v.y*v.y;
  }
  atomicAdd(&st[c0], s0); atomicAdd(&st[c0+1], s1);
  atomicAdd(&st[512+c0], q0); atomicAdd(&st[512+c0+1], q1);
}
__global__ void fin_e(float* st, const float* __restrict__ w, const float* __restrict__ b){
  const int c = threadIdx.x;
  const float m = st[c] * (1.f/19200.f);
  const float v = st[512+c] * (1.f/19200.f) - m*m;
  const float a = w[c] * rsqrtf(v + 1e-5f);
  st[1024+c] = a; st[1536+c] = b[c] - m*a;
}
__global__ __launch_bounds__(256)
void stats_o(const float* __restrict__ res, const float* __restrict__ e3, float* __restrict__ st){
  const int tid = threadIdx.x;
  const int c0 = tid*2;
  const float a0 = st[1024+c0], b0v = st[1536+c0];
  const float a1 = st[1024+c0+1], b1v = st[1536+c0+1];
  const size_t r0 = (size_t)blockIdx.x * 128;
  float s0=0,s1=0,q0=0,q1=0;
  for (int rr = 0; rr < 128; rr++){
    const size_t o2 = (r0+rr)*512 + c0;
    const float2 rv = *(const float2*)&res[o2];
    const float2 ev = *(const float2*)&e3[o2];
    const float v0 = rv.x + ev.x*a0 + b0v;
    const float v1 = rv.y + ev.y*a1 + b1v;
    s0 += v0; s1 += v1; q0 += v0*v0; q1 += v1*v1;
  }
  atomicAdd(&st[2048+c0], s0); atomicAdd(&st[2048+c0+1], s1);
  atomicAdd(&st[2560+c0], q0); atomicAdd(&st[2560+c0+1], q1);
}
__global__ void fin_o(float* st, const float* __restrict__ w, const float* __restrict__ b){
  const int c = threadIdx.x;
  const float m = st[2048+c] * (1.f/19200.f);
  const float v = st[2560+c] * (1.f/19200.f) - m*m;
  const float a = w[c] * rsqrtf(v + 1e-5f);
  st[3072+c] = a; st[3584+c] = b[c] - m*a;
}
__global__ __launch_bounds__(256)
void final_kernel(const float* __restrict__ res, const float* __restrict__ e3,
                  const float* __restrict__ st, float* __restrict__ outp)
{
  __shared__ float tile[64][65];
  const int spt = blockIdx.x, cht = blockIdx.y, b = blockIdx.z;
  const int tid = threadIdx.x;
  const int sp0 = spt*64, ch0 = cht*64;
  for (int idx = tid; idx < 4096; idx += 256){
    const int cl = idx & 63, sl = idx >> 6;
    const int sp = sp0 + sl;
    float v = 0.f;
    if (sp < 300){
      const size_t off = ((size_t)b*300 + sp)*512 + ch0 + cl;
      const int c = ch0 + cl;
      const float e = e3[off]*st[1024+c] + st[1536+c];
      v = (res[off] + e)*st[3072+c] + st[3584+c];
    }
    tile[sl][cl] = v;
  }
  __syncthreads();
  for (int idx = tid; idx < 4096; idx += 256){
    const int sl = idx & 63, cl = idx >> 6;
    const int sp = sp0 + sl;
    if (sp < 300)
      outp[((size_t)b*512 + ch0 + cl)*300 + sp] = tile[sl][cl];
  }
}

// ---------------- host ----------------
extern "C" void kernel_launch(void* const* d_in, const int* in_sizes, int n_in,
                              void* d_out, int out_size, void* d_ws, size_t ws_size,
                              hipStream_t stream)
{
  const float* x1    = (const float*)d_in[0];
  const float* x2    = (const float*)d_in[1];
  const float* cp1_w = (const float*)d_in[2];
  const float* cp1_b = (const float*)d_in[3];
  const float* ln1_w = (const float*)d_in[4];
  const float* ln1_b = (const float*)d_in[5];
  const float* cp2_w = (const float*)d_in[6];
  const float* cp2_b = (const float*)d_in[7];
  const float* ln2_w = (const float*)d_in[8];
  const float* ln2_b = (const float*)d_in[9];
  const float* skv1w = (const float*)d_in[10];
  const float* skv2w = (const float*)d_in[11];
  const float* ckv1w = (const float*)d_in[12];
  const float* ckv2w = (const float*)d_in[13];
  const float* resw  = (const float*)d_in[14];
  const float* ce1w  = (const float*)d_in[15];
  const float* ce1b  = (const float*)d_in[16];
  const float* dww   = (const float*)d_in[17];
  const float* dwb   = (const float*)d_in[18];
  const float* ce3w  = (const float*)d_in[19];
  const float* ce3b  = (const float*)d_in[20];
  const float* bnew  = (const float*)d_in[21];
  const float* bneb  = (const float*)d_in[22];
  const float* bnow  = (const float*)d_in[23];
  const float* bnob  = (const float*)d_in[24];
  float* out = (float*)d_out;
  char* ws = (char*)d_ws;

  const size_t SZ_T    = (size_t)19200*512*2;
  const size_t SZ_APRE = (size_t)19200*1024*2;
  const size_t SZ_CKV  = (size_t)32768*640*2;
  const size_t SZ_CT   = (size_t)64*512*320*2;
  const size_t SZ_F32  = (size_t)19200*512*4;

  size_t off = 0;
  auto AL = [&](size_t sz){ size_t r = off; off += (sz + 255) & ~(size_t)255; return r; };
  const size_t oR0 = AL(2*SZ_T);             // t1,t2 -> merge
  const size_t oR1 = AL(2*SZ_CKV);           // apre1,apre2 -> kv1,kv2 -> ckv1,ckv2
  const size_t oR2 = AL(2*SZ_T);             // s1,s2 -> e1,d1
  const size_t oR3 = AL(2*SZ_CT + 4096);     // cT1,cT2 -> e3(f32)
  const size_t oR4 = AL(SZ_F32);             // res f32
  const size_t oR5 = AL((size_t)2*64*8*64*64*2);  // c_sT
  const size_t oR6 = AL((size_t)2*64*4*80*96*2);  // c_cT
  const size_t oWcp1  = AL((size_t)1024*512*2);
  const size_t oWcp2  = AL((size_t)1024*512*2);
  const size_t oWskv1 = AL((size_t)1024*512*2);
  const size_t oWskv2 = AL((size_t)1024*512*2);
  const size_t oWckv1 = AL((size_t)640*320*2);
  const size_t oWckv2 = AL((size_t)640*320*2);
  const size_t oWres  = AL((size_t)512*1024*2);
  const size_t oWce1  = AL((size_t)512*1024*2);
  const size_t oWce3  = AL((size_t)512*512*2);
  const size_t oST    = AL(16384);
  (void)ws_size; (void)in_sizes; (void)n_in; (void)out_size;

  u16* t1    = (u16*)(ws + oR0);
  u16* t2    = (u16*)(ws + oR0 + SZ_T);
  u16* merge = (u16*)(ws + oR0);
  u16* apre1 = (u16*)(ws + oR1);
  u16* apre2 = (u16*)(ws + oR1 + SZ_APRE);
  u16* kv1   = apre1;
  u16* kv2   = apre2;
  u16* ckv1  = (u16*)(ws + oR1);
  u16* ckv2  = (u16*)(ws + oR1 + SZ_CKV);
  u16* s1    = (u16*)(ws + oR2);
  u16* s2    = (u16*)(ws + oR2 + SZ_T);
  u16* e1    = s1;
  u16* d1    = s2;
  u16* cT1   = (u16*)(ws + oR3);
  u16* cT2   = (u16*)(ws + oR3 + SZ_CT);
  u16* slack = (u16*)(ws + oR3 + 2*SZ_CT);
  float* e3  = (float*)(ws + oR3);
  float* resb = (float*)(ws + oR4);
  u16* csT   = (u16*)(ws + oR5);
  u16* ccT   = (u16*)(ws + oR6);
  u16* wcp1  = (u16*)(ws + oWcp1);
  u16* wcp2  = (u16*)(ws + oWcp2);
  u16* wskv1 = (u16*)(ws + oWskv1);
  u16* wskv2 = (u16*)(ws + oWskv2);
  u16* wckv1 = (u16*)(ws + oWckv1);
  u16* wckv2 = (u16*)(ws + oWckv2);
  u16* wres  = (u16*)(ws + oWres);
  u16* wce1  = (u16*)(ws + oWce1);
  u16* wce3  = (u16*)(ws + oWce3);
  float* st  = (float*)(ws + oST);

  hipMemsetAsync(st, 0, 16384, stream);
  pad_zero<<<1033,256,0,stream>>>(cT1, cT2, slack);
  pack_plain<<<2048,256,0,stream>>>(cp1_w, wcp1, 524288);
  pack_plain<<<2048,256,0,stream>>>(cp2_w, wcp2, 524288);
  pack_plain<<<2048,256,0,stream>>>(skv1w, wskv1, 524288);
  pack_plain<<<2048,256,0,stream>>>(skv2w, wskv2, 524288);
  pack_ckv_k<<<800,256,0,stream>>>(ckv1w, wckv1);
  pack_ckv_k<<<800,256,0,stream>>>(ckv2w, wckv2);
  pack_plain<<<2048,256,0,stream>>>(resw, wres, 524288);
  pack_plain<<<2048,256,0,stream>>>(ce1w, wce1, 524288);
  pack_plain<<<1024,256,0,stream>>>(ce3w, wce3, 262144);

  transpose_k<<<dim3(10,16,64),256,0,stream>>>(x1, t1);
  transpose_k<<<dim3(10,16,64),256,0,stream>>>(x2, t2);

  gemm_k<0,1><<<dim3(150,8),256,0,stream>>>(t1,512, wcp1,512, apre1,nullptr,1024, cp1_b, 512);
  gemm_k<0,1><<<dim3(150,8),256,0,stream>>>(t2,512, wcp2,512, apre2,nullptr,1024, cp2_b, 512);

  ln_kernel<<<19200,256,0,stream>>>(apre1, ln1_w, ln1_b, s1, cT1);
  ln_kernel<<<19200,256,0,stream>>>(apre2, ln2_w, ln2_b, s2, cT2);

  gemm_k<0,0><<<dim3(150,8),256,0,stream>>>(s1,512, wskv1,512, kv1,nullptr,1024, nullptr, 512);
  gemm_k<0,0><<<dim3(150,8),256,0,stream>>>(s2,512, wskv2,512, kv2,nullptr,1024, nullptr, 512);

  ctx_kernel<64,64,64><<<dim3(8,64,2),256,0,stream>>>(kv1, kv2, csT, 300, 1024, 512, 0.125f);

  gemm_k<0,0><<<dim3(256,5),256,0,stream>>>(cT1,320, wckv1,320, ckv1,nullptr,640, nullptr, 320);
  gemm_k<0,0><<<dim3(256,5),256,0,stream>>>(cT2,320, wckv2,320, ckv2,nullptr,640, nullptr, 320);

  ctx_kernel<80,75,96><<<dim3(4,64,2),256,0,stream>>>(ckv1, ckv2, ccT, 512, 640, 320, 0.115470054f);

  sp_out_kernel<<<dim3(8,64),256,0,stream>>>(s1, s2, csT, merge);
  ch_out_kernel<<<dim3(4,4,64),256,0,stream>>>(cT1, cT2, ccT, merge);

  gemm_k<1,0><<<dim3(150,4),256,0,stream>>>(merge,1024, wres,1024, nullptr,resb,512, nullptr, 1024);
  gemm_k<0,1><<<dim3(150,4),256,0,stream>>>(merge,1024, wce1,1024, e1,nullptr,512, ce1b, 1024);

  dw_kernel<<<4800,256,0,stream>>>(e1, dww, dwb, d1);

  gemm_k<1,1><<<dim3(150,4),256,0,stream>>>(d1,512, wce3,512, nullptr,e3,512, ce3b, 512);

  stats_e<<<150,256,0,stream>>>(e3, st);
  fin_e<<<1,512,0,stream>>>(st, bnew, bneb);
  stats_o<<<150,256,0,stream>>>(resb, e3, st);
  fin_o<<<1,512,0,stream>>>(st, bnow, bnob);
  final_kernel<<<dim3(5,8,64),256,0,stream>>>(resb, e3, st, out);
}

// Round 3
// 766.380 us; speedup vs baseline: 1.1718x; 1.1718x over previous
//
#include <hip/hip_runtime.h>

typedef unsigned short u16;
typedef __attribute__((ext_vector_type(8))) short bh8;
typedef __attribute__((ext_vector_type(4))) float f4;

__device__ __forceinline__ u16 f2b(float f){
  unsigned int u = __float_as_uint(f);
  u += 0x7fffu + ((u >> 16) & 1u);
  return (u16)(u >> 16);
}
__device__ __forceinline__ float b2f(u16 h){
  return __uint_as_float(((unsigned int)h) << 16);
}
__device__ __forceinline__ void gl16(const u16* g, u16* l){
  __builtin_amdgcn_global_load_lds((const __attribute__((address_space(1))) void*)g,
                                   (__attribute__((address_space(3))) void*)l, 16, 0, 0);
}

// ---------------- packing ----------------
__global__ void pack_plain(const float* __restrict__ src, u16* __restrict__ dst, int count){
  int i = blockIdx.x*256 + threadIdx.x;
  if (i < count) dst[i] = f2b(src[i]);
}
// c_kv_w (600,300) -> padded [640][320]: n = t*320+h*80+dd, k = kh*80+kd
__global__ void pack_ckv_k(const float* __restrict__ src, u16* __restrict__ dst){
  int i = blockIdx.x*256 + threadIdx.x; // 640*320
  int nn = i / 320, kk = i - (i/320)*320;
  int t_ = (nn >= 320) ? 1 : 0;
  int rem = nn - t_*320;
  int hh = rem / 80, dd = rem - hh*80;
  int kh = kk / 80, kd = kk - kh*80;
  float v = 0.f;
  if (dd < 75 && kd < 75)
    v = src[(size_t)(t_*300 + hh*75 + dd)*300 + (kh*75 + kd)];
  dst[i] = f2b(v);
}
// dw weight (512,1,3,3) -> dwt[9][512] bf16 (tap-major, coalesced per-tap loads)
__global__ void pack_dw(const float* __restrict__ src, u16* __restrict__ dst){
  int i = blockIdx.x*256 + threadIdx.x; // 4608
  if (i < 4608){
    int t = i >> 9, c = i & 511;
    dst[i] = f2b(src[c*9 + t]);
  }
}
// zero the never-written pad stripes of cT1/cT2 (cols h*80+75..79) and the
// 4KiB slack after cT2 that ch_out's tail k-chunk over-reads (x0, but must be finite)
__global__ void pad_zero(u16* __restrict__ cT1, u16* __restrict__ cT2, u16* __restrict__ slack){
  const int idx = blockIdx.x*256 + threadIdx.x;
  if (idx < 262144){
    const int t = idx >> 17;
    const int rem = idx & 131071;
    const int rc = rem >> 2, h = rem & 3;
    u16* p = (t ? cT2 : cT1) + (size_t)rc*320 + h*80 + 75;
    p[0]=0; p[1]=0; p[2]=0; p[3]=0; p[4]=0;
  } else {
    const int j = idx - 262144;
    if (j < 2048) slack[j] = 0;
  }
}

// ---------------- x (B,C,H,W) f32 -> t (B,N,C) bf16 ----------------
__global__ __launch_bounds__(256)
void transpose_k(const float* __restrict__ x, u16* __restrict__ t)
{
  __shared__ float tile[32][33];
  const int n0 = blockIdx.x * 32, c0 = blockIdx.y * 32, b = blockIdx.z;
  const int ln = threadIdx.x & 31, lr = threadIdx.x >> 5;
  #pragma unroll
  for (int q = 0; q < 4; q++) {
    const int c = c0 + lr + q*8, n = n0 + ln;
    tile[lr + q*8][ln] = (n < 300) ? x[((long)b*512 + c)*300 + n] : 0.f;
  }
  __syncthreads();
  #pragma unroll
  for (int q = 0; q < 4; q++) {
    const int n = n0 + lr + q*8;
    if (n < 300) t[((long)b*300 + n)*512 + c0 + ln] = f2b(tile[ln][lr + q*8]);
  }
}

// ---------------- generic 128x128 MFMA GEMM: C = A(M,K) @ Bw(N,K)^T ----------------
template<int OUTF, int HASB>
__global__ __launch_bounds__(256)
void gemm_k(const u16* __restrict__ A, int lda,
            const u16* __restrict__ Bw, int ldb,
            u16* __restrict__ Cb, float* __restrict__ Cf, int ldc,
            const float* __restrict__ bias, int K)
{
  __shared__ u16 As[128*32];
  __shared__ u16 Bs[128*32];
  const int tid = threadIdx.x;
  const long m0 = (long)blockIdx.x * 128;
  const long n0 = (long)blockIdx.y * 128;
  const int wave = tid >> 6, lane = tid & 63;
  const int l15 = lane & 15, lg = lane >> 4;
  const int wr = (wave >> 1) * 64, wc = (wave & 1) * 64;
  const int arow = tid >> 2, aseg = (tid & 3) * 8;
  const u16* Ag0 = A + (m0 + arow) * (long)lda + aseg;
  const u16* Ag1 = Ag0 + 64L * lda;
  const u16* Bg0 = Bw + (n0 + arow) * (long)ldb + aseg;
  const u16* Bg1 = Bg0 + 64L * ldb;
  u16* lA0 = &As[tid * 8];
  u16* lA1 = &As[2048 + tid * 8];
  u16* lB0 = &Bs[tid * 8];
  u16* lB1 = &Bs[2048 + tid * 8];
  f4 acc[4][4] = {};
  for (int kt = 0; kt < K; kt += 32) {
    gl16(Ag0 + kt, lA0);
    gl16(Ag1 + kt, lA1);
    gl16(Bg0 + kt, lB0);
    gl16(Bg1 + kt, lB1);
    __syncthreads();
    bh8 af[4], bf[4];
    #pragma unroll
    for (int mi = 0; mi < 4; mi++)
      af[mi] = *(const bh8*)&As[(wr + mi*16 + l15)*32 + lg*8];
    #pragma unroll
    for (int ni = 0; ni < 4; ni++)
      bf[ni] = *(const bh8*)&Bs[(wc + ni*16 + l15)*32 + lg*8];
    #pragma unroll
    for (int mi = 0; mi < 4; mi++)
      #pragma unroll
      for (int ni = 0; ni < 4; ni++)
        acc[mi][ni] = __builtin_amdgcn_mfma_f32_16x16x32_bf16(af[mi], bf[ni], acc[mi][ni], 0, 0, 0);
    __syncthreads();
  }
  #pragma unroll
  for (int ni = 0; ni < 4; ni++) {
    const long cn = n0 + wc + ni*16 + l15;
    const float bv = HASB ? bias[cn] : 0.0f;
    #pragma unroll
    for (int mi = 0; mi < 4; mi++) {
      #pragma unroll
      for (int r = 0; r < 4; r++) {
        const long cm = m0 + wr + mi*16 + lg*4 + r;
        const float v = acc[mi][ni][r] + bv;
        if (OUTF) Cf[cm * ldc + cn] = v;
        else      Cb[cm * ldc + cn] = f2b(v);
      }
    }
  }
}

// ---------------- LayerNorm(1024) + relu; split into s (B,N,512) and cT (B,512,320pad) ----------------
__global__ __launch_bounds__(256)
void ln_kernel(const u16* __restrict__ apre, const float* __restrict__ lw, const float* __restrict__ lb,
               u16* __restrict__ s, u16* __restrict__ cT)
{
  __shared__ float rS[4], rQ[4];
  const int r = blockIdx.x;           // b*300 + n
  const int b = r / 300, n = r - b*300;
  const int tid = threadIdx.x, lane = tid & 63, w = tid >> 6;
  const u16* row = apre + (size_t)r*1024 + tid*4;
  float v[4];
  {
    const uint2 u = *(const uint2*)row;
    v[0] = b2f((u16)(u.x & 0xffff)); v[1] = b2f((u16)(u.x >> 16));
    v[2] = b2f((u16)(u.y & 0xffff)); v[3] = b2f((u16)(u.y >> 16));
  }
  float sm = v[0]+v[1]+v[2]+v[3];
  float sq = v[0]*v[0]+v[1]*v[1]+v[2]*v[2]+v[3]*v[3];
  #pragma unroll
  for (int o = 32; o; o >>= 1){ sm += __shfl_xor(sm, o); sq += __shfl_xor(sq, o); }
  if (lane == 0){ rS[w] = sm; rQ[w] = sq; }
  __syncthreads();
  sm = rS[0]+rS[1]+rS[2]+rS[3]; sq = rQ[0]+rQ[1]+rQ[2]+rQ[3];
  const float mean = sm * (1.f/1024.f);
  const float rstd = rsqrtf(sq*(1.f/1024.f) - mean*mean + 1e-5f);
  const int col0 = tid*4;
  const int nn = (n/75)*80 + (n - (n/75)*75);
  #pragma unroll
  for (int j = 0; j < 4; j++){
    const int c = col0 + j;
    float y = (v[j]-mean)*rstd*lw[c] + lb[c];
    y = fmaxf(y, 0.f);
    const u16 hb = f2b(y);
    if (c < 512) cT[((size_t)b*512 + c)*320 + nn] = hb;
    else         s[(size_t)r*512 + (c-512)] = hb;
  }
}

// ---------------- attn ctx: out[e][d] = softmax_d( scale * sum_n k[n,d] v[n,e] ), stored transposed ----------------
template<int D, int DREAL, int OS>
__global__ __launch_bounds__(256)
void ctx_kernel(const u16* __restrict__ kva, const u16* __restrict__ kvb,
                u16* __restrict__ outp, int K, int RS, int VOFF, float scale)
{
  constexpr int NT = D/16, MT = D/16, MTL = (MT+3)/4, SEG = D/8;
  __shared__ u16 vT[D][40];
  __shared__ u16 kT[D][40];
  const int h = blockIdx.x, b = blockIdx.y, iq = blockIdx.z;
  const int Hn = gridDim.x;
  const u16* base = (iq ? kvb : kva) + (size_t)b*K*RS + h*D;
  u16* out = outp + (((size_t)iq*64 + b)*Hn + h)*(size_t)(D*OS);
  const int tid = threadIdx.x, w = tid >> 6, lane = tid & 63, l15 = lane & 15, lg = lane >> 4;
  f4 acc[MTL][NT] = {};
  for (int k0 = 0; k0 < K; k0 += 32) {
    __syncthreads();
    for (int sI = tid; sI < 32*SEG; sI += 256) {
      const int nn = sI / SEG, dseg = sI - (sI/SEG)*SEG;
      bh8 kk = {}, vv = {};
      const int krow = k0 + nn;
      if (krow < K) {
        const u16* p = base + (size_t)krow*RS + dseg*8;
        kk = *(const bh8*)p;
        vv = *(const bh8*)(p + VOFF);
      }
      #pragma unroll
      for (int j = 0; j < 8; j++){
        kT[dseg*8+j][nn] = (u16)kk[j];
        vT[dseg*8+j][nn] = (u16)vv[j];
      }
    }
    __syncthreads();
    #pragma unroll
    for (int ii = 0; ii < MTL; ii++){
      const int mt = w + ii*4;
      if (MT % 4 != 0 && mt >= MT) break;
      const bh8 a = *(const bh8*)&vT[mt*16 + l15][lg*8];
      #pragma unroll
      for (int nt = 0; nt < NT; nt++){
        const bh8 bb = *(const bh8*)&kT[nt*16 + l15][lg*8];
        acc[ii][nt] = __builtin_amdgcn_mfma_f32_16x16x32_bf16(a, bb, acc[ii][nt], 0, 0, 0);
      }
    }
  }
  #pragma unroll
  for (int ii = 0; ii < MTL; ii++){
    const int mt = w + ii*4;
    if (MT % 4 != 0 && mt >= MT) continue;
    #pragma unroll
    for (int r = 0; r < 4; r++){
      const int e = mt*16 + lg*4 + r;
      float xs[NT]; float mx = -1e30f;
      #pragma unroll
      for (int nt = 0; nt < NT; nt++){
        float x = acc[ii][nt][r] * scale;
        if (DREAL != D && (nt*16 + l15) >= DREAL) x = -1e30f;
        xs[nt] = x; mx = fmaxf(mx, x);
      }
      mx = fmaxf(mx, __shfl_xor(mx,1)); mx = fmaxf(mx, __shfl_xor(mx,2));
      mx = fmaxf(mx, __shfl_xor(mx,4)); mx = fmaxf(mx, __shfl_xor(mx,8));
      float smv = 0.f;
      #pragma unroll
      for (int nt = 0; nt < NT; nt++){
        const float p = (xs[nt] > -1e29f) ? __expf(xs[nt]-mx) : 0.f;
        xs[nt] = p; smv += p;
      }
      smv += __shfl_xor(smv,1); smv += __shfl_xor(smv,2);
      smv += __shfl_xor(smv,4); smv += __shfl_xor(smv,8);
      const float inv = 1.f / smv;
      #pragma unroll
      for (int nt = 0; nt < NT; nt++)
        out[(size_t)e*OS + nt*16 + l15] = f2b(xs[nt]*inv);
      if (OS > D) out[(size_t)e*OS + D + l15] = 0;
    }
  }
}

// ---------------- spatial out: merge[:, :512] = q1@c2 + q2@c1 ----------------
__global__ __launch_bounds__(256)
void sp_out_kernel(const u16* __restrict__ s1, const u16* __restrict__ s2,
                   const u16* __restrict__ csT, u16* __restrict__ merge)
{
  const int h = blockIdx.x, b = blockIdx.y;
  const int tid = threadIdx.x, w = tid >> 6, lane = tid & 63, l15 = lane & 15, lg = lane >> 4;
  const u16* c1 = csT + (((size_t)b)*8 + h)*4096;
  const u16* c2 = csT + (((size_t)64 + b)*8 + h)*4096;
  for (int mt = w; mt < 19; mt += 4) {
    const int m = mt*16 + l15;
    const bool mv = (m < 300);
    const u16* q1 = s1 + ((size_t)b*300 + m)*512 + h*64;
    const u16* q2 = s2 + ((size_t)b*300 + m)*512 + h*64;
    f4 acc[4] = {};
    #pragma unroll
    for (int kc = 0; kc < 2; kc++){
      bh8 a1 = {}, a2 = {};
      if (mv){ a1 = *(const bh8*)(q1 + kc*32 + lg*8); a2 = *(const bh8*)(q2 + kc*32 + lg*8); }
      #pragma unroll
      for (int nt = 0; nt < 4; nt++){
        const bh8 b2v = *(const bh8*)&c2[(size_t)(nt*16+l15)*64 + kc*32 + lg*8];
        acc[nt] = __builtin_amdgcn_mfma_f32_16x16x32_bf16(a1, b2v, acc[nt], 0, 0, 0);
        const bh8 b1v = *(const bh8*)&c1[(size_t)(nt*16+l15)*64 + kc*32 + lg*8];
        acc[nt] = __builtin_amdgcn_mfma_f32_16x16x32_bf16(a2, b1v, acc[nt], 0, 0, 0);
      }
    }
    #pragma unroll
    for (int nt = 0; nt < 4; nt++)
      #pragma unroll
      for (int r = 0; r < 4; r++){
        const int mm = mt*16 + lg*4 + r;
        if (mm < 300)
          merge[((size_t)b*300 + mm)*1024 + h*64 + nt*16 + l15] = f2b(acc[nt][r]);
      }
  }
}

// ---------------- channel out (transposed): merge[:, 512:] = (q1c@c2c + q2c@c1c)^T ----------------
__global__ __launch_bounds__(256)
void ch_out_kernel(const u16* __restrict__ cT1, const u16* __restrict__ cT2,
                   const u16* __restrict__ ccT, u16* __restrict__ merge)
{
  const int cb = blockIdx.x, h = blockIdx.y, b = blockIdx.z;
  const int tid = threadIdx.x, w = tid >> 6, lane = tid & 63, l15 = lane & 15, lg = lane >> 4;
  const int chbase = cb*128 + w*32;
  f4 acc[5][2] = {};
  #pragma unroll
  for (int oi = 0; oi < 2; oi++){
    const u16* Am = ccT + (((size_t)((oi==0)?1:0)*64 + b)*4 + h)*(size_t)(80*96);
    const u16* qb = (oi==0) ? cT1 : cT2;
    #pragma unroll
    for (int kc = 0; kc < 3; kc++){
      bh8 bf[2];
      #pragma unroll
      for (int nf = 0; nf < 2; nf++){
        const int ch = chbase + nf*16 + l15;
        bf[nf] = *(const bh8*)&qb[((size_t)b*512 + ch)*320 + h*80 + kc*32 + lg*8];
      }
      #pragma unroll
      for (int mt = 0; mt < 5; mt++){
        const bh8 a = *(const bh8*)&Am[(size_t)(mt*16+l15)*96 + kc*32 + lg*8];
        #pragma unroll
        for (int nf = 0; nf < 2; nf++)
          acc[mt][nf] = __builtin_amdgcn_mfma_f32_16x16x32_bf16(a, bf[nf], acc[mt][nf], 0, 0, 0);
      }
    }
  }
  #pragma unroll
  for (int mt = 0; mt < 5; mt++)
    #pragma unroll
    for (int nf = 0; nf < 2; nf++)
      #pragma unroll
      for (int r = 0; r < 4; r++){
        const int e = mt*16 + lg*4 + r;
        if (e < 75)
          merge[((size_t)b*300 + h*75 + e)*1024 + 512 + chbase + nf*16 + l15] = f2b(acc[mt][nf][r]);
      }
}

// ---------------- depthwise 3x3 + bias + leaky(0.01), channels-last, tap-major bf16 weights ----------------
__global__ __launch_bounds__(256)
void dw_kernel(const u16* __restrict__ e1, const u16* __restrict__ dwt,
               const float* __restrict__ bias, u16* __restrict__ d1)
{
  const int idx = blockIdx.x*256 + threadIdx.x;
  const int cg = idx & 63;
  const int sp = (idx >> 6) % 300;
  const int b  = idx / (64*300);
  const int c0 = cg*8;
  const int hh = sp / 15, ww = sp - hh*15;
  float acc[8];
  {
    const float4 b0 = *(const float4*)&bias[c0];
    const float4 b1 = *(const float4*)&bias[c0+4];
    acc[0]=b0.x; acc[1]=b0.y; acc[2]=b0.z; acc[3]=b0.w;
    acc[4]=b1.x; acc[5]=b1.y; acc[6]=b1.z; acc[7]=b1.w;
  }
  #pragma unroll
  for (int dy = -1; dy <= 1; dy++){
    const int h2 = hh + dy; if (h2 < 0 || h2 >= 20) continue;
    #pragma unroll
    for (int dx = -1; dx <= 1; dx++){
      const int w2 = ww + dx; if (w2 < 0 || w2 >= 15) continue;
      const bh8 vv = *(const bh8*)&e1[((size_t)b*300 + h2*15 + w2)*512 + c0];
      const int t = (dy+1)*3 + (dx+1);
      const bh8 wv = *(const bh8*)&dwt[t*512 + c0];
      #pragma unroll
      for (int j = 0; j < 8; j++)
        acc[j] += b2f((u16)vv[j]) * b2f((u16)wv[j]);
    }
  }
  bh8 ov;
  #pragma unroll
  for (int j = 0; j < 8; j++){
    float y = acc[j];
    y = (y >= 0.f) ? y : 0.01f*y;
    ov[j] = (short)f2b(y);
  }
  *(bh8*)&d1[((size_t)b*300 + sp)*512 + c0] = ov;
}

// ---------------- BN stats / finalize / final write ----------------
__global__ __launch_bounds__(256)
void stats_e(const float* __restrict__ e3, float* __restrict__ st){
  const int tid = threadIdx.x;
  const int c0 = tid*2;
  const size_t r0 = (size_t)blockIdx.x * 128;
  float s0=0,s1=0,q0=0,q1=0;
  for (int rr = 0; rr < 128; rr++){
    const float2 v = *(const float2*)&e3[(r0+rr)*512 + c0];
    s0 += v.x; s1 += v.y; q0 += v.x*v.x; q1 += v.y*v.y;
  }
  atomicAdd(&st[c0], s0); atomicAdd(&st[c0+1], s1);
  atomicAdd(&st[512+c0], q0); atomicAdd(&st[512+c0+1], q1);
}
__global__ void fin_e(float* st, const float* __restrict__ w, const float* __restrict__ b){
  const int c = threadIdx.x;
  const float m = st[c] * (1.f/19200.f);
  const float v = st[512+c] * (1.f/19200.f) - m*m;
  const float a = w[c] * rsqrtf(v + 1e-5f);
  st[1024+c] = a; st[1536+c] = b[c] - m*a;
}
__global__ __launch_bounds__(256)
void stats_o(const float* __restrict__ res, const float* __restrict__ e3, float* __restrict__ st){
  const int tid = threadIdx.x;
  const int c0 = tid*2;
  const float a0 = st[1024+c0], b0v = st[1536+c0];
  const float a1 = st[1024+c0+1], b1v = st[1536+c0+1];
  const size_t r0 = (size_t)blockIdx.x * 128;
  float s0=0,s1=0,q0=0,q1=0;
  for (int rr = 0; rr < 128; rr++){
    const size_t o2 = (r0+rr)*512 + c0;
    const float2 rv = *(const float2*)&res[o2];
    const float2 ev = *(const float2*)&e3[o2];
    const float v0 = rv.x + ev.x*a0 + b0v;
    const float v1 = rv.y + ev.y*a1 + b1v;
    s0 += v0; s1 += v1; q0 += v0*v0; q1 += v1*v1;
  }
  atomicAdd(&st[2048+c0], s0); atomicAdd(&st[2048+c0+1], s1);
  atomicAdd(&st[2560+c0], q0); atomicAdd(&st[2560+c0+1], q1);
}
__global__ void fin_o(float* st, const float* __restrict__ w, const float* __restrict__ b){
  const int c = threadIdx.x;
  const float m = st[2048+c] * (1.f/19200.f);
  const float v = st[2560+c] * (1.f/19200.f) - m*m;
  const float a = w[c] * rsqrtf(v + 1e-5f);
  st[3072+c] = a; st[3584+c] = b[c] - m*a;
}
__global__ __launch_bounds__(256)
void final_kernel(const float* __restrict__ res, const float* __restrict__ e3,
                  const float* __restrict__ st, float* __restrict__ outp)
{
  __shared__ float tile[64][65];
  const int spt = blockIdx.x, cht = blockIdx.y, b = blockIdx.z;
  const int tid = threadIdx.x;
  const int sp0 = spt*64, ch0 = cht*64;
  for (int idx = tid; idx < 4096; idx += 256){
    const int cl = idx & 63, sl = idx >> 6;
    const int sp = sp0 + sl;
    float v = 0.f;
    if (sp < 300){
      const size_t off = ((size_t)b*300 + sp)*512 + ch0 + cl;
      const int c = ch0 + cl;
      const float e = e3[off]*st[1024+c] + st[1536+c];
      v = (res[off] + e)*st[3072+c] + st[3584+c];
    }
    tile[sl][cl] = v;
  }
  __syncthreads();
  for (int idx = tid; idx < 4096; idx += 256){
    const int sl = idx & 63, cl = idx >> 6;
    const int sp = sp0 + sl;
    if (sp < 300)
      outp[((size_t)b*512 + ch0 + cl)*300 + sp] = tile[sl][cl];
  }
}

// ---------------- host ----------------
extern "C" void kernel_launch(void* const* d_in, const int* in_sizes, int n_in,
                              void* d_out, int out_size, void* d_ws, size_t ws_size,
                              hipStream_t stream)
{
  const float* x1    = (const float*)d_in[0];
  const float* x2    = (const float*)d_in[1];
  const float* cp1_w = (const float*)d_in[2];
  const float* cp1_b = (const float*)d_in[3];
  const float* ln1_w = (const float*)d_in[4];
  const float* ln1_b = (const float*)d_in[5];
  const float* cp2_w = (const float*)d_in[6];
  const float* cp2_b = (const float*)d_in[7];
  const float* ln2_w = (const float*)d_in[8];
  const float* ln2_b = (const float*)d_in[9];
  const float* skv1w = (const float*)d_in[10];
  const float* skv2w = (const float*)d_in[11];
  const float* ckv1w = (const float*)d_in[12];
  const float* ckv2w = (const float*)d_in[13];
  const float* resw  = (const float*)d_in[14];
  const float* ce1w  = (const float*)d_in[15];
  const float* ce1b  = (const float*)d_in[16];
  const float* dww   = (const float*)d_in[17];
  const float* dwb   = (const float*)d_in[18];
  const float* ce3w  = (const float*)d_in[19];
  const float* ce3b  = (const float*)d_in[20];
  const float* bnew  = (const float*)d_in[21];
  const float* bneb  = (const float*)d_in[22];
  const float* bnow  = (const float*)d_in[23];
  const float* bnob  = (const float*)d_in[24];
  float* out = (float*)d_out;
  char* ws = (char*)d_ws;

  const size_t SZ_T    = (size_t)19200*512*2;
  const size_t SZ_APRE = (size_t)19200*1024*2;
  const size_t SZ_CKV  = (size_t)32768*640*2;
  const size_t SZ_CT   = (size_t)64*512*320*2;
  const size_t SZ_F32  = (size_t)19200*512*4;

  size_t off = 0;
  auto AL = [&](size_t sz){ size_t r = off; off += (sz + 255) & ~(size_t)255; return r; };
  const size_t oR0 = AL(2*SZ_T);             // t1,t2 -> merge
  const size_t oR1 = AL(2*SZ_CKV);           // apre1,apre2 -> kv1,kv2 -> ckv1,ckv2
  const size_t oR2 = AL(2*SZ_T);             // s1,s2 -> e1,d1
  const size_t oR3 = AL(2*SZ_CT + 4096);     // cT1,cT2 -> e3(f32)
  const size_t oR4 = AL(SZ_F32);             // res f32
  const size_t oR5 = AL((size_t)2*64*8*64*64*2);  // c_sT
  const size_t oR6 = AL((size_t)2*64*4*80*96*2);  // c_cT
  const size_t oWcp1  = AL((size_t)1024*512*2);
  const size_t oWcp2  = AL((size_t)1024*512*2);
  const size_t oWskv1 = AL((size_t)1024*512*2);
  const size_t oWskv2 = AL((size_t)1024*512*2);
  const size_t oWckv1 = AL((size_t)640*320*2);
  const size_t oWckv2 = AL((size_t)640*320*2);
  const size_t oWres  = AL((size_t)512*1024*2);
  const size_t oWce1  = AL((size_t)512*1024*2);
  const size_t oWce3  = AL((size_t)512*512*2);
  const size_t oWdw   = AL((size_t)9*512*2);
  const size_t oST    = AL(16384);
  (void)ws_size; (void)in_sizes; (void)n_in; (void)out_size;

  u16* t1    = (u16*)(ws + oR0);
  u16* t2    = (u16*)(ws + oR0 + SZ_T);
  u16* merge = (u16*)(ws + oR0);
  u16* apre1 = (u16*)(ws + oR1);
  u16* apre2 = (u16*)(ws + oR1 + SZ_APRE);
  u16* kv1   = apre1;
  u16* kv2   = apre2;
  u16* ckv1  = (u16*)(ws + oR1);
  u16* ckv2  = (u16*)(ws + oR1 + SZ_CKV);
  u16* s1    = (u16*)(ws + oR2);
  u16* s2    = (u16*)(ws + oR2 + SZ_T);
  u16* e1    = s1;
  u16* d1    = s2;
  u16* cT1   = (u16*)(ws + oR3);
  u16* cT2   = (u16*)(ws + oR3 + SZ_CT);
  u16* slack = (u16*)(ws + oR3 + 2*SZ_CT);
  float* e3  = (float*)(ws + oR3);
  float* resb = (float*)(ws + oR4);
  u16* csT   = (u16*)(ws + oR5);
  u16* ccT   = (u16*)(ws + oR6);
  u16* wcp1  = (u16*)(ws + oWcp1);
  u16* wcp2  = (u16*)(ws + oWcp2);
  u16* wskv1 = (u16*)(ws + oWskv1);
  u16* wskv2 = (u16*)(ws + oWskv2);
  u16* wckv1 = (u16*)(ws + oWckv1);
  u16* wckv2 = (u16*)(ws + oWckv2);
  u16* wres  = (u16*)(ws + oWres);
  u16* wce1  = (u16*)(ws + oWce1);
  u16* wce3  = (u16*)(ws + oWce3);
  u16* wdw   = (u16*)(ws + oWdw);
  float* st  = (float*)(ws + oST);

  hipMemsetAsync(st, 0, 16384, stream);
  pad_zero<<<1033,256,0,stream>>>(cT1, cT2, slack);
  pack_plain<<<2048,256,0,stream>>>(cp1_w, wcp1, 524288);
  pack_plain<<<2048,256,0,stream>>>(cp2_w, wcp2, 524288);
  pack_plain<<<2048,256,0,stream>>>(skv1w, wskv1, 524288);
  pack_plain<<<2048,256,0,stream>>>(skv2w, wskv2, 524288);
  pack_ckv_k<<<800,256,0,stream>>>(ckv1w, wckv1);
  pack_ckv_k<<<800,256,0,stream>>>(ckv2w, wckv2);
  pack_plain<<<2048,256,0,stream>>>(resw, wres, 524288);
  pack_plain<<<2048,256,0,stream>>>(ce1w, wce1, 524288);
  pack_plain<<<1024,256,0,stream>>>(ce3w, wce3, 262144);
  pack_dw<<<18,256,0,stream>>>(dww, wdw);

  transpose_k<<<dim3(10,16,64),256,0,stream>>>(x1, t1);
  transpose_k<<<dim3(10,16,64),256,0,stream>>>(x2, t2);

  gemm_k<0,1><<<dim3(150,8),256,0,stream>>>(t1,512, wcp1,512, apre1,nullptr,1024, cp1_b, 512);
  gemm_k<0,1><<<dim3(150,8),256,0,stream>>>(t2,512, wcp2,512, apre2,nullptr,1024, cp2_b, 512);

  ln_kernel<<<19200,256,0,stream>>>(apre1, ln1_w, ln1_b, s1, cT1);
  ln_kernel<<<19200,256,0,stream>>>(apre2, ln2_w, ln2_b, s2, cT2);

  gemm_k<0,0><<<dim3(150,8),256,0,stream>>>(s1,512, wskv1,512, kv1,nullptr,1024, nullptr, 512);
  gemm_k<0,0><<<dim3(150,8),256,0,stream>>>(s2,512, wskv2,512, kv2,nullptr,1024, nullptr, 512);

  ctx_kernel<64,64,64><<<dim3(8,64,2),256,0,stream>>>(kv1, kv2, csT, 300, 1024, 512, 0.125f);

  gemm_k<0,0><<<dim3(256,5),256,0,stream>>>(cT1,320, wckv1,320, ckv1,nullptr,640, nullptr, 320);
  gemm_k<0,0><<<dim3(256,5),256,0,stream>>>(cT2,320, wckv2,320, ckv2,nullptr,640, nullptr, 320);

  ctx_kernel<80,75,96><<<dim3(4,64,2),256,0,stream>>>(ckv1, ckv2, ccT, 512, 640, 320, 0.115470054f);

  sp_out_kernel<<<dim3(8,64),256,0,stream>>>(s1, s2, csT, merge);
  ch_out_kernel<<<dim3(4,4,64),256,0,stream>>>(cT1, cT2, ccT, merge);

  gemm_k<1,0><<<dim3(150,4),256,0,stream>>>(merge,1024, wres,1024, nullptr,resb,512, nullptr, 1024);
  gemm_k<0,1><<<dim3(150,4),256,0,stream>>>(merge,1024, wce1,1024, e1,nullptr,512, ce1b, 1024);

  dw_kernel<<<4800,256,0,stream>>>(e1, wdw, dwb, d1);

  gemm_k<1,1><<<dim3(150,4),256,0,stream>>>(d1,512, wce3,512, nullptr,e3,512, ce3b, 512);

  stats_e<<<150,256,0,stream>>>(e3, st);
  fin_e<<<1,512,0,stream>>>(st, bnew, bneb);
  stats_o<<<150,256,0,stream>>>(resb, e3, st);
  fin_o<<<1,512,0,stream>>>(st, bnow, bnob);
  final_kernel<<<dim3(5,8,64),256,0,stream>>>(resb, e3, st, out);
}

// Round 4
// 657.922 us; speedup vs baseline: 1.3650x; 1.1648x over previous
//
#include <hip/hip_runtime.h>

typedef unsigned short u16;
typedef __attribute__((ext_vector_type(8))) short bh8;
typedef __attribute__((ext_vector_type(4))) float f4;

__device__ __forceinline__ u16 f2b(float f){
  unsigned int u = __float_as_uint(f);
  u += 0x7fffu + ((u >> 16) & 1u);
  return (u16)(u >> 16);
}
__device__ __forceinline__ float b2f(u16 h){
  return __uint_as_float(((unsigned int)h) << 16);
}
__device__ __forceinline__ void gl16(const u16* g, u16* l){
  __builtin_amdgcn_global_load_lds((const __attribute__((address_space(1))) void*)g,
                                   (__attribute__((address_space(3))) void*)l, 16, 0, 0);
}

// ---------------- packing ----------------
__global__ void pack_plain(const float* __restrict__ src, u16* __restrict__ dst, int count){
  int i = blockIdx.x*256 + threadIdx.x;
  if (i < count) dst[i] = f2b(src[i]);
}
// c_kv_w (600,300) -> padded [640][320]: n = t*320+h*80+dd, k = kh*80+kd
__global__ void pack_ckv_k(const float* __restrict__ src, u16* __restrict__ dst){
  int i = blockIdx.x*256 + threadIdx.x; // 640*320
  int nn = i / 320, kk = i - (i/320)*320;
  int t_ = (nn >= 320) ? 1 : 0;
  int rem = nn - t_*320;
  int hh = rem / 80, dd = rem - hh*80;
  int kh = kk / 80, kd = kk - kh*80;
  float v = 0.f;
  if (dd < 75 && kd < 75)
    v = src[(size_t)(t_*300 + hh*75 + dd)*300 + (kh*75 + kd)];
  dst[i] = f2b(v);
}
// dw weight (512,1,3,3) -> dwt[9][512] bf16 (tap-major, coalesced per-tap loads)
__global__ void pack_dw(const float* __restrict__ src, u16* __restrict__ dst){
  int i = blockIdx.x*256 + threadIdx.x; // 4608
  if (i < 4608){
    int t = i >> 9, c = i & 511;
    dst[i] = f2b(src[c*9 + t]);
  }
}
// zero the 4KiB slack after cT2 that ch_out's tail k-chunk over-reads (x0, but must be finite)
__global__ void pad_zero(u16* __restrict__ slack){
  const int j = blockIdx.x*256 + threadIdx.x;
  if (j < 2048) slack[j] = 0;
}

// ---------------- x (B,C,H,W) f32 -> t (B,N,C) bf16 ----------------
__global__ __launch_bounds__(256)
void transpose_k(const float* __restrict__ x, u16* __restrict__ t)
{
  __shared__ float tile[32][33];
  const int n0 = blockIdx.x * 32, c0 = blockIdx.y * 32, b = blockIdx.z;
  const int ln = threadIdx.x & 31, lr = threadIdx.x >> 5;
  #pragma unroll
  for (int q = 0; q < 4; q++) {
    const int c = c0 + lr + q*8, n = n0 + ln;
    tile[lr + q*8][ln] = (n < 300) ? x[((long)b*512 + c)*300 + n] : 0.f;
  }
  __syncthreads();
  #pragma unroll
  for (int q = 0; q < 4; q++) {
    const int n = n0 + lr + q*8;
    if (n < 300) t[((long)b*300 + n)*512 + c0 + ln] = f2b(tile[ln][lr + q*8]);
  }
}

// ---------------- generic 128x128 MFMA GEMM: C = A(M,K) @ Bw(N,K)^T ----------------
template<int OUTF, int HASB>
__global__ __launch_bounds__(256)
void gemm_k(const u16* __restrict__ A, int lda,
            const u16* __restrict__ Bw, int ldb,
            u16* __restrict__ Cb, float* __restrict__ Cf, int ldc,
            const float* __restrict__ bias, int K)
{
  __shared__ u16 As[128*32];
  __shared__ u16 Bs[128*32];
  const int tid = threadIdx.x;
  const long m0 = (long)blockIdx.x * 128;
  const long n0 = (long)blockIdx.y * 128;
  const int wave = tid >> 6, lane = tid & 63;
  const int l15 = lane & 15, lg = lane >> 4;
  const int wr = (wave >> 1) * 64, wc = (wave & 1) * 64;
  const int arow = tid >> 2, aseg = (tid & 3) * 8;
  const u16* Ag0 = A + (m0 + arow) * (long)lda + aseg;
  const u16* Ag1 = Ag0 + 64L * lda;
  const u16* Bg0 = Bw + (n0 + arow) * (long)ldb + aseg;
  const u16* Bg1 = Bg0 + 64L * ldb;
  u16* lA0 = &As[tid * 8];
  u16* lA1 = &As[2048 + tid * 8];
  u16* lB0 = &Bs[tid * 8];
  u16* lB1 = &Bs[2048 + tid * 8];
  f4 acc[4][4] = {};
  for (int kt = 0; kt < K; kt += 32) {
    gl16(Ag0 + kt, lA0);
    gl16(Ag1 + kt, lA1);
    gl16(Bg0 + kt, lB0);
    gl16(Bg1 + kt, lB1);
    __syncthreads();
    bh8 af[4], bf[4];
    #pragma unroll
    for (int mi = 0; mi < 4; mi++)
      af[mi] = *(const bh8*)&As[(wr + mi*16 + l15)*32 + lg*8];
    #pragma unroll
    for (int ni = 0; ni < 4; ni++)
      bf[ni] = *(const bh8*)&Bs[(wc + ni*16 + l15)*32 + lg*8];
    #pragma unroll
    for (int mi = 0; mi < 4; mi++)
      #pragma unroll
      for (int ni = 0; ni < 4; ni++)
        acc[mi][ni] = __builtin_amdgcn_mfma_f32_16x16x32_bf16(af[mi], bf[ni], acc[mi][ni], 0, 0, 0);
    __syncthreads();
  }
  #pragma unroll
  for (int ni = 0; ni < 4; ni++) {
    const long cn = n0 + wc + ni*16 + l15;
    const float bv = HASB ? bias[cn] : 0.0f;
    #pragma unroll
    for (int mi = 0; mi < 4; mi++) {
      #pragma unroll
      for (int r = 0; r < 4; r++) {
        const long cm = m0 + wr + mi*16 + lg*4 + r;
        const float v = acc[mi][ni][r] + bv;
        if (OUTF) Cf[cm * ldc + cn] = v;
        else      Cb[cm * ldc + cn] = f2b(v);
      }
    }
  }
}

// ---------------- LayerNorm(1024) + relu; split into s (B,N,512) coalesced and
// cT (B,512,320pad) via LDS block-transpose (coalesced 16B chunks along nn) ----------------
__global__ __launch_bounds__(256)
void ln_kernel(const u16* __restrict__ apre, const float* __restrict__ lw, const float* __restrict__ lb,
               u16* __restrict__ s, u16* __restrict__ cT)
{
  __shared__ u16 tile[40][520];   // pitch 520: rows 16B-aligned
  const int bh = blockIdx.x;      // b*4 + h
  const int b = bh >> 2, h = bh & 3;
  const int z = blockIdx.y;
  const int dd0 = z ? 40 : 0;
  const int ndd = z ? 35 : 40;    // z=0: dd 0..39 (segs 0..4), z=1: dd 40..74 (+pad 75..79, segs 5..9)
  const int segbase = z ? 5 : 0;
  const int tid = threadIdx.x, w = tid >> 6, lane = tid & 63;
  const int r0 = b*300 + h*75 + dd0;
  for (int dl = w; dl < ndd; dl += 4){
    const int r = r0 + dl;
    const u16* row = apre + (size_t)r*1024 + lane*8;
    const bh8 vc = *(const bh8*)row;          // c-half cols lane*8..+7
    const bh8 vs = *(const bh8*)(row + 512);  // s-half
    float fc[8], fs[8];
    float sm = 0.f, sq = 0.f;
    #pragma unroll
    for (int j = 0; j < 8; j++){
      fc[j] = b2f((u16)vc[j]); fs[j] = b2f((u16)vs[j]);
      sm += fc[j] + fs[j];
      sq += fc[j]*fc[j] + fs[j]*fs[j];
    }
    #pragma unroll
    for (int o = 32; o; o >>= 1){ sm += __shfl_xor(sm, o); sq += __shfl_xor(sq, o); }
    const float mean = sm * (1.f/1024.f);
    const float rstd = rsqrtf(sq*(1.f/1024.f) - mean*mean + 1e-5f);
    bh8 oc, os;
    #pragma unroll
    for (int j = 0; j < 8; j++){
      const int c = lane*8 + j;
      const float y1 = (fc[j]-mean)*rstd*lw[c] + lb[c];
      oc[j] = (short)f2b(fmaxf(y1, 0.f));
      const float y2 = (fs[j]-mean)*rstd*lw[512+c] + lb[512+c];
      os[j] = (short)f2b(fmaxf(y2, 0.f));
    }
    *(bh8*)&tile[dl][lane*8] = oc;
    *(bh8*)&s[(size_t)r*512 + lane*8] = os;
  }
  __syncthreads();
  for (int i = tid; i < 2560; i += 256){
    const int c = i / 5, sg = i - (i/5)*5;
    const int seg = segbase + sg;
    bh8 ov;
    #pragma unroll
    for (int j = 0; j < 8; j++){
      const int dl = seg*8 + j - dd0;
      ov[j] = (short)((dl >= 0 && dl < ndd) ? tile[dl][c] : (u16)0);
    }
    *(bh8*)&cT[((size_t)b*512 + c)*320 + h*80 + seg*8] = ov;
  }
}

// ---------------- attn ctx: out[e][d] = softmax_d( scale * sum_n k[n,d] v[n,e] ), stored transposed ----------------
template<int D, int DREAL, int OS>
__global__ __launch_bounds__(256)
void ctx_kernel(const u16* __restrict__ kva, const u16* __restrict__ kvb,
                u16* __restrict__ outp, int K, int RS, int VOFF, float scale)
{
  constexpr int NT = D/16, MT = D/16, MTL = (MT+3)/4, SEG = D/8;
  __shared__ u16 vT[D][40];
  __shared__ u16 kT[D][40];
  const int h = blockIdx.x, b = blockIdx.y, iq = blockIdx.z;
  const int Hn = gridDim.x;
  const u16* base = (iq ? kvb : kva) + (size_t)b*K*RS + h*D;
  u16* out = outp + (((size_t)iq*64 + b)*Hn + h)*(size_t)(D*OS);
  const int tid = threadIdx.x, w = tid >> 6, lane = tid & 63, l15 = lane & 15, lg = lane >> 4;
  f4 acc[MTL][NT] = {};
  for (int k0 = 0; k0 < K; k0 += 32) {
    __syncthreads();
    for (int sI = tid; sI < 32*SEG; sI += 256) {
      const int nn = sI / SEG, dseg = sI - (sI/SEG)*SEG;
      bh8 kk = {}, vv = {};
      const int krow = k0 + nn;
      if (krow < K) {
        const u16* p = base + (size_t)krow*RS + dseg*8;
        kk = *(const bh8*)p;
        vv = *(const bh8*)(p + VOFF);
      }
      #pragma unroll
      for (int j = 0; j < 8; j++){
        kT[dseg*8+j][nn] = (u16)kk[j];
        vT[dseg*8+j][nn] = (u16)vv[j];
      }
    }
    __syncthreads();
    #pragma unroll
    for (int ii = 0; ii < MTL; ii++){
      const int mt = w + ii*4;
      if (MT % 4 != 0 && mt >= MT) break;
      const bh8 a = *(const bh8*)&vT[mt*16 + l15][lg*8];
      #pragma unroll
      for (int nt = 0; nt < NT; nt++){
        const bh8 bb = *(const bh8*)&kT[nt*16 + l15][lg*8];
        acc[ii][nt] = __builtin_amdgcn_mfma_f32_16x16x32_bf16(a, bb, acc[ii][nt], 0, 0, 0);
      }
    }
  }
  #pragma unroll
  for (int ii = 0; ii < MTL; ii++){
    const int mt = w + ii*4;
    if (MT % 4 != 0 && mt >= MT) continue;
    #pragma unroll
    for (int r = 0; r < 4; r++){
      const int e = mt*16 + lg*4 + r;
      float xs[NT]; float mx = -1e30f;
      #pragma unroll
      for (int nt = 0; nt < NT; nt++){
        float x = acc[ii][nt][r] * scale;
        if (DREAL != D && (nt*16 + l15) >= DREAL) x = -1e30f;
        xs[nt] = x; mx = fmaxf(mx, x);
      }
      mx = fmaxf(mx, __shfl_xor(mx,1)); mx = fmaxf(mx, __shfl_xor(mx,2));
      mx = fmaxf(mx, __shfl_xor(mx,4)); mx = fmaxf(mx, __shfl_xor(mx,8));
      float smv = 0.f;
      #pragma unroll
      for (int nt = 0; nt < NT; nt++){
        const float p = (xs[nt] > -1e29f) ? __expf(xs[nt]-mx) : 0.f;
        xs[nt] = p; smv += p;
      }
      smv += __shfl_xor(smv,1); smv += __shfl_xor(smv,2);
      smv += __shfl_xor(smv,4); smv += __shfl_xor(smv,8);
      const float inv = 1.f / smv;
      #pragma unroll
      for (int nt = 0; nt < NT; nt++)
        out[(size_t)e*OS + nt*16 + l15] = f2b(xs[nt]*inv);
      if (OS > D) out[(size_t)e*OS + D + l15] = 0;
    }
  }
}

// ---------------- spatial out: merge[:, :512] = q1@c2 + q2@c1 ----------------
__global__ __launch_bounds__(256)
void sp_out_kernel(const u16* __restrict__ s1, const u16* __restrict__ s2,
                   const u16* __restrict__ csT, u16* __restrict__ merge)
{
  const int h = blockIdx.x, b = blockIdx.y;
  const int tid = threadIdx.x, w = tid >> 6, lane = tid & 63, l15 = lane & 15, lg = lane >> 4;
  const u16* c1 = csT + (((size_t)b)*8 + h)*4096;
  const u16* c2 = csT + (((size_t)64 + b)*8 + h)*4096;
  for (int mt = w; mt < 19; mt += 4) {
    const int m = mt*16 + l15;
    const bool mv = (m < 300);
    const u16* q1 = s1 + ((size_t)b*300 + m)*512 + h*64;
    const u16* q2 = s2 + ((size_t)b*300 + m)*512 + h*64;
    f4 acc[4] = {};
    #pragma unroll
    for (int kc = 0; kc < 2; kc++){
      bh8 a1 = {}, a2 = {};
      if (mv){ a1 = *(const bh8*)(q1 + kc*32 + lg*8); a2 = *(const bh8*)(q2 + kc*32 + lg*8); }
      #pragma unroll
      for (int nt = 0; nt < 4; nt++){
        const bh8 b2v = *(const bh8*)&c2[(size_t)(nt*16+l15)*64 + kc*32 + lg*8];
        acc[nt] = __builtin_amdgcn_mfma_f32_16x16x32_bf16(a1, b2v, acc[nt], 0, 0, 0);
        const bh8 b1v = *(const bh8*)&c1[(size_t)(nt*16+l15)*64 + kc*32 + lg*8];
        acc[nt] = __builtin_amdgcn_mfma_f32_16x16x32_bf16(a2, b1v, acc[nt], 0, 0, 0);
      }
    }
    #pragma unroll
    for (int nt = 0; nt < 4; nt++)
      #pragma unroll
      for (int r = 0; r < 4; r++){
        const int mm = mt*16 + lg*4 + r;
        if (mm < 300)
          merge[((size_t)b*300 + mm)*1024 + h*64 + nt*16 + l15] = f2b(acc[nt][r]);
      }
  }
}

// ---------------- channel out (transposed): merge[:, 512:] = (q1c@c2c + q2c@c1c)^T ----------------
__global__ __launch_bounds__(256)
void ch_out_kernel(const u16* __restrict__ cT1, const u16* __restrict__ cT2,
                   const u16* __restrict__ ccT, u16* __restrict__ merge)
{
  const int cb = blockIdx.x, h = blockIdx.y, b = blockIdx.z;
  const int tid = threadIdx.x, w = tid >> 6, lane = tid & 63, l15 = lane & 15, lg = lane >> 4;
  const int chbase = cb*128 + w*32;
  f4 acc[5][2] = {};
  #pragma unroll
  for (int oi = 0; oi < 2; oi++){
    const u16* Am = ccT + (((size_t)((oi==0)?1:0)*64 + b)*4 + h)*(size_t)(80*96);
    const u16* qb = (oi==0) ? cT1 : cT2;
    #pragma unroll
    for (int kc = 0; kc < 3; kc++){
      bh8 bf[2];
      #pragma unroll
      for (int nf = 0; nf < 2; nf++){
        const int ch = chbase + nf*16 + l15;
        bf[nf] = *(const bh8*)&qb[((size_t)b*512 + ch)*320 + h*80 + kc*32 + lg*8];
      }
      #pragma unroll
      for (int mt = 0; mt < 5; mt++){
        const bh8 a = *(const bh8*)&Am[(size_t)(mt*16+l15)*96 + kc*32 + lg*8];
        #pragma unroll
        for (int nf = 0; nf < 2; nf++)
          acc[mt][nf] = __builtin_amdgcn_mfma_f32_16x16x32_bf16(a, bf[nf], acc[mt][nf], 0, 0, 0);
      }
    }
  }
  #pragma unroll
  for (int mt = 0; mt < 5; mt++)
    #pragma unroll
    for (int nf = 0; nf < 2; nf++)
      #pragma unroll
      for (int r = 0; r < 4; r++){
        const int e = mt*16 + lg*4 + r;
        if (e < 75)
          merge[((size_t)b*300 + h*75 + e)*1024 + 512 + chbase + nf*16 + l15] = f2b(acc[mt][nf][r]);
      }
}

// ---------------- depthwise 3x3 + bias + leaky(0.01), channels-last, tap-major bf16 weights ----------------
__global__ __launch_bounds__(256)
void dw_kernel(const u16* __restrict__ e1, const u16* __restrict__ dwt,
               const float* __restrict__ bias, u16* __restrict__ d1)
{
  const int idx = blockIdx.x*256 + threadIdx.x;
  const int cg = idx & 63;
  const int sp = (idx >> 6) % 300;
  const int b  = idx / (64*300);
  const int c0 = cg*8;
  const int hh = sp / 15, ww = sp - hh*15;
  float acc[8];
  {
    const float4 b0 = *(const float4*)&bias[c0];
    const float4 b1 = *(const float4*)&bias[c0+4];
    acc[0]=b0.x; acc[1]=b0.y; acc[2]=b0.z; acc[3]=b0.w;
    acc[4]=b1.x; acc[5]=b1.y; acc[6]=b1.z; acc[7]=b1.w;
  }
  #pragma unroll
  for (int dy = -1; dy <= 1; dy++){
    const int h2 = hh + dy; if (h2 < 0 || h2 >= 20) continue;
    #pragma unroll
    for (int dx = -1; dx <= 1; dx++){
      const int w2 = ww + dx; if (w2 < 0 || w2 >= 15) continue;
      const bh8 vv = *(const bh8*)&e1[((size_t)b*300 + h2*15 + w2)*512 + c0];
      const int t = (dy+1)*3 + (dx+1);
      const bh8 wv = *(const bh8*)&dwt[t*512 + c0];
      #pragma unroll
      for (int j = 0; j < 8; j++)
        acc[j] += b2f((u16)vv[j]) * b2f((u16)wv[j]);
    }
  }
  bh8 ov;
  #pragma unroll
  for (int j = 0; j < 8; j++){
    float y = acc[j];
    y = (y >= 0.f) ? y : 0.01f*y;
    ov[j] = (short)f2b(y);
  }
  *(bh8*)&d1[((size_t)b*300 + sp)*512 + c0] = ov;
}

// ---------------- BN stats / finalize / final write ----------------
__global__ __launch_bounds__(256)
void stats_e(const float* __restrict__ e3, float* __restrict__ st){
  const int tid = threadIdx.x;
  const int c0 = tid*2;
  const size_t r0 = (size_t)blockIdx.x * 128;
  float s0=0,s1=0,q0=0,q1=0;
  for (int rr = 0; rr < 128; rr++){
    const float2 v = *(const float2*)&e3[(r0+rr)*512 + c0];
    s0 += v.x; s1 += v.y; q0 += v.x*v.x; q1 += v.y*v.y;
  }
  atomicAdd(&st[c0], s0); atomicAdd(&st[c0+1], s1);
  atomicAdd(&st[512+c0], q0); atomicAdd(&st[512+c0+1], q1);
}
__global__ void fin_e(float* st, const float* __restrict__ w, const float* __restrict__ b){
  const int c = threadIdx.x;
  const float m = st[c] * (1.f/19200.f);
  const float v = st[512+c] * (1.f/19200.f) - m*m;
  const float a = w[c] * rsqrtf(v + 1e-5f);
  st[1024+c] = a; st[1536+c] = b[c] - m*a;
}
__global__ __launch_bounds__(256)
void stats_o(const float* __restrict__ res, const float* __restrict__ e3, float* __restrict__ st){
  const int tid = threadIdx.x;
  const int c0 = tid*2;
  const float a0 = st[1024+c0], b0v = st[1536+c0];
  const float a1 = st[1024+c0+1], b1v = st[1536+c0+1];
  const size_t r0 = (size_t)blockIdx.x * 128;
  float s0=0,s1=0,q0=0,q1=0;
  for (int rr = 0; rr < 128; rr++){
    const size_t o2 = (r0+rr)*512 + c0;
    const float2 rv = *(const float2*)&res[o2];
    const float2 ev = *(const float2*)&e3[o2];
    const float v0 = rv.x + ev.x*a0 + b0v;
    const float v1 = rv.y + ev.y*a1 + b1v;
    s0 += v0; s1 += v1; q0 += v0*v0; q1 += v1*v1;
  }
  atomicAdd(&st[2048+c0], s0); atomicAdd(&st[2048+c0+1], s1);
  atomicAdd(&st[2560+c0], q0); atomicAdd(&st[2560+c0+1], q1);
}
__global__ void fin_o(float* st, const float* __restrict__ w, const float* __restrict__ b){
  const int c = threadIdx.x;
  const float m = st[2048+c] * (1.f/19200.f);
  const float v = st[2560+c] * (1.f/19200.f) - m*m;
  const float a = w[c] * rsqrtf(v + 1e-5f);
  st[3072+c] = a; st[3584+c] = b[c] - m*a;
}
__global__ __launch_bounds__(256)
void final_kernel(const float* __restrict__ res, const float* __restrict__ e3,
                  const float* __restrict__ st, float* __restrict__ outp)
{
  __shared__ float tile[64][65];
  const int spt = blockIdx.x, cht = blockIdx.y, b = blockIdx.z;
  const int tid = threadIdx.x;
  const int sp0 = spt*64, ch0 = cht*64;
  for (int idx = tid; idx < 4096; idx += 256){
    const int cl = idx & 63, sl = idx >> 6;
    const int sp = sp0 + sl;
    float v = 0.f;
    if (sp < 300){
      const size_t off = ((size_t)b*300 + sp)*512 + ch0 + cl;
      const int c = ch0 + cl;
      const float e = e3[off]*st[1024+c] + st[1536+c];
      v = (res[off] + e)*st[3072+c] + st[3584+c];
    }
    tile[sl][cl] = v;
  }
  __syncthreads();
  for (int idx = tid; idx < 4096; idx += 256){
    const int sl = idx & 63, cl = idx >> 6;
    const int sp = sp0 + sl;
    if (sp < 300)
      outp[((size_t)b*512 + ch0 + cl)*300 + sp] = tile[sl][cl];
  }
}

// ---------------- host ----------------
extern "C" void kernel_launch(void* const* d_in, const int* in_sizes, int n_in,
                              void* d_out, int out_size, void* d_ws, size_t ws_size,
                              hipStream_t stream)
{
  const float* x1    = (const float*)d_in[0];
  const float* x2    = (const float*)d_in[1];
  const float* cp1_w = (const float*)d_in[2];
  const float* cp1_b = (const float*)d_in[3];
  const float* ln1_w = (const float*)d_in[4];
  const float* ln1_b = (const float*)d_in[5];
  const float* cp2_w = (const float*)d_in[6];
  const float* cp2_b = (const float*)d_in[7];
  const float* ln2_w = (const float*)d_in[8];
  const float* ln2_b = (const float*)d_in[9];
  const float* skv1w = (const float*)d_in[10];
  const float* skv2w = (const float*)d_in[11];
  const float* ckv1w = (const float*)d_in[12];
  const float* ckv2w = (const float*)d_in[13];
  const float* resw  = (const float*)d_in[14];
  const float* ce1w  = (const float*)d_in[15];
  const float* ce1b  = (const float*)d_in[16];
  const float* dww   = (const float*)d_in[17];
  const float* dwb   = (const float*)d_in[18];
  const float* ce3w  = (const float*)d_in[19];
  const float* ce3b  = (const float*)d_in[20];
  const float* bnew  = (const float*)d_in[21];
  const float* bneb  = (const float*)d_in[22];
  const float* bnow  = (const float*)d_in[23];
  const float* bnob  = (const float*)d_in[24];
  float* out = (float*)d_out;
  char* ws = (char*)d_ws;

  const size_t SZ_T    = (size_t)19200*512*2;
  const size_t SZ_APRE = (size_t)19200*1024*2;
  const size_t SZ_CKV  = (size_t)32768*640*2;
  const size_t SZ_CT   = (size_t)64*512*320*2;
  const size_t SZ_F32  = (size_t)19200*512*4;

  size_t off = 0;
  auto AL = [&](size_t sz){ size_t r = off; off += (sz + 255) & ~(size_t)255; return r; };
  const size_t oR0 = AL(2*SZ_T);             // t1,t2 -> merge
  const size_t oR1 = AL(2*SZ_CKV);           // apre1,apre2 -> kv1,kv2 -> ckv1,ckv2
  const size_t oR2 = AL(2*SZ_T);             // s1,s2 -> e1,d1
  const size_t oR3 = AL(2*SZ_CT + 4096);     // cT1,cT2 -> e3(f32)
  const size_t oR4 = AL(SZ_F32);             // res f32
  const size_t oR5 = AL((size_t)2*64*8*64*64*2);  // c_sT
  const size_t oR6 = AL((size_t)2*64*4*80*96*2);  // c_cT
  const size_t oWcp1  = AL((size_t)1024*512*2);
  const size_t oWcp2  = AL((size_t)1024*512*2);
  const size_t oWskv1 = AL((size_t)1024*512*2);
  const size_t oWskv2 = AL((size_t)1024*512*2);
  const size_t oWckv1 = AL((size_t)640*320*2);
  const size_t oWckv2 = AL((size_t)640*320*2);
  const size_t oWres  = AL((size_t)512*1024*2);
  const size_t oWce1  = AL((size_t)512*1024*2);
  const size_t oWce3  = AL((size_t)512*512*2);
  const size_t oWdw   = AL((size_t)9*512*2);
  const size_t oST    = AL(16384);
  (void)ws_size; (void)in_sizes; (void)n_in; (void)out_size;

  u16* t1    = (u16*)(ws + oR0);
  u16* t2    = (u16*)(ws + oR0 + SZ_T);
  u16* merge = (u16*)(ws + oR0);
  u16* apre1 = (u16*)(ws + oR1);
  u16* apre2 = (u16*)(ws + oR1 + SZ_APRE);
  u16* kv1   = apre1;
  u16* kv2   = apre2;
  u16* ckv1  = (u16*)(ws + oR1);
  u16* ckv2  = (u16*)(ws + oR1 + SZ_CKV);
  u16* s1    = (u16*)(ws + oR2);
  u16* s2    = (u16*)(ws + oR2 + SZ_T);
  u16* e1    = s1;
  u16* d1    = s2;
  u16* cT1   = (u16*)(ws + oR3);
  u16* cT2   = (u16*)(ws + oR3 + SZ_CT);
  u16* slack = (u16*)(ws + oR3 + 2*SZ_CT);
  float* e3  = (float*)(ws + oR3);
  float* resb = (float*)(ws + oR4);
  u16* csT   = (u16*)(ws + oR5);
  u16* ccT   = (u16*)(ws + oR6);
  u16* wcp1  = (u16*)(ws + oWcp1);
  u16* wcp2  = (u16*)(ws + oWcp2);
  u16* wskv1 = (u16*)(ws + oWskv1);
  u16* wskv2 = (u16*)(ws + oWskv2);
  u16* wckv1 = (u16*)(ws + oWckv1);
  u16* wckv2 = (u16*)(ws + oWckv2);
  u16* wres  = (u16*)(ws + oWres);
  u16* wce1  = (u16*)(ws + oWce1);
  u16* wce3  = (u16*)(ws + oWce3);
  u16* wdw   = (u16*)(ws + oWdw);
  float* st  = (float*)(ws + oST);

  hipMemsetAsync(st, 0, 16384, stream);
  pad_zero<<<8,256,0,stream>>>(slack);
  pack_plain<<<2048,256,0,stream>>>(cp1_w, wcp1, 524288);
  pack_plain<<<2048,256,0,stream>>>(cp2_w, wcp2, 524288);
  pack_plain<<<2048,256,0,stream>>>(skv1w, wskv1, 524288);
  pack_plain<<<2048,256,0,stream>>>(skv2w, wskv2, 524288);
  pack_ckv_k<<<800,256,0,stream>>>(ckv1w, wckv1);
  pack_ckv_k<<<800,256,0,stream>>>(ckv2w, wckv2);
  pack_plain<<<2048,256,0,stream>>>(resw, wres, 524288);
  pack_plain<<<2048,256,0,stream>>>(ce1w, wce1, 524288);
  pack_plain<<<1024,256,0,stream>>>(ce3w, wce3, 262144);
  pack_dw<<<18,256,0,stream>>>(dww, wdw);

  transpose_k<<<dim3(10,16,64),256,0,stream>>>(x1, t1);
  transpose_k<<<dim3(10,16,64),256,0,stream>>>(x2, t2);

  gemm_k<0,1><<<dim3(150,8),256,0,stream>>>(t1,512, wcp1,512, apre1,nullptr,1024, cp1_b, 512);
  gemm_k<0,1><<<dim3(150,8),256,0,stream>>>(t2,512, wcp2,512, apre2,nullptr,1024, cp2_b, 512);

  ln_kernel<<<dim3(256,2),256,0,stream>>>(apre1, ln1_w, ln1_b, s1, cT1);
  ln_kernel<<<dim3(256,2),256,0,stream>>>(apre2, ln2_w, ln2_b, s2, cT2);

  gemm_k<0,0><<<dim3(150,8),256,0,stream>>>(s1,512, wskv1,512, kv1,nullptr,1024, nullptr, 512);
  gemm_k<0,0><<<dim3(150,8),256,0,stream>>>(s2,512, wskv2,512, kv2,nullptr,1024, nullptr, 512);

  ctx_kernel<64,64,64><<<dim3(8,64,2),256,0,stream>>>(kv1, kv2, csT, 300, 1024, 512, 0.125f);

  gemm_k<0,0><<<dim3(256,5),256,0,stream>>>(cT1,320, wckv1,320, ckv1,nullptr,640, nullptr, 320);
  gemm_k<0,0><<<dim3(256,5),256,0,stream>>>(cT2,320, wckv2,320, ckv2,nullptr,640, nullptr, 320);

  ctx_kernel<80,75,96><<<dim3(4,64,2),256,0,stream>>>(ckv1, ckv2, ccT, 512, 640, 320, 0.115470054f);

  sp_out_kernel<<<dim3(8,64),256,0,stream>>>(s1, s2, csT, merge);
  ch_out_kernel<<<dim3(4,4,64),256,0,stream>>>(cT1, cT2, ccT, merge);

  gemm_k<1,0><<<dim3(150,4),256,0,stream>>>(merge,1024, wres,1024, nullptr,resb,512, nullptr, 1024);
  gemm_k<0,1><<<dim3(150,4),256,0,stream>>>(merge,1024, wce1,1024, e1,nullptr,512, ce1b, 1024);

  dw_kernel<<<4800,256,0,stream>>>(e1, wdw, dwb, d1);

  gemm_k<1,1><<<dim3(150,4),256,0,stream>>>(d1,512, wce3,512, nullptr,e3,512, ce3b, 512);

  stats_e<<<150,256,0,stream>>>(e3, st);
  fin_e<<<1,512,0,stream>>>(st, bnew, bneb);
  stats_o<<<150,256,0,stream>>>(resb, e3, st);
  fin_o<<<1,512,0,stream>>>(st, bnow, bnob);
  final_kernel<<<dim3(5,8,64),256,0,stream>>>(resb, e3, st, out);
}

// Round 5
// 629.200 us; speedup vs baseline: 1.4273x; 1.0456x over previous
//
#include <hip/hip_runtime.h>

typedef unsigned short u16;
typedef __attribute__((ext_vector_type(8))) short bh8;
typedef __attribute__((ext_vector_type(4))) float f4;

__device__ __forceinline__ u16 f2b(float f){
  unsigned int u = __float_as_uint(f);
  u += 0x7fffu + ((u >> 16) & 1u);
  return (u16)(u >> 16);
}
__device__ __forceinline__ float b2f(u16 h){
  return __uint_as_float(((unsigned int)h) << 16);
}
__device__ __forceinline__ void gl16(const u16* g, u16* l){
  __builtin_amdgcn_global_load_lds((const __attribute__((address_space(1))) void*)g,
                                   (__attribute__((address_space(3))) void*)l, 16, 0, 0);
}

// ---------------- packing ----------------
__global__ void pack_plain(const float* __restrict__ src, u16* __restrict__ dst, int count){
  int i = blockIdx.x*256 + threadIdx.x;
  if (i < count) dst[i] = f2b(src[i]);
}
// c_kv_w (600,300) -> padded [640][320]: n = t*320+h*80+dd, k = kh*80+kd
__global__ void pack_ckv_k(const float* __restrict__ src, u16* __restrict__ dst){
  int i = blockIdx.x*256 + threadIdx.x; // 640*320
  int nn = i / 320, kk = i - (i/320)*320;
  int t_ = (nn >= 320) ? 1 : 0;
  int rem = nn - t_*320;
  int hh = rem / 80, dd = rem - hh*80;
  int kh = kk / 80, kd = kk - kh*80;
  float v = 0.f;
  if (dd < 75 && kd < 75)
    v = src[(size_t)(t_*300 + hh*75 + dd)*300 + (kh*75 + kd)];
  dst[i] = f2b(v);
}
// dw weight (512,1,3,3) -> dwt[9][512] bf16 (tap-major, coalesced per-tap loads)
__global__ void pack_dw(const float* __restrict__ src, u16* __restrict__ dst){
  int i = blockIdx.x*256 + threadIdx.x; // 4608
  if (i < 4608){
    int t = i >> 9, c = i & 511;
    dst[i] = f2b(src[c*9 + t]);
  }
}
// zero the 4KiB slack after cT2 that ch_out's tail k-chunk over-reads (x0, but must be finite)
__global__ void pad_zero(u16* __restrict__ slack){
  const int j = blockIdx.x*256 + threadIdx.x;
  if (j < 2048) slack[j] = 0;
}

// ---------------- x (B,C,H,W) f32 -> t (B,N,C) bf16 ----------------
__global__ __launch_bounds__(256)
void transpose_k(const float* __restrict__ x, u16* __restrict__ t)
{
  __shared__ float tile[32][33];
  const int n0 = blockIdx.x * 32, c0 = blockIdx.y * 32, b = blockIdx.z;
  const int ln = threadIdx.x & 31, lr = threadIdx.x >> 5;
  #pragma unroll
  for (int q = 0; q < 4; q++) {
    const int c = c0 + lr + q*8, n = n0 + ln;
    tile[lr + q*8][ln] = (n < 300) ? x[((long)b*512 + c)*300 + n] : 0.f;
  }
  __syncthreads();
  #pragma unroll
  for (int q = 0; q < 4; q++) {
    const int n = n0 + lr + q*8;
    if (n < 300) t[((long)b*300 + n)*512 + c0 + ln] = f2b(tile[ln][lr + q*8]);
  }
}

// ---------------- generic 128x128 MFMA GEMM: C = A(M,K) @ Bw(N,K)^T ----------------
// Double-buffered LDS prefetch (stage t+1 before compute t; ONE barrier per K-step).
// Grid: blockIdx.x = n-tile (fastest, shares A m-tile in L2), blockIdx.y = m-tile.
// OUTF: 0 = bf16 out (+bias if HASB); 1 = f32 out (+bias if HASB);
//       2 = split: n<512 -> f32 (no bias), n>=512 -> bf16 (+bias[cn-512])
template<int OUTF, int HASB>
__global__ __launch_bounds__(256)
void gemm_k(const u16* __restrict__ A, int lda,
            const u16* __restrict__ Bw, int ldb,
            u16* __restrict__ Cb, float* __restrict__ Cf, int ldc,
            const float* __restrict__ bias, int K)
{
  __shared__ u16 As[2][4096];
  __shared__ u16 Bs[2][4096];
  const int tid = threadIdx.x;
  const long n0 = (long)blockIdx.x * 128;
  const long m0 = (long)blockIdx.y * 128;
  const int wave = tid >> 6, lane = tid & 63;
  const int l15 = lane & 15, lg = lane >> 4;
  const int wr = (wave >> 1) * 64, wc = (wave & 1) * 64;
  const int arow = tid >> 2, aseg = (tid & 3) * 8;
  const u16* Ag0 = A + (m0 + arow) * (long)lda + aseg;
  const u16* Ag1 = Ag0 + 64L * lda;
  const u16* Bg0 = Bw + (n0 + arow) * (long)ldb + aseg;
  const u16* Bg1 = Bg0 + 64L * ldb;
  const int to8 = tid * 8;
  f4 acc[4][4] = {};
  const int NT = K >> 5;
  // prologue: stage tile 0 into buf 0
  gl16(Ag0, &As[0][to8]); gl16(Ag1, &As[0][2048 + to8]);
  gl16(Bg0, &Bs[0][to8]); gl16(Bg1, &Bs[0][2048 + to8]);
  __syncthreads();
  int cur = 0;
  for (int t = 0; t < NT - 1; t++) {
    const int kt = (t + 1) << 5;
    const int nb = cur ^ 1;
    gl16(Ag0 + kt, &As[nb][to8]); gl16(Ag1 + kt, &As[nb][2048 + to8]);
    gl16(Bg0 + kt, &Bs[nb][to8]); gl16(Bg1 + kt, &Bs[nb][2048 + to8]);
    bh8 af[4], bf[4];
    #pragma unroll
    for (int mi = 0; mi < 4; mi++)
      af[mi] = *(const bh8*)&As[cur][(wr + mi*16 + l15)*32 + lg*8];
    #pragma unroll
    for (int ni = 0; ni < 4; ni++)
      bf[ni] = *(const bh8*)&Bs[cur][(wc + ni*16 + l15)*32 + lg*8];
    #pragma unroll
    for (int mi = 0; mi < 4; mi++)
      #pragma unroll
      for (int ni = 0; ni < 4; ni++)
        acc[mi][ni] = __builtin_amdgcn_mfma_f32_16x16x32_bf16(af[mi], bf[ni], acc[mi][ni], 0, 0, 0);
    __syncthreads();   // drains prefetch vmcnt + syncs; buf[nb] ready
    cur = nb;
  }
  { // final tile
    bh8 af[4], bf[4];
    #pragma unroll
    for (int mi = 0; mi < 4; mi++)
      af[mi] = *(const bh8*)&As[cur][(wr + mi*16 + l15)*32 + lg*8];
    #pragma unroll
    for (int ni = 0; ni < 4; ni++)
      bf[ni] = *(const bh8*)&Bs[cur][(wc + ni*16 + l15)*32 + lg*8];
    #pragma unroll
    for (int mi = 0; mi < 4; mi++)
      #pragma unroll
      for (int ni = 0; ni < 4; ni++)
        acc[mi][ni] = __builtin_amdgcn_mfma_f32_16x16x32_bf16(af[mi], bf[ni], acc[mi][ni], 0, 0, 0);
  }
  if (OUTF == 2) {
    if (n0 < 512) {
      #pragma unroll
      for (int ni = 0; ni < 4; ni++) {
        const long cn = n0 + wc + ni*16 + l15;
        #pragma unroll
        for (int mi = 0; mi < 4; mi++)
          #pragma unroll
          for (int r = 0; r < 4; r++) {
            const long cm = m0 + wr + mi*16 + lg*4 + r;
            Cf[cm * ldc + cn] = acc[mi][ni][r];
          }
      }
    } else {
      #pragma unroll
      for (int ni = 0; ni < 4; ni++) {
        const long cn = n0 - 512 + wc + ni*16 + l15;
        const float bv = bias[cn];
        #pragma unroll
        for (int mi = 0; mi < 4; mi++)
          #pragma unroll
          for (int r = 0; r < 4; r++) {
            const long cm = m0 + wr + mi*16 + lg*4 + r;
            Cb[cm * ldc + cn] = f2b(acc[mi][ni][r] + bv);
          }
      }
    }
  } else {
    #pragma unroll
    for (int ni = 0; ni < 4; ni++) {
      const long cn = n0 + wc + ni*16 + l15;
      const float bv = HASB ? bias[cn] : 0.0f;
      #pragma unroll
      for (int mi = 0; mi < 4; mi++) {
        #pragma unroll
        for (int r = 0; r < 4; r++) {
          const long cm = m0 + wr + mi*16 + lg*4 + r;
          const float v = acc[mi][ni][r] + bv;
          if (OUTF) Cf[cm * ldc + cn] = v;
          else      Cb[cm * ldc + cn] = f2b(v);
        }
      }
    }
  }
}

// ---------------- LayerNorm(1024) + relu; split into s (B,N,512) coalesced and
// cT (B,512,320pad) via LDS block-transpose (coalesced 16B chunks along nn) ----------------
__global__ __launch_bounds__(256)
void ln_kernel(const u16* __restrict__ apre, const float* __restrict__ lw, const float* __restrict__ lb,
               u16* __restrict__ s, u16* __restrict__ cT)
{
  __shared__ u16 tile[40][520];   // pitch 520: rows 16B-aligned
  const int bh = blockIdx.x;      // b*4 + h
  const int b = bh >> 2, h = bh & 3;
  const int z = blockIdx.y;
  const int dd0 = z ? 40 : 0;
  const int ndd = z ? 35 : 40;    // z=0: dd 0..39 (segs 0..4), z=1: dd 40..74 (+pad 75..79, segs 5..9)
  const int segbase = z ? 5 : 0;
  const int tid = threadIdx.x, w = tid >> 6, lane = tid & 63;
  const int r0 = b*300 + h*75 + dd0;
  for (int dl = w; dl < ndd; dl += 4){
    const int r = r0 + dl;
    const u16* row = apre + (size_t)r*1024 + lane*8;
    const bh8 vc = *(const bh8*)row;          // c-half cols lane*8..+7
    const bh8 vs = *(const bh8*)(row + 512);  // s-half
    float fc[8], fs[8];
    float sm = 0.f, sq = 0.f;
    #pragma unroll
    for (int j = 0; j < 8; j++){
      fc[j] = b2f((u16)vc[j]); fs[j] = b2f((u16)vs[j]);
      sm += fc[j] + fs[j];
      sq += fc[j]*fc[j] + fs[j]*fs[j];
    }
    #pragma unroll
    for (int o = 32; o; o >>= 1){ sm += __shfl_xor(sm, o); sq += __shfl_xor(sq, o); }
    const float mean = sm * (1.f/1024.f);
    const float rstd = rsqrtf(sq*(1.f/1024.f) - mean*mean + 1e-5f);
    bh8 oc, os;
    #pragma unroll
    for (int j = 0; j < 8; j++){
      const int c = lane*8 + j;
      const float y1 = (fc[j]-mean)*rstd*lw[c] + lb[c];
      oc[j] = (short)f2b(fmaxf(y1, 0.f));
      const float y2 = (fs[j]-mean)*rstd*lw[512+c] + lb[512+c];
      os[j] = (short)f2b(fmaxf(y2, 0.f));
    }
    *(bh8*)&tile[dl][lane*8] = oc;
    *(bh8*)&s[(size_t)r*512 + lane*8] = os;
  }
  __syncthreads();
  for (int i = tid; i < 2560; i += 256){
    const int c = i / 5, sg = i - (i/5)*5;
    const int seg = segbase + sg;
    bh8 ov;
    #pragma unroll
    for (int j = 0; j < 8; j++){
      const int dl = seg*8 + j - dd0;
      ov[j] = (short)((dl >= 0 && dl < ndd) ? tile[dl][c] : (u16)0);
    }
    *(bh8*)&cT[((size_t)b*512 + c)*320 + h*80 + seg*8] = ov;
  }
}

// ---------------- attn ctx: out[e][d] = softmax_d( scale * sum_n k[n,d] v[n,e] ), stored transposed ----------------
template<int D, int DREAL, int OS>
__global__ __launch_bounds__(256)
void ctx_kernel(const u16* __restrict__ kva, const u16* __restrict__ kvb,
                u16* __restrict__ outp, int K, int RS, int VOFF, float scale)
{
  constexpr int NT = D/16, MT = D/16, MTL = (MT+3)/4, SEG = D/8;
  __shared__ u16 vT[D][40];
  __shared__ u16 kT[D][40];
  const int h = blockIdx.x, b = blockIdx.y, iq = blockIdx.z;
  const int Hn = gridDim.x;
  const u16* base = (iq ? kvb : kva) + (size_t)b*K*RS + h*D;
  u16* out = outp + (((size_t)iq*64 + b)*Hn + h)*(size_t)(D*OS);
  const int tid = threadIdx.x, w = tid >> 6, lane = tid & 63, l15 = lane & 15, lg = lane >> 4;
  f4 acc[MTL][NT] = {};
  for (int k0 = 0; k0 < K; k0 += 32) {
    __syncthreads();
    for (int sI = tid; sI < 32*SEG; sI += 256) {
      const int nn = sI / SEG, dseg = sI - (sI/SEG)*SEG;
      bh8 kk = {}, vv = {};
      const int krow = k0 + nn;
      if (krow < K) {
        const u16* p = base + (size_t)krow*RS + dseg*8;
        kk = *(const bh8*)p;
        vv = *(const bh8*)(p + VOFF);
      }
      #pragma unroll
      for (int j = 0; j < 8; j++){
        kT[dseg*8+j][nn] = (u16)kk[j];
        vT[dseg*8+j][nn] = (u16)vv[j];
      }
    }
    __syncthreads();
    #pragma unroll
    for (int ii = 0; ii < MTL; ii++){
      const int mt = w + ii*4;
      if (MT % 4 != 0 && mt >= MT) break;
      const bh8 a = *(const bh8*)&vT[mt*16 + l15][lg*8];
      #pragma unroll
      for (int nt = 0; nt < NT; nt++){
        const bh8 bb = *(const bh8*)&kT[nt*16 + l15][lg*8];
        acc[ii][nt] = __builtin_amdgcn_mfma_f32_16x16x32_bf16(a, bb, acc[ii][nt], 0, 0, 0);
      }
    }
  }
  #pragma unroll
  for (int ii = 0; ii < MTL; ii++){
    const int mt = w + ii*4;
    if (MT % 4 != 0 && mt >= MT) continue;
    #pragma unroll
    for (int r = 0; r < 4; r++){
      const int e = mt*16 + lg*4 + r;
      float xs[NT]; float mx = -1e30f;
      #pragma unroll
      for (int nt = 0; nt < NT; nt++){
        float x = acc[ii][nt][r] * scale;
        if (DREAL != D && (nt*16 + l15) >= DREAL) x = -1e30f;
        xs[nt] = x; mx = fmaxf(mx, x);
      }
      mx = fmaxf(mx, __shfl_xor(mx,1)); mx = fmaxf(mx, __shfl_xor(mx,2));
      mx = fmaxf(mx, __shfl_xor(mx,4)); mx = fmaxf(mx, __shfl_xor(mx,8));
      float smv = 0.f;
      #pragma unroll
      for (int nt = 0; nt < NT; nt++){
        const float p = (xs[nt] > -1e29f) ? __expf(xs[nt]-mx) : 0.f;
        xs[nt] = p; smv += p;
      }
      smv += __shfl_xor(smv,1); smv += __shfl_xor(smv,2);
      smv += __shfl_xor(smv,4); smv += __shfl_xor(smv,8);
      const float inv = 1.f / smv;
      #pragma unroll
      for (int nt = 0; nt < NT; nt++)
        out[(size_t)e*OS + nt*16 + l15] = f2b(xs[nt]*inv);
      if (OS > D) out[(size_t)e*OS + D + l15] = 0;
    }
  }
}

// ---------------- spatial out: merge[:, :512] = q1@c2 + q2@c1 ----------------
__global__ __launch_bounds__(256)
void sp_out_kernel(const u16* __restrict__ s1, const u16* __restrict__ s2,
                   const u16* __restrict__ csT, u16* __restrict__ merge)
{
  const int h = blockIdx.x, b = blockIdx.y;
  const int tid = threadIdx.x, w = tid >> 6, lane = tid & 63, l15 = lane & 15, lg = lane >> 4;
  const u16* c1 = csT + (((size_t)b)*8 + h)*4096;
  const u16* c2 = csT + (((size_t)64 + b)*8 + h)*4096;
  for (int mt = w; mt < 19; mt += 4) {
    const int m = mt*16 + l15;
    const bool mv = (m < 300);
    const u16* q1 = s1 + ((size_t)b*300 + m)*512 + h*64;
    const u16* q2 = s2 + ((size_t)b*300 + m)*512 + h*64;
    f4 acc[4] = {};
    #pragma unroll
    for (int kc = 0; kc < 2; kc++){
      bh8 a1 = {}, a2 = {};
      if (mv){ a1 = *(const bh8*)(q1 + kc*32 + lg*8); a2 = *(const bh8*)(q2 + kc*32 + lg*8); }
      #pragma unroll
      for (int nt = 0; nt < 4; nt++){
        const bh8 b2v = *(const bh8*)&c2[(size_t)(nt*16+l15)*64 + kc*32 + lg*8];
        acc[nt] = __builtin_amdgcn_mfma_f32_16x16x32_bf16(a1, b2v, acc[nt], 0, 0, 0);
        const bh8 b1v = *(const bh8*)&c1[(size_t)(nt*16+l15)*64 + kc*32 + lg*8];
        acc[nt] = __builtin_amdgcn_mfma_f32_16x16x32_bf16(a2, b1v, acc[nt], 0, 0, 0);
      }
    }
    #pragma unroll
    for (int nt = 0; nt < 4; nt++)
      #pragma unroll
      for (int r = 0; r < 4; r++){
        const int mm = mt*16 + lg*4 + r;
        if (mm < 300)
          merge[((size_t)b*300 + mm)*1024 + h*64 + nt*16 + l15] = f2b(acc[nt][r]);
      }
  }
}

// ---------------- channel out (transposed): merge[:, 512:] = (q1c@c2c + q2c@c1c)^T ----------------
__global__ __launch_bounds__(256)
void ch_out_kernel(const u16* __restrict__ cT1, const u16* __restrict__ cT2,
                   const u16* __restrict__ ccT, u16* __restrict__ merge)
{
  const int cb = blockIdx.x, h = blockIdx.y, b = blockIdx.z;
  const int tid = threadIdx.x, w = tid >> 6, lane = tid & 63, l15 = lane & 15, lg = lane >> 4;
  const int chbase = cb*128 + w*32;
  f4 acc[5][2] = {};
  #pragma unroll
  for (int oi = 0; oi < 2; oi++){
    const u16* Am = ccT + (((size_t)((oi==0)?1:0)*64 + b)*4 + h)*(size_t)(80*96);
    const u16* qb = (oi==0) ? cT1 : cT2;
    #pragma unroll
    for (int kc = 0; kc < 3; kc++){
      bh8 bf[2];
      #pragma unroll
      for (int nf = 0; nf < 2; nf++){
        const int ch = chbase + nf*16 + l15;
        bf[nf] = *(const bh8*)&qb[((size_t)b*512 + ch)*320 + h*80 + kc*32 + lg*8];
      }
      #pragma unroll
      for (int mt = 0; mt < 5; mt++){
        const bh8 a = *(const bh8*)&Am[(size_t)(mt*16+l15)*96 + kc*32 + lg*8];
        #pragma unroll
        for (int nf = 0; nf < 2; nf++)
          acc[mt][nf] = __builtin_amdgcn_mfma_f32_16x16x32_bf16(a, bf[nf], acc[mt][nf], 0, 0, 0);
      }
    }
  }
  #pragma unroll
  for (int mt = 0; mt < 5; mt++)
    #pragma unroll
    for (int nf = 0; nf < 2; nf++)
      #pragma unroll
      for (int r = 0; r < 4; r++){
        const int e = mt*16 + lg*4 + r;
        if (e < 75)
          merge[((size_t)b*300 + h*75 + e)*1024 + 512 + chbase + nf*16 + l15] = f2b(acc[mt][nf][r]);
      }
}

// ---------------- depthwise 3x3 + bias + leaky(0.01), channels-last, tap-major bf16 weights ----------------
__global__ __launch_bounds__(256)
void dw_kernel(const u16* __restrict__ e1, const u16* __restrict__ dwt,
               const float* __restrict__ bias, u16* __restrict__ d1)
{
  const int idx = blockIdx.x*256 + threadIdx.x;
  const int cg = idx & 63;
  const int sp = (idx >> 6) % 300;
  const int b  = idx / (64*300);
  const int c0 = cg*8;
  const int hh = sp / 15, ww = sp - hh*15;
  float acc[8];
  {
    const float4 b0 = *(const float4*)&bias[c0];
    const float4 b1 = *(const float4*)&bias[c0+4];
    acc[0]=b0.x; acc[1]=b0.y; acc[2]=b0.z; acc[3]=b0.w;
    acc[4]=b1.x; acc[5]=b1.y; acc[6]=b1.z; acc[7]=b1.w;
  }
  #pragma unroll
  for (int dy = -1; dy <= 1; dy++){
    const int h2 = hh + dy; if (h2 < 0 || h2 >= 20) continue;
    #pragma unroll
    for (int dx = -1; dx <= 1; dx++){
      const int w2 = ww + dx; if (w2 < 0 || w2 >= 15) continue;
      const bh8 vv = *(const bh8*)&e1[((size_t)b*300 + h2*15 + w2)*512 + c0];
      const int t = (dy+1)*3 + (dx+1);
      const bh8 wv = *(const bh8*)&dwt[t*512 + c0];
      #pragma unroll
      for (int j = 0; j < 8; j++)
        acc[j] += b2f((u16)vv[j]) * b2f((u16)wv[j]);
    }
  }
  bh8 ov;
  #pragma unroll
  for (int j = 0; j < 8; j++){
    float y = acc[j];
    y = (y >= 0.f) ? y : 0.01f*y;
    ov[j] = (short)f2b(y);
  }
  *(bh8*)&d1[((size_t)b*300 + sp)*512 + c0] = ov;
}

// ---------------- BN stats / finalize / final write ----------------
__global__ __launch_bounds__(256)
void stats_e(const float* __restrict__ e3, float* __restrict__ st){
  const int tid = threadIdx.x;
  const int c0 = tid*2;
  const size_t r0 = (size_t)blockIdx.x * 128;
  float s0=0,s1=0,q0=0,q1=0;
  for (int rr = 0; rr < 128; rr++){
    const float2 v = *(const float2*)&e3[(r0+rr)*512 + c0];
    s0 += v.x; s1 += v.y; q0 += v.x*v.x; q1 += v.y*v.y;
  }
  atomicAdd(&st[c0], s0); atomicAdd(&st[c0+1], s1);
  atomicAdd(&st[512+c0], q0); atomicAdd(&st[512+c0+1], q1);
}
__global__ void fin_e(float* st, const float* __restrict__ w, const float* __restrict__ b){
  const int c = threadIdx.x;
  const float m = st[c] * (1.f/19200.f);
  const float v = st[512+c] * (1.f/19200.f) - m*m;
  const float a = w[c] * rsqrtf(v + 1e-5f);
  st[1024+c] = a; st[1536+c] = b[c] - m*a;
}
__global__ __launch_bounds__(256)
void stats_o(const float* __restrict__ res, const float* __restrict__ e3, float* __restrict__ st){
  const int tid = threadIdx.x;
  const int c0 = tid*2;
  const float a0 = st[1024+c0], b0v = st[1536+c0];
  const float a1 = st[1024+c0+1], b1v = st[1536+c0+1];
  const size_t r0 = (size_t)blockIdx.x * 128;
  float s0=0,s1=0,q0=0,q1=0;
  for (int rr = 0; rr < 128; rr++){
    const size_t o2 = (r0+rr)*512 + c0;
    const float2 rv = *(const float2*)&res[o2];
    const float2 ev = *(const float2*)&e3[o2];
    const float v0 = rv.x + ev.x*a0 + b0v;
    const float v1 = rv.y + ev.y*a1 + b1v;
    s0 += v0; s1 += v1; q0 += v0*v0; q1 += v1*v1;
  }
  atomicAdd(&st[2048+c0], s0); atomicAdd(&st[2048+c0+1], s1);
  atomicAdd(&st[2560+c0], q0); atomicAdd(&st[2560+c0+1], q1);
}
__global__ void fin_o(float* st, const float* __restrict__ w, const float* __restrict__ b){
  const int c = threadIdx.x;
  const float m = st[2048+c] * (1.f/19200.f);
  const float v = st[2560+c] * (1.f/19200.f) - m*m;
  const float a = w[c] * rsqrtf(v + 1e-5f);
  st[3072+c] = a; st[3584+c] = b[c] - m*a;
}
__global__ __launch_bounds__(256)
void final_kernel(const float* __restrict__ res, const float* __restrict__ e3,
                  const float* __restrict__ st, float* __restrict__ outp)
{
  __shared__ float tile[64][65];
  const int spt = blockIdx.x, cht = blockIdx.y, b = blockIdx.z;
  const int tid = threadIdx.x;
  const int sp0 = spt*64, ch0 = cht*64;
  for (int idx = tid; idx < 4096; idx += 256){
    const int cl = idx & 63, sl = idx >> 6;
    const int sp = sp0 + sl;
    float v = 0.f;
    if (sp < 300){
      const size_t off = ((size_t)b*300 + sp)*512 + ch0 + cl;
      const int c = ch0 + cl;
      const float e = e3[off]*st[1024+c] + st[1536+c];
      v = (res[off] + e)*st[3072+c] + st[3584+c];
    }
    tile[sl][cl] = v;
  }
  __syncthreads();
  for (int idx = tid; idx < 4096; idx += 256){
    const int sl = idx & 63, cl = idx >> 6;
    const int sp = sp0 + sl;
    if (sp < 300)
      outp[((size_t)b*512 + ch0 + cl)*300 + sp] = tile[sl][cl];
  }
}

// ---------------- host ----------------
extern "C" void kernel_launch(void* const* d_in, const int* in_sizes, int n_in,
                              void* d_out, int out_size, void* d_ws, size_t ws_size,
                              hipStream_t stream)
{
  const float* x1    = (const float*)d_in[0];
  const float* x2    = (const float*)d_in[1];
  const float* cp1_w = (const float*)d_in[2];
  const float* cp1_b = (const float*)d_in[3];
  const float* ln1_w = (const float*)d_in[4];
  const float* ln1_b = (const float*)d_in[5];
  const float* cp2_w = (const float*)d_in[6];
  const float* cp2_b = (const float*)d_in[7];
  const float* ln2_w = (const float*)d_in[8];
  const float* ln2_b = (const float*)d_in[9];
  const float* skv1w = (const float*)d_in[10];
  const float* skv2w = (const float*)d_in[11];
  const float* ckv1w = (const float*)d_in[12];
  const float* ckv2w = (const float*)d_in[13];
  const float* resw  = (const float*)d_in[14];
  const float* ce1w  = (const float*)d_in[15];
  const float* ce1b  = (const float*)d_in[16];
  const float* dww   = (const float*)d_in[17];
  const float* dwb   = (const float*)d_in[18];
  const float* ce3w  = (const float*)d_in[19];
  const float* ce3b  = (const float*)d_in[20];
  const float* bnew  = (const float*)d_in[21];
  const float* bneb  = (const float*)d_in[22];
  const float* bnow  = (const float*)d_in[23];
  const float* bnob  = (const float*)d_in[24];
  float* out = (float*)d_out;
  char* ws = (char*)d_ws;

  const size_t SZ_T    = (size_t)19200*512*2;
  const size_t SZ_APRE = (size_t)19200*1024*2;
  const size_t SZ_CKV  = (size_t)32768*640*2;
  const size_t SZ_CT   = (size_t)64*512*320*2;
  const size_t SZ_F32  = (size_t)19200*512*4;

  size_t off = 0;
  auto AL = [&](size_t sz){ size_t r = off; off += (sz + 255) & ~(size_t)255; return r; };
  const size_t oR0 = AL(2*SZ_T);             // t1,t2 -> merge
  const size_t oR1 = AL(2*SZ_CKV);           // apre1,apre2 -> kv1,kv2 -> ckv1,ckv2
  const size_t oR2 = AL(2*SZ_T);             // s1,s2 -> e1,d1
  const size_t oR3 = AL(2*SZ_CT + 4096);     // cT1,cT2 -> e3(f32)
  const size_t oR4 = AL(SZ_F32);             // res f32
  const size_t oR5 = AL((size_t)2*64*8*64*64*2);  // c_sT
  const size_t oR6 = AL((size_t)2*64*4*80*96*2);  // c_cT
  const size_t oWcp1  = AL((size_t)1024*512*2);
  const size_t oWcp2  = AL((size_t)1024*512*2);
  const size_t oWskv1 = AL((size_t)1024*512*2);
  const size_t oWskv2 = AL((size_t)1024*512*2);
  const size_t oWckv1 = AL((size_t)640*320*2);
  const size_t oWckv2 = AL((size_t)640*320*2);
  const size_t oWresce = AL((size_t)1024*1024*2);  // [res(512) | ce1(512)] x K=1024
  const size_t oWce3  = AL((size_t)512*512*2);
  const size_t oWdw   = AL((size_t)9*512*2);
  const size_t oST    = AL(16384);
  (void)ws_size; (void)in_sizes; (void)n_in; (void)out_size;

  u16* t1    = (u16*)(ws + oR0);
  u16* t2    = (u16*)(ws + oR0 + SZ_T);
  u16* merge = (u16*)(ws + oR0);
  u16* apre1 = (u16*)(ws + oR1);
  u16* apre2 = (u16*)(ws + oR1 + SZ_APRE);
  u16* kv1   = apre1;
  u16* kv2   = apre2;
  u16* ckv1  = (u16*)(ws + oR1);
  u16* ckv2  = (u16*)(ws + oR1 + SZ_CKV);
  u16* s1    = (u16*)(ws + oR2);
  u16* s2    = (u16*)(ws + oR2 + SZ_T);
  u16* e1    = s1;
  u16* d1    = s2;
  u16* cT1   = (u16*)(ws + oR3);
  u16* cT2   = (u16*)(ws + oR3 + SZ_CT);
  u16* slack = (u16*)(ws + oR3 + 2*SZ_CT);
  float* e3  = (float*)(ws + oR3);
  float* resb = (float*)(ws + oR4);
  u16* csT   = (u16*)(ws + oR5);
  u16* ccT   = (u16*)(ws + oR6);
  u16* wcp1  = (u16*)(ws + oWcp1);
  u16* wcp2  = (u16*)(ws + oWcp2);
  u16* wskv1 = (u16*)(ws + oWskv1);
  u16* wskv2 = (u16*)(ws + oWskv2);
  u16* wckv1 = (u16*)(ws + oWckv1);
  u16* wckv2 = (u16*)(ws + oWckv2);
  u16* wresce = (u16*)(ws + oWresce);
  u16* wce3  = (u16*)(ws + oWce3);
  u16* wdw   = (u16*)(ws + oWdw);
  float* st  = (float*)(ws + oST);

  hipMemsetAsync(st, 0, 16384, stream);
  pad_zero<<<8,256,0,stream>>>(slack);
  pack_plain<<<2048,256,0,stream>>>(cp1_w, wcp1, 524288);
  pack_plain<<<2048,256,0,stream>>>(cp2_w, wcp2, 524288);
  pack_plain<<<2048,256,0,stream>>>(skv1w, wskv1, 524288);
  pack_plain<<<2048,256,0,stream>>>(skv2w, wskv2, 524288);
  pack_ckv_k<<<800,256,0,stream>>>(ckv1w, wckv1);
  pack_ckv_k<<<800,256,0,stream>>>(ckv2w, wckv2);
  pack_plain<<<2048,256,0,stream>>>(resw, wresce, 524288);
  pack_plain<<<2048,256,0,stream>>>(ce1w, wresce + 524288, 524288);
  pack_plain<<<1024,256,0,stream>>>(ce3w, wce3, 262144);
  pack_dw<<<18,256,0,stream>>>(dww, wdw);

  transpose_k<<<dim3(10,16,64),256,0,stream>>>(x1, t1);
  transpose_k<<<dim3(10,16,64),256,0,stream>>>(x2, t2);

  gemm_k<0,1><<<dim3(8,150),256,0,stream>>>(t1,512, wcp1,512, apre1,nullptr,1024, cp1_b, 512);
  gemm_k<0,1><<<dim3(8,150),256,0,stream>>>(t2,512, wcp2,512, apre2,nullptr,1024, cp2_b, 512);

  ln_kernel<<<dim3(256,2),256,0,stream>>>(apre1, ln1_w, ln1_b, s1, cT1);
  ln_kernel<<<dim3(256,2),256,0,stream>>>(apre2, ln2_w, ln2_b, s2, cT2);

  gemm_k<0,0><<<dim3(8,150),256,0,stream>>>(s1,512, wskv1,512, kv1,nullptr,1024, nullptr, 512);
  gemm_k<0,0><<<dim3(8,150),256,0,stream>>>(s2,512, wskv2,512, kv2,nullptr,1024, nullptr, 512);

  ctx_kernel<64,64,64><<<dim3(8,64,2),256,0,stream>>>(kv1, kv2, csT, 300, 1024, 512, 0.125f);

  gemm_k<0,0><<<dim3(5,256),256,0,stream>>>(cT1,320, wckv1,320, ckv1,nullptr,640, nullptr, 320);
  gemm_k<0,0><<<dim3(5,256),256,0,stream>>>(cT2,320, wckv2,320, ckv2,nullptr,640, nullptr, 320);

  ctx_kernel<80,75,96><<<dim3(4,64,2),256,0,stream>>>(ckv1, ckv2, ccT, 512, 640, 320, 0.115470054f);

  sp_out_kernel<<<dim3(8,64),256,0,stream>>>(s1, s2, csT, merge);
  ch_out_kernel<<<dim3(4,4,64),256,0,stream>>>(cT1, cT2, ccT, merge);

  // merged res (f32, cols 0..511) + ce1 (bf16+bias, cols 512..1023)
  gemm_k<2,0><<<dim3(8,150),256,0,stream>>>(merge,1024, wresce,1024, e1, resb, 512, ce1b, 1024);

  dw_kernel<<<4800,256,0,stream>>>(e1, wdw, dwb, d1);

  gemm_k<1,1><<<dim3(4,150),256,0,stream>>>(d1,512, wce3,512, nullptr,e3,512, ce3b, 512);

  stats_e<<<150,256,0,stream>>>(e3, st);
  fin_e<<<1,512,0,stream>>>(st, bnew, bneb);
  stats_o<<<150,256,0,stream>>>(resb, e3, st);
  fin_o<<<1,512,0,stream>>>(st, bnow, bnob);
  final_kernel<<<dim3(5,8,64),256,0,stream>>>(resb, e3, st, out);
}

// Round 6
// 597.522 us; speedup vs baseline: 1.5030x; 1.0530x over previous
//
#include <hip/hip_runtime.h>

typedef unsigned short u16;
typedef __attribute__((ext_vector_type(8))) short bh8;
typedef __attribute__((ext_vector_type(4))) float f4;

__device__ __forceinline__ u16 f2b(float f){
  unsigned int u = __float_as_uint(f);
  u += 0x7fffu + ((u >> 16) & 1u);
  return (u16)(u >> 16);
}
__device__ __forceinline__ float b2f(u16 h){
  return __uint_as_float(((unsigned int)h) << 16);
}
__device__ __forceinline__ void gl16(const u16* g, u16* l){
  __builtin_amdgcn_global_load_lds((const __attribute__((address_space(1))) void*)g,
                                   (__attribute__((address_space(3))) void*)l, 16, 0, 0);
}

// ---------------- packing ----------------
__global__ void pack_plain(const float* __restrict__ src, u16* __restrict__ dst, int count){
  int i = blockIdx.x*256 + threadIdx.x;
  if (i < count) dst[i] = f2b(src[i]);
}
// c_kv_w (600,300) -> padded [640][320]: n = t*320+h*80+dd, k = kh*80+kd
__global__ void pack_ckv_k(const float* __restrict__ src, u16* __restrict__ dst){
  int i = blockIdx.x*256 + threadIdx.x; // 640*320
  int nn = i / 320, kk = i - (i/320)*320;
  int t_ = (nn >= 320) ? 1 : 0;
  int rem = nn - t_*320;
  int hh = rem / 80, dd = rem - hh*80;
  int kh = kk / 80, kd = kk - kh*80;
  float v = 0.f;
  if (dd < 75 && kd < 75)
    v = src[(size_t)(t_*300 + hh*75 + dd)*300 + (kh*75 + kd)];
  dst[i] = f2b(v);
}
// dw weight (512,1,3,3) -> dwt[9][512] bf16 (tap-major, coalesced per-tap loads)
__global__ void pack_dw(const float* __restrict__ src, u16* __restrict__ dst){
  int i = blockIdx.x*256 + threadIdx.x; // 4608
  if (i < 4608){
    int t = i >> 9, c = i & 511;
    dst[i] = f2b(src[c*9 + t]);
  }
}
// zero the 4KiB slack after cT2 that ch_out's tail k-chunk over-reads (x0, but must be finite)
__global__ void pad_zero(u16* __restrict__ slack){
  const int j = blockIdx.x*256 + threadIdx.x;
  if (j < 2048) slack[j] = 0;
}

// ---------------- x (B,C,H,W) f32 -> t (B,N,C) bf16 ----------------
__global__ __launch_bounds__(256)
void transpose_k(const float* __restrict__ x, u16* __restrict__ t)
{
  __shared__ float tile[32][33];
  const int n0 = blockIdx.x * 32, c0 = blockIdx.y * 32, b = blockIdx.z;
  const int ln = threadIdx.x & 31, lr = threadIdx.x >> 5;
  #pragma unroll
  for (int q = 0; q < 4; q++) {
    const int c = c0 + lr + q*8, n = n0 + ln;
    tile[lr + q*8][ln] = (n < 300) ? x[((long)b*512 + c)*300 + n] : 0.f;
  }
  __syncthreads();
  #pragma unroll
  for (int q = 0; q < 4; q++) {
    const int n = n0 + lr + q*8;
    if (n < 300) t[((long)b*300 + n)*512 + c0 + ln] = f2b(tile[ln][lr + q*8]);
  }
}

// ---------------- generic 128x128 MFMA GEMM: C = A(M,K) @ Bw(N,K)^T ----------------
// Double-buffered LDS prefetch, ONE barrier per K-step.
// XCD-aware bijective block remap (nwg must be divisible by 8): each XCD owns a
// contiguous m-tile range so A panels are fetched once per L2.
// Both-sides XOR LDS swizzle: stage global seg^((row>>1)&3) into linear LDS,
// read slot lg^((r>>1)&3) -> 16-lane quarter-wave hits 8 distinct bank groups.
// OUTF: 0 = bf16 out (+bias if HASB); 1 = f32 out (+bias if HASB);
//       2 = split: n<512 -> f32 (no bias), n>=512 -> bf16 (+bias[cn-512])
template<int OUTF, int HASB>
__global__ __launch_bounds__(256)
void gemm_k(const u16* __restrict__ A, int lda,
            const u16* __restrict__ Bw, int ldb,
            u16* __restrict__ Cb, float* __restrict__ Cf, int ldc,
            const float* __restrict__ bias, int K)
{
  __shared__ u16 As[2][4096];
  __shared__ u16 Bs[2][4096];
  const int tid = threadIdx.x;
  const int gx = gridDim.x;
  const int nwg = gx * gridDim.y;
  const int flat = blockIdx.y * gx + blockIdx.x;
  const int newid = (flat & 7) * (nwg >> 3) + (flat >> 3);
  const long n0 = (long)(newid % gx) * 128;
  const long m0 = (long)(newid / gx) * 128;
  const int wave = tid >> 6, lane = tid & 63;
  const int l15 = lane & 15, lg = lane >> 4;
  const int wr = (wave >> 1) * 64, wc = (wave & 1) * 64;
  const int arow = tid >> 2;
  const int aseg = (((tid & 3) ^ ((arow >> 1) & 3))) * 8;  // pre-swizzled global segment
  const u16* Ag0 = A + (m0 + arow) * (long)lda + aseg;
  const u16* Ag1 = Ag0 + 64L * lda;
  const u16* Bg0 = Bw + (n0 + arow) * (long)ldb + aseg;
  const u16* Bg1 = Bg0 + 64L * ldb;
  const int to8 = tid * 8;
  // swizzled LDS read offsets (elements), loop-invariant per lane
  int roA[4], roB[4];
  #pragma unroll
  for (int i = 0; i < 4; i++){
    const int rA = wr + i*16 + l15;
    roA[i] = rA*32 + ((lg ^ ((rA >> 1) & 3)) * 8);
    const int rB = wc + i*16 + l15;
    roB[i] = rB*32 + ((lg ^ ((rB >> 1) & 3)) * 8);
  }
  f4 acc[4][4] = {};
  const int NT = K >> 5;
  gl16(Ag0, &As[0][to8]); gl16(Ag1, &As[0][2048 + to8]);
  gl16(Bg0, &Bs[0][to8]); gl16(Bg1, &Bs[0][2048 + to8]);
  __syncthreads();
  int cur = 0;
  for (int t = 0; t < NT - 1; t++) {
    const int kt = (t + 1) << 5;
    const int nb = cur ^ 1;
    gl16(Ag0 + kt, &As[nb][to8]); gl16(Ag1 + kt, &As[nb][2048 + to8]);
    gl16(Bg0 + kt, &Bs[nb][to8]); gl16(Bg1 + kt, &Bs[nb][2048 + to8]);
    bh8 af[4], bf[4];
    #pragma unroll
    for (int mi = 0; mi < 4; mi++) af[mi] = *(const bh8*)&As[cur][roA[mi]];
    #pragma unroll
    for (int ni = 0; ni < 4; ni++) bf[ni] = *(const bh8*)&Bs[cur][roB[ni]];
    #pragma unroll
    for (int mi = 0; mi < 4; mi++)
      #pragma unroll
      for (int ni = 0; ni < 4; ni++)
        acc[mi][ni] = __builtin_amdgcn_mfma_f32_16x16x32_bf16(af[mi], bf[ni], acc[mi][ni], 0, 0, 0);
    __syncthreads();   // drains prefetch vmcnt + syncs; buf[nb] ready
    cur = nb;
  }
  { // final tile
    bh8 af[4], bf[4];
    #pragma unroll
    for (int mi = 0; mi < 4; mi++) af[mi] = *(const bh8*)&As[cur][roA[mi]];
    #pragma unroll
    for (int ni = 0; ni < 4; ni++) bf[ni] = *(const bh8*)&Bs[cur][roB[ni]];
    #pragma unroll
    for (int mi = 0; mi < 4; mi++)
      #pragma unroll
      for (int ni = 0; ni < 4; ni++)
        acc[mi][ni] = __builtin_amdgcn_mfma_f32_16x16x32_bf16(af[mi], bf[ni], acc[mi][ni], 0, 0, 0);
  }
  if (OUTF == 2) {
    if (n0 < 512) {
      #pragma unroll
      for (int ni = 0; ni < 4; ni++) {
        const long cn = n0 + wc + ni*16 + l15;
        #pragma unroll
        for (int mi = 0; mi < 4; mi++)
          #pragma unroll
          for (int r = 0; r < 4; r++) {
            const long cm = m0 + wr + mi*16 + lg*4 + r;
            Cf[cm * ldc + cn] = acc[mi][ni][r];
          }
      }
    } else {
      #pragma unroll
      for (int ni = 0; ni < 4; ni++) {
        const long cn = n0 - 512 + wc + ni*16 + l15;
        const float bv = bias[cn];
        #pragma unroll
        for (int mi = 0; mi < 4; mi++)
          #pragma unroll
          for (int r = 0; r < 4; r++) {
            const long cm = m0 + wr + mi*16 + lg*4 + r;
            Cb[cm * ldc + cn] = f2b(acc[mi][ni][r] + bv);
          }
      }
    }
  } else {
    #pragma unroll
    for (int ni = 0; ni < 4; ni++) {
      const long cn = n0 + wc + ni*16 + l15;
      const float bv = HASB ? bias[cn] : 0.0f;
      #pragma unroll
      for (int mi = 0; mi < 4; mi++) {
        #pragma unroll
        for (int r = 0; r < 4; r++) {
          const long cm = m0 + wr + mi*16 + lg*4 + r;
          const float v = acc[mi][ni][r] + bv;
          if (OUTF) Cf[cm * ldc + cn] = v;
          else      Cb[cm * ldc + cn] = f2b(v);
        }
      }
    }
  }
}

// ---------------- LayerNorm(1024) + relu; split into s (B,N,512) coalesced and
// cT (B,512,320pad) via LDS block-transpose (coalesced 16B chunks along nn) ----------------
__global__ __launch_bounds__(256)
void ln_kernel(const u16* __restrict__ apre, const float* __restrict__ lw, const float* __restrict__ lb,
               u16* __restrict__ s, u16* __restrict__ cT)
{
  __shared__ u16 tile[40][520];   // pitch 520: rows 16B-aligned
  const int bh = blockIdx.x;      // b*4 + h
  const int b = bh >> 2, h = bh & 3;
  const int z = blockIdx.y;
  const int dd0 = z ? 40 : 0;
  const int ndd = z ? 35 : 40;    // z=0: dd 0..39 (segs 0..4), z=1: dd 40..74 (+pad 75..79, segs 5..9)
  const int segbase = z ? 5 : 0;
  const int tid = threadIdx.x, w = tid >> 6, lane = tid & 63;
  const int r0 = b*300 + h*75 + dd0;
  for (int dl = w; dl < ndd; dl += 4){
    const int r = r0 + dl;
    const u16* row = apre + (size_t)r*1024 + lane*8;
    const bh8 vc = *(const bh8*)row;          // c-half cols lane*8..+7
    const bh8 vs = *(const bh8*)(row + 512);  // s-half
    float fc[8], fs[8];
    float sm = 0.f, sq = 0.f;
    #pragma unroll
    for (int j = 0; j < 8; j++){
      fc[j] = b2f((u16)vc[j]); fs[j] = b2f((u16)vs[j]);
      sm += fc[j] + fs[j];
      sq += fc[j]*fc[j] + fs[j]*fs[j];
    }
    #pragma unroll
    for (int o = 32; o; o >>= 1){ sm += __shfl_xor(sm, o); sq += __shfl_xor(sq, o); }
    const float mean = sm * (1.f/1024.f);
    const float rstd = rsqrtf(sq*(1.f/1024.f) - mean*mean + 1e-5f);
    bh8 oc, os;
    #pragma unroll
    for (int j = 0; j < 8; j++){
      const int c = lane*8 + j;
      const float y1 = (fc[j]-mean)*rstd*lw[c] + lb[c];
      oc[j] = (short)f2b(fmaxf(y1, 0.f));
      const float y2 = (fs[j]-mean)*rstd*lw[512+c] + lb[512+c];
      os[j] = (short)f2b(fmaxf(y2, 0.f));
    }
    *(bh8*)&tile[dl][lane*8] = oc;
    *(bh8*)&s[(size_t)r*512 + lane*8] = os;
  }
  __syncthreads();
  for (int i = tid; i < 2560; i += 256){
    const int c = i / 5, sg = i - (i/5)*5;
    const int seg = segbase + sg;
    bh8 ov;
    #pragma unroll
    for (int j = 0; j < 8; j++){
      const int dl = seg*8 + j - dd0;
      ov[j] = (short)((dl >= 0 && dl < ndd) ? tile[dl][c] : (u16)0);
    }
    *(bh8*)&cT[((size_t)b*512 + c)*320 + h*80 + seg*8] = ov;
  }
}

// ---------------- attn ctx: out[e][d] = softmax_d( scale * sum_n k[n,d] v[n,e] ), stored transposed ----------------
template<int D, int DREAL, int OS>
__global__ __launch_bounds__(256)
void ctx_kernel(const u16* __restrict__ kva, const u16* __restrict__ kvb,
                u16* __restrict__ outp, int K, int RS, int VOFF, float scale)
{
  constexpr int NT = D/16, MT = D/16, MTL = (MT+3)/4, SEG = D/8;
  __shared__ u16 vT[D][40];
  __shared__ u16 kT[D][40];
  const int h = blockIdx.x, b = blockIdx.y, iq = blockIdx.z;
  const int Hn = gridDim.x;
  const u16* base = (iq ? kvb : kva) + (size_t)b*K*RS + h*D;
  u16* out = outp + (((size_t)iq*64 + b)*Hn + h)*(size_t)(D*OS);
  const int tid = threadIdx.x, w = tid >> 6, lane = tid & 63, l15 = lane & 15, lg = lane >> 4;
  f4 acc[MTL][NT] = {};
  for (int k0 = 0; k0 < K; k0 += 32) {
    __syncthreads();
    for (int sI = tid; sI < 32*SEG; sI += 256) {
      const int nn = sI / SEG, dseg = sI - (sI/SEG)*SEG;
      bh8 kk = {}, vv = {};
      const int krow = k0 + nn;
      if (krow < K) {
        const u16* p = base + (size_t)krow*RS + dseg*8;
        kk = *(const bh8*)p;
        vv = *(const bh8*)(p + VOFF);
      }
      #pragma unroll
      for (int j = 0; j < 8; j++){
        kT[dseg*8+j][nn] = (u16)kk[j];
        vT[dseg*8+j][nn] = (u16)vv[j];
      }
    }
    __syncthreads();
    #pragma unroll
    for (int ii = 0; ii < MTL; ii++){
      const int mt = w + ii*4;
      if (MT % 4 != 0 && mt >= MT) break;
      const bh8 a = *(const bh8*)&vT[mt*16 + l15][lg*8];
      #pragma unroll
      for (int nt = 0; nt < NT; nt++){
        const bh8 bb = *(const bh8*)&kT[nt*16 + l15][lg*8];
        acc[ii][nt] = __builtin_amdgcn_mfma_f32_16x16x32_bf16(a, bb, acc[ii][nt], 0, 0, 0);
      }
    }
  }
  #pragma unroll
  for (int ii = 0; ii < MTL; ii++){
    const int mt = w + ii*4;
    if (MT % 4 != 0 && mt >= MT) continue;
    #pragma unroll
    for (int r = 0; r < 4; r++){
      const int e = mt*16 + lg*4 + r;
      float xs[NT]; float mx = -1e30f;
      #pragma unroll
      for (int nt = 0; nt < NT; nt++){
        float x = acc[ii][nt][r] * scale;
        if (DREAL != D && (nt*16 + l15) >= DREAL) x = -1e30f;
        xs[nt] = x; mx = fmaxf(mx, x);
      }
      mx = fmaxf(mx, __shfl_xor(mx,1)); mx = fmaxf(mx, __shfl_xor(mx,2));
      mx = fmaxf(mx, __shfl_xor(mx,4)); mx = fmaxf(mx, __shfl_xor(mx,8));
      float smv = 0.f;
      #pragma unroll
      for (int nt = 0; nt < NT; nt++){
        const float p = (xs[nt] > -1e29f) ? __expf(xs[nt]-mx) : 0.f;
        xs[nt] = p; smv += p;
      }
      smv += __shfl_xor(smv,1); smv += __shfl_xor(smv,2);
      smv += __shfl_xor(smv,4); smv += __shfl_xor(smv,8);
      const float inv = 1.f / smv;
      #pragma unroll
      for (int nt = 0; nt < NT; nt++)
        out[(size_t)e*OS + nt*16 + l15] = f2b(xs[nt]*inv);
      if (OS > D) out[(size_t)e*OS + D + l15] = 0;
    }
  }
}

// ---------------- spatial out: merge[:, :512] = q1@c2 + q2@c1 ----------------
__global__ __launch_bounds__(256)
void sp_out_kernel(const u16* __restrict__ s1, const u16* __restrict__ s2,
                   const u16* __restrict__ csT, u16* __restrict__ merge)
{
  const int h = blockIdx.x, b = blockIdx.y;
  const int tid = threadIdx.x, w = tid >> 6, lane = tid & 63, l15 = lane & 15, lg = lane >> 4;
  const u16* c1 = csT + (((size_t)b)*8 + h)*4096;
  const u16* c2 = csT + (((size_t)64 + b)*8 + h)*4096;
  for (int mt = w; mt < 19; mt += 4) {
    const int m = mt*16 + l15;
    const bool mv = (m < 300);
    const u16* q1 = s1 + ((size_t)b*300 + m)*512 + h*64;
    const u16* q2 = s2 + ((size_t)b*300 + m)*512 + h*64;
    f4 acc[4] = {};
    #pragma unroll
    for (int kc = 0; kc < 2; kc++){
      bh8 a1 = {}, a2 = {};
      if (mv){ a1 = *(const bh8*)(q1 + kc*32 + lg*8); a2 = *(const bh8*)(q2 + kc*32 + lg*8); }
      #pragma unroll
      for (int nt = 0; nt < 4; nt++){
        const bh8 b2v = *(const bh8*)&c2[(size_t)(nt*16+l15)*64 + kc*32 + lg*8];
        acc[nt] = __builtin_amdgcn_mfma_f32_16x16x32_bf16(a1, b2v, acc[nt], 0, 0, 0);
        const bh8 b1v = *(const bh8*)&c1[(size_t)(nt*16+l15)*64 + kc*32 + lg*8];
        acc[nt] = __builtin_amdgcn_mfma_f32_16x16x32_bf16(a2, b1v, acc[nt], 0, 0, 0);
      }
    }
    #pragma unroll
    for (int nt = 0; nt < 4; nt++)
      #pragma unroll
      for (int r = 0; r < 4; r++){
        const int mm = mt*16 + lg*4 + r;
        if (mm < 300)
          merge[((size_t)b*300 + mm)*1024 + h*64 + nt*16 + l15] = f2b(acc[nt][r]);
      }
  }
}

// ---------------- channel out (transposed): merge[:, 512:] = (q1c@c2c + q2c@c1c)^T ----------------
__global__ __launch_bounds__(256)
void ch_out_kernel(const u16* __restrict__ cT1, const u16* __restrict__ cT2,
                   const u16* __restrict__ ccT, u16* __restrict__ merge)
{
  const int cb = blockIdx.x, h = blockIdx.y, b = blockIdx.z;
  const int tid = threadIdx.x, w = tid >> 6, lane = tid & 63, l15 = lane & 15, lg = lane >> 4;
  const int chbase = cb*128 + w*32;
  f4 acc[5][2] = {};
  #pragma unroll
  for (int oi = 0; oi < 2; oi++){
    const u16* Am = ccT + (((size_t)((oi==0)?1:0)*64 + b)*4 + h)*(size_t)(80*96);
    const u16* qb = (oi==0) ? cT1 : cT2;
    #pragma unroll
    for (int kc = 0; kc < 3; kc++){
      bh8 bf[2];
      #pragma unroll
      for (int nf = 0; nf < 2; nf++){
        const int ch = chbase + nf*16 + l15;
        bf[nf] = *(const bh8*)&qb[((size_t)b*512 + ch)*320 + h*80 + kc*32 + lg*8];
      }
      #pragma unroll
      for (int mt = 0; mt < 5; mt++){
        const bh8 a = *(const bh8*)&Am[(size_t)(mt*16+l15)*96 + kc*32 + lg*8];
        #pragma unroll
        for (int nf = 0; nf < 2; nf++)
          acc[mt][nf] = __builtin_amdgcn_mfma_f32_16x16x32_bf16(a, bf[nf], acc[mt][nf], 0, 0, 0);
      }
    }
  }
  #pragma unroll
  for (int mt = 0; mt < 5; mt++)
    #pragma unroll
    for (int nf = 0; nf < 2; nf++)
      #pragma unroll
      for (int r = 0; r < 4; r++){
        const int e = mt*16 + lg*4 + r;
        if (e < 75)
          merge[((size_t)b*300 + h*75 + e)*1024 + 512 + chbase + nf*16 + l15] = f2b(acc[mt][nf][r]);
      }
}

// ---------------- depthwise 3x3 + bias + leaky(0.01), channels-last, tap-major bf16 weights ----------------
__global__ __launch_bounds__(256)
void dw_kernel(const u16* __restrict__ e1, const u16* __restrict__ dwt,
               const float* __restrict__ bias, u16* __restrict__ d1)
{
  const int idx = blockIdx.x*256 + threadIdx.x;
  const int cg = idx & 63;
  const int sp = (idx >> 6) % 300;
  const int b  = idx / (64*300);
  const int c0 = cg*8;
  const int hh = sp / 15, ww = sp - hh*15;
  float acc[8];
  {
    const float4 b0 = *(const float4*)&bias[c0];
    const float4 b1 = *(const float4*)&bias[c0+4];
    acc[0]=b0.x; acc[1]=b0.y; acc[2]=b0.z; acc[3]=b0.w;
    acc[4]=b1.x; acc[5]=b1.y; acc[6]=b1.z; acc[7]=b1.w;
  }
  #pragma unroll
  for (int dy = -1; dy <= 1; dy++){
    const int h2 = hh + dy; if (h2 < 0 || h2 >= 20) continue;
    #pragma unroll
    for (int dx = -1; dx <= 1; dx++){
      const int w2 = ww + dx; if (w2 < 0 || w2 >= 15) continue;
      const bh8 vv = *(const bh8*)&e1[((size_t)b*300 + h2*15 + w2)*512 + c0];
      const int t = (dy+1)*3 + (dx+1);
      const bh8 wv = *(const bh8*)&dwt[t*512 + c0];
      #pragma unroll
      for (int j = 0; j < 8; j++)
        acc[j] += b2f((u16)vv[j]) * b2f((u16)wv[j]);
    }
  }
  bh8 ov;
  #pragma unroll
  for (int j = 0; j < 8; j++){
    float y = acc[j];
    y = (y >= 0.f) ? y : 0.01f*y;
    ov[j] = (short)f2b(y);
  }
  *(bh8*)&d1[((size_t)b*300 + sp)*512 + c0] = ov;
}

// ---------------- BN stats / finalize / final write ----------------
__global__ __launch_bounds__(256)
void stats_e(const float* __restrict__ e3, float* __restrict__ st){
  const int tid = threadIdx.x;
  const int c0 = tid*2;
  const size_t r0 = (size_t)blockIdx.x * 128;
  float s0=0,s1=0,q0=0,q1=0;
  for (int rr = 0; rr < 128; rr++){
    const float2 v = *(const float2*)&e3[(r0+rr)*512 + c0];
    s0 += v.x; s1 += v.y; q0 += v.x*v.x; q1 += v.y*v.y;
  }
  atomicAdd(&st[c0], s0); atomicAdd(&st[c0+1], s1);
  atomicAdd(&st[512+c0], q0); atomicAdd(&st[512+c0+1], q1);
}
__global__ void fin_e(float* st, const float* __restrict__ w, const float* __restrict__ b){
  const int c = threadIdx.x;
  const float m = st[c] * (1.f/19200.f);
  const float v = st[512+c] * (1.f/19200.f) - m*m;
  const float a = w[c] * rsqrtf(v + 1e-5f);
  st[1024+c] = a; st[1536+c] = b[c] - m*a;
}
__global__ __launch_bounds__(256)
void stats_o(const float* __restrict__ res, const float* __restrict__ e3, float* __restrict__ st){
  const int tid = threadIdx.x;
  const int c0 = tid*2;
  const float a0 = st[1024+c0], b0v = st[1536+c0];
  const float a1 = st[1024+c0+1], b1v = st[1536+c0+1];
  const size_t r0 = (size_t)blockIdx.x * 128;
  float s0=0,s1=0,q0=0,q1=0;
  for (int rr = 0; rr < 128; rr++){
    const size_t o2 = (r0+rr)*512 + c0;
    const float2 rv = *(const float2*)&res[o2];
    const float2 ev = *(const float2*)&e3[o2];
    const float v0 = rv.x + ev.x*a0 + b0v;
    const float v1 = rv.y + ev.y*a1 + b1v;
    s0 += v0; s1 += v1; q0 += v0*v0; q1 += v1*v1;
  }
  atomicAdd(&st[2048+c0], s0); atomicAdd(&st[2048+c0+1], s1);
  atomicAdd(&st[2560+c0], q0); atomicAdd(&st[2560+c0+1], q1);
}
__global__ void fin_o(float* st, const float* __restrict__ w, const float* __restrict__ b){
  const int c = threadIdx.x;
  const float m = st[2048+c] * (1.f/19200.f);
  const float v = st[2560+c] * (1.f/19200.f) - m*m;
  const float a = w[c] * rsqrtf(v + 1e-5f);
  st[3072+c] = a; st[3584+c] = b[c] - m*a;
}
__global__ __launch_bounds__(256)
void final_kernel(const float* __restrict__ res, const float* __restrict__ e3,
                  const float* __restrict__ st, float* __restrict__ outp)
{
  __shared__ float tile[64][65];
  const int spt = blockIdx.x, cht = blockIdx.y, b = blockIdx.z;
  const int tid = threadIdx.x;
  const int sp0 = spt*64, ch0 = cht*64;
  for (int idx = tid; idx < 4096; idx += 256){
    const int cl = idx & 63, sl = idx >> 6;
    const int sp = sp0 + sl;
    float v = 0.f;
    if (sp < 300){
      const size_t off = ((size_t)b*300 + sp)*512 + ch0 + cl;
      const int c = ch0 + cl;
      const float e = e3[off]*st[1024+c] + st[1536+c];
      v = (res[off] + e)*st[3072+c] + st[3584+c];
    }
    tile[sl][cl] = v;
  }
  __syncthreads();
  for (int idx = tid; idx < 4096; idx += 256){
    const int sl = idx & 63, cl = idx >> 6;
    const int sp = sp0 + sl;
    if (sp < 300)
      outp[((size_t)b*512 + ch0 + cl)*300 + sp] = tile[sl][cl];
  }
}

// ---------------- host ----------------
extern "C" void kernel_launch(void* const* d_in, const int* in_sizes, int n_in,
                              void* d_out, int out_size, void* d_ws, size_t ws_size,
                              hipStream_t stream)
{
  const float* x1    = (const float*)d_in[0];
  const float* x2    = (const float*)d_in[1];
  const float* cp1_w = (const float*)d_in[2];
  const float* cp1_b = (const float*)d_in[3];
  const float* ln1_w = (const float*)d_in[4];
  const float* ln1_b = (const float*)d_in[5];
  const float* cp2_w = (const float*)d_in[6];
  const float* cp2_b = (const float*)d_in[7];
  const float* ln2_w = (const float*)d_in[8];
  const float* ln2_b = (const float*)d_in[9];
  const float* skv1w = (const float*)d_in[10];
  const float* skv2w = (const float*)d_in[11];
  const float* ckv1w = (const float*)d_in[12];
  const float* ckv2w = (const float*)d_in[13];
  const float* resw  = (const float*)d_in[14];
  const float* ce1w  = (const float*)d_in[15];
  const float* ce1b  = (const float*)d_in[16];
  const float* dww   = (const float*)d_in[17];
  const float* dwb   = (const float*)d_in[18];
  const float* ce3w  = (const float*)d_in[19];
  const float* ce3b  = (const float*)d_in[20];
  const float* bnew  = (const float*)d_in[21];
  const float* bneb  = (const float*)d_in[22];
  const float* bnow  = (const float*)d_in[23];
  const float* bnob  = (const float*)d_in[24];
  float* out = (float*)d_out;
  char* ws = (char*)d_ws;

  const size_t SZ_T    = (size_t)19200*512*2;
  const size_t SZ_APRE = (size_t)19200*1024*2;
  const size_t SZ_CKV  = (size_t)32768*640*2;
  const size_t SZ_CT   = (size_t)64*512*320*2;
  const size_t SZ_F32  = (size_t)19200*512*4;

  size_t off = 0;
  auto AL = [&](size_t sz){ size_t r = off; off += (sz + 255) & ~(size_t)255; return r; };
  const size_t oR0 = AL(2*SZ_T);             // t1,t2 -> merge
  const size_t oR1 = AL(2*SZ_CKV);           // apre1,apre2 -> kv1,kv2 -> ckv1,ckv2
  const size_t oR2 = AL(2*SZ_T);             // s1,s2 -> e1,d1
  const size_t oR3 = AL(2*SZ_CT + 4096);     // cT1,cT2 -> e3(f32)
  const size_t oR4 = AL(SZ_F32);             // res f32
  const size_t oR5 = AL((size_t)2*64*8*64*64*2);  // c_sT
  const size_t oR6 = AL((size_t)2*64*4*80*96*2);  // c_cT
  const size_t oWcp1  = AL((size_t)1024*512*2);
  const size_t oWcp2  = AL((size_t)1024*512*2);
  const size_t oWskv1 = AL((size_t)1024*512*2);
  const size_t oWskv2 = AL((size_t)1024*512*2);
  const size_t oWckv1 = AL((size_t)640*320*2);
  const size_t oWckv2 = AL((size_t)640*320*2);
  const size_t oWresce = AL((size_t)1024*1024*2);  // [res(512) | ce1(512)] x K=1024
  const size_t oWce3  = AL((size_t)512*512*2);
  const size_t oWdw   = AL((size_t)9*512*2);
  const size_t oST    = AL(16384);
  (void)ws_size; (void)in_sizes; (void)n_in; (void)out_size;

  u16* t1    = (u16*)(ws + oR0);
  u16* t2    = (u16*)(ws + oR0 + SZ_T);
  u16* merge = (u16*)(ws + oR0);
  u16* apre1 = (u16*)(ws + oR1);
  u16* apre2 = (u16*)(ws + oR1 + SZ_APRE);
  u16* kv1   = apre1;
  u16* kv2   = apre2;
  u16* ckv1  = (u16*)(ws + oR1);
  u16* ckv2  = (u16*)(ws + oR1 + SZ_CKV);
  u16* s1    = (u16*)(ws + oR2);
  u16* s2    = (u16*)(ws + oR2 + SZ_T);
  u16* e1    = s1;
  u16* d1    = s2;
  u16* cT1   = (u16*)(ws + oR3);
  u16* cT2   = (u16*)(ws + oR3 + SZ_CT);
  u16* slack = (u16*)(ws + oR3 + 2*SZ_CT);
  float* e3  = (float*)(ws + oR3);
  float* resb = (float*)(ws + oR4);
  u16* csT   = (u16*)(ws + oR5);
  u16* ccT   = (u16*)(ws + oR6);
  u16* wcp1  = (u16*)(ws + oWcp1);
  u16* wcp2  = (u16*)(ws + oWcp2);
  u16* wskv1 = (u16*)(ws + oWskv1);
  u16* wskv2 = (u16*)(ws + oWskv2);
  u16* wckv1 = (u16*)(ws + oWckv1);
  u16* wckv2 = (u16*)(ws + oWckv2);
  u16* wresce = (u16*)(ws + oWresce);
  u16* wce3  = (u16*)(ws + oWce3);
  u16* wdw   = (u16*)(ws + oWdw);
  float* st  = (float*)(ws + oST);

  hipMemsetAsync(st, 0, 16384, stream);
  pad_zero<<<8,256,0,stream>>>(slack);
  pack_plain<<<2048,256,0,stream>>>(cp1_w, wcp1, 524288);
  pack_plain<<<2048,256,0,stream>>>(cp2_w, wcp2, 524288);
  pack_plain<<<2048,256,0,stream>>>(skv1w, wskv1, 524288);
  pack_plain<<<2048,256,0,stream>>>(skv2w, wskv2, 524288);
  pack_ckv_k<<<800,256,0,stream>>>(ckv1w, wckv1);
  pack_ckv_k<<<800,256,0,stream>>>(ckv2w, wckv2);
  pack_plain<<<2048,256,0,stream>>>(resw, wresce, 524288);
  pack_plain<<<2048,256,0,stream>>>(ce1w, wresce + 524288, 524288);
  pack_plain<<<1024,256,0,stream>>>(ce3w, wce3, 262144);
  pack_dw<<<18,256,0,stream>>>(dww, wdw);

  transpose_k<<<dim3(10,16,64),256,0,stream>>>(x1, t1);
  transpose_k<<<dim3(10,16,64),256,0,stream>>>(x2, t2);

  gemm_k<0,1><<<dim3(8,150),256,0,stream>>>(t1,512, wcp1,512, apre1,nullptr,1024, cp1_b, 512);
  gemm_k<0,1><<<dim3(8,150),256,0,stream>>>(t2,512, wcp2,512, apre2,nullptr,1024, cp2_b, 512);

  ln_kernel<<<dim3(256,2),256,0,stream>>>(apre1, ln1_w, ln1_b, s1, cT1);
  ln_kernel<<<dim3(256,2),256,0,stream>>>(apre2, ln2_w, ln2_b, s2, cT2);

  gemm_k<0,0><<<dim3(8,150),256,0,stream>>>(s1,512, wskv1,512, kv1,nullptr,1024, nullptr, 512);
  gemm_k<0,0><<<dim3(8,150),256,0,stream>>>(s2,512, wskv2,512, kv2,nullptr,1024, nullptr, 512);

  ctx_kernel<64,64,64><<<dim3(8,64,2),256,0,stream>>>(kv1, kv2, csT, 300, 1024, 512, 0.125f);

  gemm_k<0,0><<<dim3(5,256),256,0,stream>>>(cT1,320, wckv1,320, ckv1,nullptr,640, nullptr, 320);
  gemm_k<0,0><<<dim3(5,256),256,0,stream>>>(cT2,320, wckv2,320, ckv2,nullptr,640, nullptr, 320);

  ctx_kernel<80,75,96><<<dim3(4,64,2),256,0,stream>>>(ckv1, ckv2, ccT, 512, 640, 320, 0.115470054f);

  sp_out_kernel<<<dim3(8,64),256,0,stream>>>(s1, s2, csT, merge);
  ch_out_kernel<<<dim3(4,4,64),256,0,stream>>>(cT1, cT2, ccT, merge);

  // merged res (f32, cols 0..511) + ce1 (bf16+bias, cols 512..1023)
  gemm_k<2,0><<<dim3(8,150),256,0,stream>>>(merge,1024, wresce,1024, e1, resb, 512, ce1b, 1024);

  dw_kernel<<<4800,256,0,stream>>>(e1, wdw, dwb, d1);

  gemm_k<1,1><<<dim3(4,150),256,0,stream>>>(d1,512, wce3,512, nullptr,e3,512, ce3b, 512);

  stats_e<<<150,256,0,stream>>>(e3, st);
  fin_e<<<1,512,0,stream>>>(st, bnew, bneb);
  stats_o<<<150,256,0,stream>>>(resb, e3, st);
  fin_o<<<1,512,0,stream>>>(st, bnow, bnob);
  final_kernel<<<dim3(5,8,64),256,0,stream>>>(resb, e3, st, out);
}

// Round 7
// 547.131 us; speedup vs baseline: 1.6414x; 1.0921x over previous
//
#include <hip/hip_runtime.h>

typedef unsigned short u16;
typedef __attribute__((ext_vector_type(8))) short bh8;
typedef __attribute__((ext_vector_type(4))) float f4;

__device__ __forceinline__ u16 f2b(float f){
  unsigned int u = __float_as_uint(f);
  u += 0x7fffu + ((u >> 16) & 1u);
  return (u16)(u >> 16);
}
__device__ __forceinline__ float b2f(u16 h){
  return __uint_as_float(((unsigned int)h) << 16);
}
__device__ __forceinline__ void gl16(const u16* g, u16* l){
  __builtin_amdgcn_global_load_lds((const __attribute__((address_space(1))) void*)g,
                                   (__attribute__((address_space(3))) void*)l, 16, 0, 0);
}

// ---------------- packing ----------------
__global__ void pack_plain(const float* __restrict__ src, u16* __restrict__ dst, int count){
  int i = blockIdx.x*256 + threadIdx.x;
  if (i < count) dst[i] = f2b(src[i]);
}
// c_kv_w (600,300) -> padded [640][320]: n = t*320+h*80+dd, k = kh*80+kd
__global__ void pack_ckv_k(const float* __restrict__ src, u16* __restrict__ dst){
  int i = blockIdx.x*256 + threadIdx.x; // 640*320
  int nn = i / 320, kk = i - (i/320)*320;
  int t_ = (nn >= 320) ? 1 : 0;
  int rem = nn - t_*320;
  int hh = rem / 80, dd = rem - hh*80;
  int kh = kk / 80, kd = kk - kh*80;
  float v = 0.f;
  if (dd < 75 && kd < 75)
    v = src[(size_t)(t_*300 + hh*75 + dd)*300 + (kh*75 + kd)];
  dst[i] = f2b(v);
}
// dw weight (512,1,3,3) -> dwt[9][512] bf16 (tap-major, coalesced per-tap loads)
__global__ void pack_dw(const float* __restrict__ src, u16* __restrict__ dst){
  int i = blockIdx.x*256 + threadIdx.x; // 4608
  if (i < 4608){
    int t = i >> 9, c = i & 511;
    dst[i] = f2b(src[c*9 + t]);
  }
}
// zero the 4KiB slack after cT2 that ch_out's tail k-chunk over-reads (x0, but must be finite)
__global__ void pad_zero(u16* __restrict__ slack){
  const int j = blockIdx.x*256 + threadIdx.x;
  if (j < 2048) slack[j] = 0;
}

// ---------------- x (B,C,H,W) f32 -> t (B,N,C) bf16 ----------------
__global__ __launch_bounds__(256)
void transpose_k(const float* __restrict__ x, u16* __restrict__ t)
{
  __shared__ float tile[32][33];
  const int n0 = blockIdx.x * 32, c0 = blockIdx.y * 32, b = blockIdx.z;
  const int ln = threadIdx.x & 31, lr = threadIdx.x >> 5;
  #pragma unroll
  for (int q = 0; q < 4; q++) {
    const int c = c0 + lr + q*8, n = n0 + ln;
    tile[lr + q*8][ln] = (n < 300) ? x[((long)b*512 + c)*300 + n] : 0.f;
  }
  __syncthreads();
  #pragma unroll
  for (int q = 0; q < 4; q++) {
    const int n = n0 + lr + q*8;
    if (n < 300) t[((long)b*300 + n)*512 + c0 + ln] = f2b(tile[ln][lr + q*8]);
  }
}

// ---------------- generic 128x128 MFMA GEMM: C = A(M,K) @ Bw(N,K)^T ----------------
// 3-stage LDS pipeline with counted vmcnt(4) + raw s_barrier (never drains to 0 in loop).
// XCD-aware bijective block remap (nwg divisible by 8).
// Both-sides XOR LDS swizzle (bank-conflict-free ds_read_b128).
// Optional paired weights: rows >= mhalf use Bw2/bias2 (A and C contiguous across pair).
// OUTF: 0 = bf16 out (+bias if HASB); 1 = f32 out (+bias if HASB);
//       2 = split: n<512 -> f32 (no bias), n>=512 -> bf16 (+bias[cn-512])
template<int OUTF, int HASB>
__global__ __launch_bounds__(256)
void gemm_k(const u16* __restrict__ A, int lda,
            const u16* __restrict__ Bw, const u16* __restrict__ Bw2, int ldb, long mhalf,
            u16* __restrict__ Cb, float* __restrict__ Cf, int ldc,
            const float* __restrict__ bias, const float* __restrict__ bias2, int K)
{
  __shared__ u16 As[3][4096];
  __shared__ u16 Bs[3][4096];
  const int tid = threadIdx.x;
  const int gx = gridDim.x;
  const int nwg = gx * gridDim.y;
  const int flat = blockIdx.y * gx + blockIdx.x;
  const int newid = (flat & 7) * (nwg >> 3) + (flat >> 3);
  const long n0 = (long)(newid % gx) * 128;
  const long m0 = (long)(newid / gx) * 128;
  const u16* Bwp = Bw; const float* bp = bias;
  if (Bw2 != nullptr && m0 >= mhalf){ Bwp = Bw2; bp = bias2; }
  const int wave = tid >> 6, lane = tid & 63;
  const int l15 = lane & 15, lg = lane >> 4;
  const int wr = (wave >> 1) * 64, wc = (wave & 1) * 64;
  const int arow = tid >> 2;
  const int aseg = (((tid & 3) ^ ((arow >> 1) & 3))) * 8;  // pre-swizzled global segment
  const u16* Ag0 = A + (m0 + arow) * (long)lda + aseg;
  const u16* Ag1 = Ag0 + 64L * lda;
  const u16* Bg0 = Bwp + (n0 + arow) * (long)ldb + aseg;
  const u16* Bg1 = Bg0 + 64L * ldb;
  const int to8 = tid * 8;
  // swizzled LDS read offsets (elements), loop-invariant per lane
  int roA[4], roB[4];
  #pragma unroll
  for (int i = 0; i < 4; i++){
    const int rA = wr + i*16 + l15;
    roA[i] = rA*32 + ((lg ^ ((rA >> 1) & 3)) * 8);
    const int rB = wc + i*16 + l15;
    roB[i] = rB*32 + ((lg ^ ((rB >> 1) & 3)) * 8);
  }
  f4 acc[4][4] = {};
  const int NT = K >> 5;
  // prologue: stages 0,1 in flight (8 loads)
  {
    gl16(Ag0, &As[0][to8]); gl16(Ag1, &As[0][2048 + to8]);
    gl16(Bg0, &Bs[0][to8]); gl16(Bg1, &Bs[0][2048 + to8]);
    gl16(Ag0 + 32, &As[1][to8]); gl16(Ag1 + 32, &As[1][2048 + to8]);
    gl16(Bg0 + 32, &Bs[1][to8]); gl16(Bg1 + 32, &Bs[1][2048 + to8]);
  }
  int rd = 0;
  for (int t = 0; t < NT; t++) {
    if (t < NT - 1) { asm volatile("s_waitcnt vmcnt(4)" ::: "memory"); }
    else            { asm volatile("s_waitcnt vmcnt(0)" ::: "memory"); }
    __builtin_amdgcn_sched_barrier(0);
    __builtin_amdgcn_s_barrier();
    __builtin_amdgcn_sched_barrier(0);
    if (t + 2 < NT) {
      int wb = rd + 2; if (wb >= 3) wb -= 3;
      const int kt = (t + 2) << 5;
      gl16(Ag0 + kt, &As[wb][to8]); gl16(Ag1 + kt, &As[wb][2048 + to8]);
      gl16(Bg0 + kt, &Bs[wb][to8]); gl16(Bg1 + kt, &Bs[wb][2048 + to8]);
    }
    bh8 af[4], bf[4];
    #pragma unroll
    for (int mi = 0; mi < 4; mi++) af[mi] = *(const bh8*)&As[rd][roA[mi]];
    #pragma unroll
    for (int ni = 0; ni < 4; ni++) bf[ni] = *(const bh8*)&Bs[rd][roB[ni]];
    #pragma unroll
    for (int mi = 0; mi < 4; mi++)
      #pragma unroll
      for (int ni = 0; ni < 4; ni++)
        acc[mi][ni] = __builtin_amdgcn_mfma_f32_16x16x32_bf16(af[mi], bf[ni], acc[mi][ni], 0, 0, 0);
    rd++; if (rd == 3) rd = 0;
  }
  if (OUTF == 2) {
    if (n0 < 512) {
      #pragma unroll
      for (int ni = 0; ni < 4; ni++) {
        const long cn = n0 + wc + ni*16 + l15;
        #pragma unroll
        for (int mi = 0; mi < 4; mi++)
          #pragma unroll
          for (int r = 0; r < 4; r++) {
            const long cm = m0 + wr + mi*16 + lg*4 + r;
            Cf[cm * ldc + cn] = acc[mi][ni][r];
          }
      }
    } else {
      #pragma unroll
      for (int ni = 0; ni < 4; ni++) {
        const long cn = n0 - 512 + wc + ni*16 + l15;
        const float bv = bias[cn];
        #pragma unroll
        for (int mi = 0; mi < 4; mi++)
          #pragma unroll
          for (int r = 0; r < 4; r++) {
            const long cm = m0 + wr + mi*16 + lg*4 + r;
            Cb[cm * ldc + cn] = f2b(acc[mi][ni][r] + bv);
          }
      }
    }
  } else {
    #pragma unroll
    for (int ni = 0; ni < 4; ni++) {
      const long cn = n0 + wc + ni*16 + l15;
      const float bv = HASB ? bp[cn] : 0.0f;
      #pragma unroll
      for (int mi = 0; mi < 4; mi++) {
        #pragma unroll
        for (int r = 0; r < 4; r++) {
          const long cm = m0 + wr + mi*16 + lg*4 + r;
          const float v = acc[mi][ni][r] + bv;
          if (OUTF) Cf[cm * ldc + cn] = v;
          else      Cb[cm * ldc + cn] = f2b(v);
        }
      }
    }
  }
}

// ---------------- LayerNorm(1024) + relu; split into s (B,N,512) coalesced and
// cT (B,512,320pad) via LDS block-transpose (coalesced 16B chunks along nn) ----------------
__global__ __launch_bounds__(256)
void ln_kernel(const u16* __restrict__ apre, const float* __restrict__ lw, const float* __restrict__ lb,
               u16* __restrict__ s, u16* __restrict__ cT)
{
  __shared__ u16 tile[40][520];   // pitch 520: rows 16B-aligned
  const int bh = blockIdx.x;      // b*4 + h
  const int b = bh >> 2, h = bh & 3;
  const int z = blockIdx.y;
  const int dd0 = z ? 40 : 0;
  const int ndd = z ? 35 : 40;    // z=0: dd 0..39 (segs 0..4), z=1: dd 40..74 (+pad 75..79, segs 5..9)
  const int segbase = z ? 5 : 0;
  const int tid = threadIdx.x, w = tid >> 6, lane = tid & 63;
  const int r0 = b*300 + h*75 + dd0;
  for (int dl = w; dl < ndd; dl += 4){
    const int r = r0 + dl;
    const u16* row = apre + (size_t)r*1024 + lane*8;
    const bh8 vc = *(const bh8*)row;          // c-half cols lane*8..+7
    const bh8 vs = *(const bh8*)(row + 512);  // s-half
    float fc[8], fs[8];
    float sm = 0.f, sq = 0.f;
    #pragma unroll
    for (int j = 0; j < 8; j++){
      fc[j] = b2f((u16)vc[j]); fs[j] = b2f((u16)vs[j]);
      sm += fc[j] + fs[j];
      sq += fc[j]*fc[j] + fs[j]*fs[j];
    }
    #pragma unroll
    for (int o = 32; o; o >>= 1){ sm += __shfl_xor(sm, o); sq += __shfl_xor(sq, o); }
    const float mean = sm * (1.f/1024.f);
    const float rstd = rsqrtf(sq*(1.f/1024.f) - mean*mean + 1e-5f);
    bh8 oc, os;
    #pragma unroll
    for (int j = 0; j < 8; j++){
      const int c = lane*8 + j;
      const float y1 = (fc[j]-mean)*rstd*lw[c] + lb[c];
      oc[j] = (short)f2b(fmaxf(y1, 0.f));
      const float y2 = (fs[j]-mean)*rstd*lw[512+c] + lb[512+c];
      os[j] = (short)f2b(fmaxf(y2, 0.f));
    }
    *(bh8*)&tile[dl][lane*8] = oc;
    *(bh8*)&s[(size_t)r*512 + lane*8] = os;
  }
  __syncthreads();
  for (int i = tid; i < 2560; i += 256){
    const int c = i / 5, sg = i - (i/5)*5;
    const int seg = segbase + sg;
    bh8 ov;
    #pragma unroll
    for (int j = 0; j < 8; j++){
      const int dl = seg*8 + j - dd0;
      ov[j] = (short)((dl >= 0 && dl < ndd) ? tile[dl][c] : (u16)0);
    }
    *(bh8*)&cT[((size_t)b*512 + c)*320 + h*80 + seg*8] = ov;
  }
}

// ---------------- attn ctx: out[e][d] = softmax_d( scale * sum_n k[n,d] v[n,e] ), stored transposed ----------------
template<int D, int DREAL, int OS>
__global__ __launch_bounds__(256)
void ctx_kernel(const u16* __restrict__ kva, const u16* __restrict__ kvb,
                u16* __restrict__ outp, int K, int RS, int VOFF, float scale)
{
  constexpr int NT = D/16, MT = D/16, MTL = (MT+3)/4, SEG = D/8;
  __shared__ u16 vT[D][40];
  __shared__ u16 kT[D][40];
  const int h = blockIdx.x, b = blockIdx.y, iq = blockIdx.z;
  const int Hn = gridDim.x;
  const u16* base = (iq ? kvb : kva) + (size_t)b*K*RS + h*D;
  u16* out = outp + (((size_t)iq*64 + b)*Hn + h)*(size_t)(D*OS);
  const int tid = threadIdx.x, w = tid >> 6, lane = tid & 63, l15 = lane & 15, lg = lane >> 4;
  f4 acc[MTL][NT] = {};
  for (int k0 = 0; k0 < K; k0 += 32) {
    __syncthreads();
    for (int sI = tid; sI < 32*SEG; sI += 256) {
      const int nn = sI / SEG, dseg = sI - (sI/SEG)*SEG;
      bh8 kk = {}, vv = {};
      const int krow = k0 + nn;
      if (krow < K) {
        const u16* p = base + (size_t)krow*RS + dseg*8;
        kk = *(const bh8*)p;
        vv = *(const bh8*)(p + VOFF);
      }
      #pragma unroll
      for (int j = 0; j < 8; j++){
        kT[dseg*8+j][nn] = (u16)kk[j];
        vT[dseg*8+j][nn] = (u16)vv[j];
      }
    }
    __syncthreads();
    #pragma unroll
    for (int ii = 0; ii < MTL; ii++){
      const int mt = w + ii*4;
      if (MT % 4 != 0 && mt >= MT) break;
      const bh8 a = *(const bh8*)&vT[mt*16 + l15][lg*8];
      #pragma unroll
      for (int nt = 0; nt < NT; nt++){
        const bh8 bb = *(const bh8*)&kT[nt*16 + l15][lg*8];
        acc[ii][nt] = __builtin_amdgcn_mfma_f32_16x16x32_bf16(a, bb, acc[ii][nt], 0, 0, 0);
      }
    }
  }
  #pragma unroll
  for (int ii = 0; ii < MTL; ii++){
    const int mt = w + ii*4;
    if (MT % 4 != 0 && mt >= MT) continue;
    #pragma unroll
    for (int r = 0; r < 4; r++){
      const int e = mt*16 + lg*4 + r;
      float xs[NT]; float mx = -1e30f;
      #pragma unroll
      for (int nt = 0; nt < NT; nt++){
        float x = acc[ii][nt][r] * scale;
        if (DREAL != D && (nt*16 + l15) >= DREAL) x = -1e30f;
        xs[nt] = x; mx = fmaxf(mx, x);
      }
      mx = fmaxf(mx, __shfl_xor(mx,1)); mx = fmaxf(mx, __shfl_xor(mx,2));
      mx = fmaxf(mx, __shfl_xor(mx,4)); mx = fmaxf(mx, __shfl_xor(mx,8));
      float smv = 0.f;
      #pragma unroll
      for (int nt = 0; nt < NT; nt++){
        const float p = (xs[nt] > -1e29f) ? __expf(xs[nt]-mx) : 0.f;
        xs[nt] = p; smv += p;
      }
      smv += __shfl_xor(smv,1); smv += __shfl_xor(smv,2);
      smv += __shfl_xor(smv,4); smv += __shfl_xor(smv,8);
      const float inv = 1.f / smv;
      #pragma unroll
      for (int nt = 0; nt < NT; nt++)
        out[(size_t)e*OS + nt*16 + l15] = f2b(xs[nt]*inv);
      if (OS > D) out[(size_t)e*OS + D + l15] = 0;
    }
  }
}

// ---------------- spatial out: merge[:, :512] = q1@c2 + q2@c1 ----------------
__global__ __launch_bounds__(256)
void sp_out_kernel(const u16* __restrict__ s1, const u16* __restrict__ s2,
                   const u16* __restrict__ csT, u16* __restrict__ merge)
{
  const int h = blockIdx.x, b = blockIdx.y;
  const int tid = threadIdx.x, w = tid >> 6, lane = tid & 63, l15 = lane & 15, lg = lane >> 4;
  const u16* c1 = csT + (((size_t)b)*8 + h)*4096;
  const u16* c2 = csT + (((size_t)64 + b)*8 + h)*4096;
  for (int mt = w; mt < 19; mt += 4) {
    const int m = mt*16 + l15;
    const bool mv = (m < 300);
    const u16* q1 = s1 + ((size_t)b*300 + m)*512 + h*64;
    const u16* q2 = s2 + ((size_t)b*300 + m)*512 + h*64;
    f4 acc[4] = {};
    #pragma unroll
    for (int kc = 0; kc < 2; kc++){
      bh8 a1 = {}, a2 = {};
      if (mv){ a1 = *(const bh8*)(q1 + kc*32 + lg*8); a2 = *(const bh8*)(q2 + kc*32 + lg*8); }
      #pragma unroll
      for (int nt = 0; nt < 4; nt++){
        const bh8 b2v = *(const bh8*)&c2[(size_t)(nt*16+l15)*64 + kc*32 + lg*8];
        acc[nt] = __builtin_amdgcn_mfma_f32_16x16x32_bf16(a1, b2v, acc[nt], 0, 0, 0);
        const bh8 b1v = *(const bh8*)&c1[(size_t)(nt*16+l15)*64 + kc*32 + lg*8];
        acc[nt] = __builtin_amdgcn_mfma_f32_16x16x32_bf16(a2, b1v, acc[nt], 0, 0, 0);
      }
    }
    #pragma unroll
    for (int nt = 0; nt < 4; nt++)
      #pragma unroll
      for (int r = 0; r < 4; r++){
        const int mm = mt*16 + lg*4 + r;
        if (mm < 300)
          merge[((size_t)b*300 + mm)*1024 + h*64 + nt*16 + l15] = f2b(acc[nt][r]);
      }
  }
}

// ---------------- channel out (transposed): merge[:, 512:] = (q1c@c2c + q2c@c1c)^T ----------------
__global__ __launch_bounds__(256)
void ch_out_kernel(const u16* __restrict__ cT1, const u16* __restrict__ cT2,
                   const u16* __restrict__ ccT, u16* __restrict__ merge)
{
  const int cb = blockIdx.x, h = blockIdx.y, b = blockIdx.z;
  const int tid = threadIdx.x, w = tid >> 6, lane = tid & 63, l15 = lane & 15, lg = lane >> 4;
  const int chbase = cb*128 + w*32;
  f4 acc[5][2] = {};
  #pragma unroll
  for (int oi = 0; oi < 2; oi++){
    const u16* Am = ccT + (((size_t)((oi==0)?1:0)*64 + b)*4 + h)*(size_t)(80*96);
    const u16* qb = (oi==0) ? cT1 : cT2;
    #pragma unroll
    for (int kc = 0; kc < 3; kc++){
      bh8 bf[2];
      #pragma unroll
      for (int nf = 0; nf < 2; nf++){
        const int ch = chbase + nf*16 + l15;
        bf[nf] = *(const bh8*)&qb[((size_t)b*512 + ch)*320 + h*80 + kc*32 + lg*8];
      }
      #pragma unroll
      for (int mt = 0; mt < 5; mt++){
        const bh8 a = *(const bh8*)&Am[(size_t)(mt*16+l15)*96 + kc*32 + lg*8];
        #pragma unroll
        for (int nf = 0; nf < 2; nf++)
          acc[mt][nf] = __builtin_amdgcn_mfma_f32_16x16x32_bf16(a, bf[nf], acc[mt][nf], 0, 0, 0);
      }
    }
  }
  #pragma unroll
  for (int mt = 0; mt < 5; mt++)
    #pragma unroll
    for (int nf = 0; nf < 2; nf++)
      #pragma unroll
      for (int r = 0; r < 4; r++){
        const int e = mt*16 + lg*4 + r;
        if (e < 75)
          merge[((size_t)b*300 + h*75 + e)*1024 + 512 + chbase + nf*16 + l15] = f2b(acc[mt][nf][r]);
      }
}

// ---------------- depthwise 3x3 + bias + leaky(0.01), channels-last, tap-major bf16 weights ----------------
__global__ __launch_bounds__(256)
void dw_kernel(const u16* __restrict__ e1, const u16* __restrict__ dwt,
               const float* __restrict__ bias, u16* __restrict__ d1)
{
  const int idx = blockIdx.x*256 + threadIdx.x;
  const int cg = idx & 63;
  const int sp = (idx >> 6) % 300;
  const int b  = idx / (64*300);
  const int c0 = cg*8;
  const int hh = sp / 15, ww = sp - hh*15;
  float acc[8];
  {
    const float4 b0 = *(const float4*)&bias[c0];
    const float4 b1 = *(const float4*)&bias[c0+4];
    acc[0]=b0.x; acc[1]=b0.y; acc[2]=b0.z; acc[3]=b0.w;
    acc[4]=b1.x; acc[5]=b1.y; acc[6]=b1.z; acc[7]=b1.w;
  }
  #pragma unroll
  for (int dy = -1; dy <= 1; dy++){
    const int h2 = hh + dy; if (h2 < 0 || h2 >= 20) continue;
    #pragma unroll
    for (int dx = -1; dx <= 1; dx++){
      const int w2 = ww + dx; if (w2 < 0 || w2 >= 15) continue;
      const bh8 vv = *(const bh8*)&e1[((size_t)b*300 + h2*15 + w2)*512 + c0];
      const int t = (dy+1)*3 + (dx+1);
      const bh8 wv = *(const bh8*)&dwt[t*512 + c0];
      #pragma unroll
      for (int j = 0; j < 8; j++)
        acc[j] += b2f((u16)vv[j]) * b2f((u16)wv[j]);
    }
  }
  bh8 ov;
  #pragma unroll
  for (int j = 0; j < 8; j++){
    float y = acc[j];
    y = (y >= 0.f) ? y : 0.01f*y;
    ov[j] = (short)f2b(y);
  }
  *(bh8*)&d1[((size_t)b*300 + sp)*512 + c0] = ov;
}

// ---------------- BN: one stats pass (5 sums), analytic finalize, final write ----------------
// st layout (floats): [0]=S_e [512]=Q_e [1024]=S_r [1536]=Q_r [2048]=X(=sum e3*res)
//                     [2560]=a_e [3072]=b_e [3584]=a_o [4096]=b_o
__global__ __launch_bounds__(256)
void stats_k(const float* __restrict__ e3, const float* __restrict__ res, float* __restrict__ st){
  const int tid = threadIdx.x;
  const int c0 = tid*2;
  const size_t r0 = (size_t)blockIdx.x * 128;
  float se0=0,se1=0,qe0=0,qe1=0,sr0=0,sr1=0,qr0=0,qr1=0,x0=0,x1=0;
  for (int rr = 0; rr < 128; rr++){
    const size_t o2 = (r0+rr)*512 + c0;
    const float2 ev = *(const float2*)&e3[o2];
    const float2 rv = *(const float2*)&res[o2];
    se0 += ev.x; se1 += ev.y; qe0 += ev.x*ev.x; qe1 += ev.y*ev.y;
    sr0 += rv.x; sr1 += rv.y; qr0 += rv.x*rv.x; qr1 += rv.y*rv.y;
    x0  += ev.x*rv.x; x1 += ev.y*rv.y;
  }
  atomicAdd(&st[c0], se0);      atomicAdd(&st[c0+1], se1);
  atomicAdd(&st[512+c0], qe0);  atomicAdd(&st[512+c0+1], qe1);
  atomicAdd(&st[1024+c0], sr0); atomicAdd(&st[1024+c0+1], sr1);
  atomicAdd(&st[1536+c0], qr0); atomicAdd(&st[1536+c0+1], qr1);
  atomicAdd(&st[2048+c0], x0);  atomicAdd(&st[2048+c0+1], x1);
}
__global__ void fin_k(float* st, const float* __restrict__ we, const float* __restrict__ be,
                      const float* __restrict__ wo, const float* __restrict__ bo){
  const int c = threadIdx.x;
  const float Nf = 19200.f, iN = 1.f/19200.f;
  const float Se = st[c], Qe = st[512+c], Sr = st[1024+c], Qr = st[1536+c], X = st[2048+c];
  const float me = Se*iN;
  const float ve = Qe*iN - me*me;
  const float ae = we[c]*rsqrtf(ve + 1e-5f);
  const float bev = be[c] - me*ae;
  const float So = Sr + ae*Se + Nf*bev;
  const float Qo = Qr + ae*ae*Qe + Nf*bev*bev + 2.f*ae*X + 2.f*bev*Sr + 2.f*ae*bev*Se;
  const float mo = So*iN;
  const float vo = Qo*iN - mo*mo;
  const float ao = wo[c]*rsqrtf(vo + 1e-5f);
  const float bov = bo[c] - mo*ao;
  st[2560+c] = ae; st[3072+c] = bev; st[3584+c] = ao; st[4096+c] = bov;
}
__global__ __launch_bounds__(256)
void final_kernel(const float* __restrict__ res, const float* __restrict__ e3,
                  const float* __restrict__ st, float* __restrict__ outp)
{
  __shared__ float tile[64][65];
  const int spt = blockIdx.x, cht = blockIdx.y, b = blockIdx.z;
  const int tid = threadIdx.x;
  const int sp0 = spt*64, ch0 = cht*64;
  for (int idx = tid; idx < 4096; idx += 256){
    const int cl = idx & 63, sl = idx >> 6;
    const int sp = sp0 + sl;
    float v = 0.f;
    if (sp < 300){
      const size_t off = ((size_t)b*300 + sp)*512 + ch0 + cl;
      const int c = ch0 + cl;
      const float e = e3[off]*st[2560+c] + st[3072+c];
      v = (res[off] + e)*st[3584+c] + st[4096+c];
    }
    tile[sl][cl] = v;
  }
  __syncthreads();
  for (int idx = tid; idx < 4096; idx += 256){
    const int sl = idx & 63, cl = idx >> 6;
    const int sp = sp0 + sl;
    if (sp < 300)
      outp[((size_t)b*512 + ch0 + cl)*300 + sp] = tile[sl][cl];
  }
}

// ---------------- host ----------------
extern "C" void kernel_launch(void* const* d_in, const int* in_sizes, int n_in,
                              void* d_out, int out_size, void* d_ws, size_t ws_size,
                              hipStream_t stream)
{
  const float* x1    = (const float*)d_in[0];
  const float* x2    = (const float*)d_in[1];
  const float* cp1_w = (const float*)d_in[2];
  const float* cp1_b = (const float*)d_in[3];
  const float* ln1_w = (const float*)d_in[4];
  const float* ln1_b = (const float*)d_in[5];
  const float* cp2_w = (const float*)d_in[6];
  const float* cp2_b = (const float*)d_in[7];
  const float* ln2_w = (const float*)d_in[8];
  const float* ln2_b = (const float*)d_in[9];
  const float* skv1w = (const float*)d_in[10];
  const float* skv2w = (const float*)d_in[11];
  const float* ckv1w = (const float*)d_in[12];
  const float* ckv2w = (const float*)d_in[13];
  const float* resw  = (const float*)d_in[14];
  const float* ce1w  = (const float*)d_in[15];
  const float* ce1b  = (const float*)d_in[16];
  const float* dww   = (const float*)d_in[17];
  const float* dwb   = (const float*)d_in[18];
  const float* ce3w  = (const float*)d_in[19];
  const float* ce3b  = (const float*)d_in[20];
  const float* bnew  = (const float*)d_in[21];
  const float* bneb  = (const float*)d_in[22];
  const float* bnow  = (const float*)d_in[23];
  const float* bnob  = (const float*)d_in[24];
  float* out = (float*)d_out;
  char* ws = (char*)d_ws;

  const size_t SZ_T    = (size_t)19200*512*2;
  const size_t SZ_APRE = (size_t)19200*1024*2;
  const size_t SZ_CKV  = (size_t)32768*640*2;
  const size_t SZ_CT   = (size_t)64*512*320*2;
  const size_t SZ_F32  = (size_t)19200*512*4;

  size_t off = 0;
  auto AL = [&](size_t sz){ size_t r = off; off += (sz + 255) & ~(size_t)255; return r; };
  const size_t oR0 = AL(2*SZ_T);             // t1,t2 -> merge
  const size_t oR1 = AL(2*SZ_CKV);           // apre1,apre2 -> kv1,kv2 -> ckv1,ckv2
  const size_t oR2 = AL(2*SZ_T);             // s1,s2 -> e1,d1
  const size_t oR3 = AL(2*SZ_CT + 4096);     // cT1,cT2 -> e3(f32)
  const size_t oR4 = AL(SZ_F32);             // res f32
  const size_t oR5 = AL((size_t)2*64*8*64*64*2);  // c_sT
  const size_t oR6 = AL((size_t)2*64*4*80*96*2);  // c_cT
  const size_t oWcp1  = AL((size_t)1024*512*2);
  const size_t oWcp2  = AL((size_t)1024*512*2);
  const size_t oWskv1 = AL((size_t)1024*512*2);
  const size_t oWskv2 = AL((size_t)1024*512*2);
  const size_t oWckv1 = AL((size_t)640*320*2);
  const size_t oWckv2 = AL((size_t)640*320*2);
  const size_t oWresce = AL((size_t)1024*1024*2);  // [res(512) | ce1(512)] x K=1024
  const size_t oWce3  = AL((size_t)512*512*2);
  const size_t oWdw   = AL((size_t)9*512*2);
  const size_t oST    = AL(20480);
  (void)ws_size; (void)in_sizes; (void)n_in; (void)out_size;

  u16* t1    = (u16*)(ws + oR0);
  u16* merge = (u16*)(ws + oR0);
  u16* apre1 = (u16*)(ws + oR1);
  u16* ckv1  = (u16*)(ws + oR1);
  u16* s1    = (u16*)(ws + oR2);
  u16* s2    = (u16*)(ws + oR2 + SZ_T);
  u16* e1    = s1;
  u16* d1    = s2;
  u16* cT1   = (u16*)(ws + oR3);
  u16* cT2   = (u16*)(ws + oR3 + SZ_CT);
  u16* slack = (u16*)(ws + oR3 + 2*SZ_CT);
  float* e3  = (float*)(ws + oR3);
  float* resb = (float*)(ws + oR4);
  u16* csT   = (u16*)(ws + oR5);
  u16* ccT   = (u16*)(ws + oR6);
  u16* wcp1  = (u16*)(ws + oWcp1);
  u16* wcp2  = (u16*)(ws + oWcp2);
  u16* wskv1 = (u16*)(ws + oWskv1);
  u16* wskv2 = (u16*)(ws + oWskv2);
  u16* wckv1 = (u16*)(ws + oWckv1);
  u16* wckv2 = (u16*)(ws + oWckv2);
  u16* wresce = (u16*)(ws + oWresce);
  u16* wce3  = (u16*)(ws + oWce3);
  u16* wdw   = (u16*)(ws + oWdw);
  float* st  = (float*)(ws + oST);

  u16* t2    = t1 + 19200*512;        // contiguous after t1
  u16* kv1   = apre1;
  u16* ckv2  = ckv1 + (size_t)32768*640;

  hipMemsetAsync(st, 0, 10240, stream);
  pad_zero<<<8,256,0,stream>>>(slack);
  pack_plain<<<2048,256,0,stream>>>(cp1_w, wcp1, 524288);
  pack_plain<<<2048,256,0,stream>>>(cp2_w, wcp2, 524288);
  pack_plain<<<2048,256,0,stream>>>(skv1w, wskv1, 524288);
  pack_plain<<<2048,256,0,stream>>>(skv2w, wskv2, 524288);
  pack_ckv_k<<<800,256,0,stream>>>(ckv1w, wckv1);
  pack_ckv_k<<<800,256,0,stream>>>(ckv2w, wckv2);
  pack_plain<<<2048,256,0,stream>>>(resw, wresce, 524288);
  pack_plain<<<2048,256,0,stream>>>(ce1w, wresce + 524288, 524288);
  pack_plain<<<1024,256,0,stream>>>(ce3w, wce3, 262144);
  pack_dw<<<18,256,0,stream>>>(dww, wdw);

  transpose_k<<<dim3(10,16,64),256,0,stream>>>(x1, t1);
  transpose_k<<<dim3(10,16,64),256,0,stream>>>(x2, t2);

  // cp1+cp2 batched: A = [t1;t2] (38400,512), weight/bias switch at row 19200
  gemm_k<0,1><<<dim3(8,300),256,0,stream>>>(t1,512, wcp1,wcp2,512, 19200L,
                                            apre1,nullptr,1024, cp1_b,cp2_b, 512);

  ln_kernel<<<dim3(256,2),256,0,stream>>>(apre1, ln1_w, ln1_b, s1, cT1);
  ln_kernel<<<dim3(256,2),256,0,stream>>>(apre1 + (size_t)19200*1024, ln2_w, ln2_b, s2, cT2);

  // skv1+skv2 batched: A = [s1;s2], out = [kv1;kv2] (contiguous)
  gemm_k<0,0><<<dim3(8,300),256,0,stream>>>(s1,512, wskv1,wskv2,512, 19200L,
                                            kv1,nullptr,1024, nullptr,nullptr, 512);

  ctx_kernel<64,64,64><<<dim3(8,64,2),256,0,stream>>>(kv1, kv1 + (size_t)19200*1024, csT, 300, 1024, 512, 0.125f);

  // ckv1+ckv2 batched: A = [cT1;cT2] (65536,320), out = [ckv1;ckv2]
  gemm_k<0,0><<<dim3(5,512),256,0,stream>>>(cT1,320, wckv1,wckv2,320, 32768L,
                                            ckv1,nullptr,640, nullptr,nullptr, 320);

  ctx_kernel<80,75,96><<<dim3(4,64,2),256,0,stream>>>(ckv1, ckv2, ccT, 512, 640, 320, 0.115470054f);

  sp_out_kernel<<<dim3(8,64),256,0,stream>>>(s1, s2, csT, merge);
  ch_out_kernel<<<dim3(4,4,64),256,0,stream>>>(cT1, cT2, ccT, merge);

  // merged res (f32, cols 0..511) + ce1 (bf16+bias, cols 512..1023)
  gemm_k<2,0><<<dim3(8,150),256,0,stream>>>(merge,1024, wresce,nullptr,1024, (long)1<<40,
                                            e1, resb, 512, ce1b,nullptr, 1024);

  dw_kernel<<<4800,256,0,stream>>>(e1, wdw, dwb, d1);

  gemm_k<1,1><<<dim3(4,150),256,0,stream>>>(d1,512, wce3,nullptr,512, (long)1<<40,
                                            nullptr,e3,512, ce3b,nullptr, 512);

  stats_k<<<150,256,0,stream>>>(e3, resb, st);
  fin_k<<<1,512,0,stream>>>(st, bnew, bneb, bnow, bnob);
  final_kernel<<<dim3(5,8,64),256,0,stream>>>(resb, e3, st, out);
}

// Round 8
// 544.113 us; speedup vs baseline: 1.6505x; 1.0055x over previous
//
#include <hip/hip_runtime.h>

typedef unsigned short u16;
typedef __attribute__((ext_vector_type(8))) short bh8;
typedef __attribute__((ext_vector_type(4))) float f4;

__device__ __forceinline__ u16 f2b(float f){
  unsigned int u = __float_as_uint(f);
  u += 0x7fffu + ((u >> 16) & 1u);
  return (u16)(u >> 16);
}
__device__ __forceinline__ float b2f(u16 h){
  return __uint_as_float(((unsigned int)h) << 16);
}
__device__ __forceinline__ void gl16(const u16* g, u16* l){
  __builtin_amdgcn_global_load_lds((const __attribute__((address_space(1))) void*)g,
                                   (__attribute__((address_space(3))) void*)l, 16, 0, 0);
}

// ---------------- packing ----------------
__global__ void pack_plain(const float* __restrict__ src, u16* __restrict__ dst, int count){
  int i = blockIdx.x*256 + threadIdx.x;
  if (i < count) dst[i] = f2b(src[i]);
}
// c_kv_w (600,300) -> padded [640][320]: n = t*320+h*80+dd, k = kh*80+kd
__global__ void pack_ckv_k(const float* __restrict__ src, u16* __restrict__ dst){
  int i = blockIdx.x*256 + threadIdx.x; // 640*320
  int nn = i / 320, kk = i - (i/320)*320;
  int t_ = (nn >= 320) ? 1 : 0;
  int rem = nn - t_*320;
  int hh = rem / 80, dd = rem - hh*80;
  int kh = kk / 80, kd = kk - kh*80;
  float v = 0.f;
  if (dd < 75 && kd < 75)
    v = src[(size_t)(t_*300 + hh*75 + dd)*300 + (kh*75 + kd)];
  dst[i] = f2b(v);
}
// dw weight (512,1,3,3) -> dwt[9][512] bf16 (tap-major, coalesced per-tap loads)
__global__ void pack_dw(const float* __restrict__ src, u16* __restrict__ dst){
  int i = blockIdx.x*256 + threadIdx.x; // 4608
  if (i < 4608){
    int t = i >> 9, c = i & 511;
    dst[i] = f2b(src[c*9 + t]);
  }
}
// zero the 4KiB slack after cT2 that ch_out's tail k-chunk over-reads (x0, but must be finite)
__global__ void pad_zero(u16* __restrict__ slack){
  const int j = blockIdx.x*256 + threadIdx.x;
  if (j < 2048) slack[j] = 0;
}

// ---------------- x (B,C,H,W) f32 -> t (B,N,C) bf16 ----------------
__global__ __launch_bounds__(256)
void transpose_k(const float* __restrict__ x, u16* __restrict__ t)
{
  __shared__ float tile[32][33];
  const int n0 = blockIdx.x * 32, c0 = blockIdx.y * 32, b = blockIdx.z;
  const int ln = threadIdx.x & 31, lr = threadIdx.x >> 5;
  #pragma unroll
  for (int q = 0; q < 4; q++) {
    const int c = c0 + lr + q*8, n = n0 + ln;
    tile[lr + q*8][ln] = (n < 300) ? x[((long)b*512 + c)*300 + n] : 0.f;
  }
  __syncthreads();
  #pragma unroll
  for (int q = 0; q < 4; q++) {
    const int n = n0 + lr + q*8;
    if (n < 300) t[((long)b*300 + n)*512 + c0 + ln] = f2b(tile[ln][lr + q*8]);
  }
}

// ---------------- 256x128 MFMA GEMM: C = A(M,K) @ Bw(N,K)^T ----------------
// 8 waves (512 thr), per-wave 64x64 (4x4 fragments). 3-stage LDS pipeline,
// counted vmcnt(3) + raw s_barrier (never drains to 0 in loop). LDS 72KB -> 2 blocks/CU.
// Bijective XCD-aware block remap (any nwg). Both-sides XOR LDS swizzle.
// Optional paired weights: m-tiles >= mhalf use Bw2/bias2.
// OUTF: 0 = bf16 out (+bias if HASB); 1 = f32 out (+bias if HASB);
//       2 = split: n<512 -> f32 (no bias), n>=512 -> bf16 (+bias[cn-512])
template<int OUTF, int HASB>
__global__ __launch_bounds__(512)
void gemm_k(const u16* __restrict__ A, int lda,
            const u16* __restrict__ Bw, const u16* __restrict__ Bw2, int ldb, long mhalf,
            u16* __restrict__ Cb, float* __restrict__ Cf, int ldc,
            const float* __restrict__ bias, const float* __restrict__ bias2, int K)
{
  __shared__ u16 As[3][8192];   // 256 x 32 per stage
  __shared__ u16 Bs[3][4096];   // 128 x 32 per stage
  const int tid = threadIdx.x;
  const int gx = gridDim.x;
  const int nwg = gx * gridDim.y;
  const int flat = blockIdx.y * gx + blockIdx.x;
  // m204 general bijective XCD remap
  const int qq = nwg >> 3, rr = nwg & 7, xcd = flat & 7, lin = flat >> 3;
  const int newid = (xcd < rr ? xcd*(qq+1) : rr*(qq+1) + (xcd-rr)*qq) + lin;
  const long n0 = (long)(newid % gx) * 128;
  const long m0 = (long)(newid / gx) * 256;
  const u16* Bwp = Bw; const float* bp = bias;
  if (Bw2 != nullptr && m0 >= mhalf){ Bwp = Bw2; bp = bias2; }
  const int wave = tid >> 6, lane = tid & 63;
  const int l15 = lane & 15, lg = lane >> 4;
  const int wr = (wave >> 1) * 64, wc = (wave & 1) * 64;
  // staging: A chunks q*512+tid -> row q*128+(tid>>2), col-chunk tid&3 (linear LDS);
  // global col-chunk pre-swizzled by row bits (involution matches read XOR).
  const int arow = tid >> 2;
  const int aseg = ((tid & 3) ^ ((arow >> 1) & 3)) * 8;
  const u16* Ag0 = A + (m0 + arow) * (long)lda + aseg;          // q=0: rows 0..127
  const u16* Ag1 = A + (m0 + 128 + arow) * (long)lda + aseg;    // q=1: rows 128..255 (same swz bits)
  const u16* Bg0 = Bwp + (n0 + arow) * (long)ldb + aseg;        // rows 0..127
  const int to8 = tid * 8;
  // swizzled LDS read offsets (elements), loop-invariant per lane
  int roA[4], roB[4];
  #pragma unroll
  for (int i = 0; i < 4; i++){
    const int rA = wr + i*16 + l15;
    roA[i] = rA*32 + ((lg ^ ((rA >> 1) & 3)) * 8);
    const int rB = wc + i*16 + l15;
    roB[i] = rB*32 + ((lg ^ ((rB >> 1) & 3)) * 8);
  }
  f4 acc[4][4] = {};
  const int NT = K >> 5;
  // prologue: stages 0,1 in flight (6 loads/thread)
  {
    gl16(Ag0, &As[0][to8]); gl16(Ag1, &As[0][4096 + to8]); gl16(Bg0, &Bs[0][to8]);
    gl16(Ag0 + 32, &As[1][to8]); gl16(Ag1 + 32, &As[1][4096 + to8]); gl16(Bg0 + 32, &Bs[1][to8]);
  }
  int rd = 0;
  for (int t = 0; t < NT; t++) {
    if (t < NT - 1) { asm volatile("s_waitcnt vmcnt(3)" ::: "memory"); }
    else            { asm volatile("s_waitcnt vmcnt(0)" ::: "memory"); }
    __builtin_amdgcn_sched_barrier(0);
    __builtin_amdgcn_s_barrier();
    __builtin_amdgcn_sched_barrier(0);
    if (t + 2 < NT) {
      int wb = rd + 2; if (wb >= 3) wb -= 3;
      const int kt = (t + 2) << 5;
      gl16(Ag0 + kt, &As[wb][to8]); gl16(Ag1 + kt, &As[wb][4096 + to8]); gl16(Bg0 + kt, &Bs[wb][to8]);
    }
    bh8 af[4], bf[4];
    #pragma unroll
    for (int mi = 0; mi < 4; mi++) af[mi] = *(const bh8*)&As[rd][roA[mi]];
    #pragma unroll
    for (int ni = 0; ni < 4; ni++) bf[ni] = *(const bh8*)&Bs[rd][roB[ni]];
    #pragma unroll
    for (int mi = 0; mi < 4; mi++)
      #pragma unroll
      for (int ni = 0; ni < 4; ni++)
        acc[mi][ni] = __builtin_amdgcn_mfma_f32_16x16x32_bf16(af[mi], bf[ni], acc[mi][ni], 0, 0, 0);
    rd++; if (rd == 3) rd = 0;
  }
  if (OUTF == 2) {
    if (n0 < 512) {
      #pragma unroll
      for (int ni = 0; ni < 4; ni++) {
        const long cn = n0 + wc + ni*16 + l15;
        #pragma unroll
        for (int mi = 0; mi < 4; mi++)
          #pragma unroll
          for (int r = 0; r < 4; r++) {
            const long cm = m0 + wr + mi*16 + lg*4 + r;
            Cf[cm * ldc + cn] = acc[mi][ni][r];
          }
      }
    } else {
      #pragma unroll
      for (int ni = 0; ni < 4; ni++) {
        const long cn = n0 - 512 + wc + ni*16 + l15;
        const float bv = bias[cn];
        #pragma unroll
        for (int mi = 0; mi < 4; mi++)
          #pragma unroll
          for (int r = 0; r < 4; r++) {
            const long cm = m0 + wr + mi*16 + lg*4 + r;
            Cb[cm * ldc + cn] = f2b(acc[mi][ni][r] + bv);
          }
      }
    }
  } else {
    #pragma unroll
    for (int ni = 0; ni < 4; ni++) {
      const long cn = n0 + wc + ni*16 + l15;
      const float bv = HASB ? bp[cn] : 0.0f;
      #pragma unroll
      for (int mi = 0; mi < 4; mi++) {
        #pragma unroll
        for (int r = 0; r < 4; r++) {
          const long cm = m0 + wr + mi*16 + lg*4 + r;
          const float v = acc[mi][ni][r] + bv;
          if (OUTF) Cf[cm * ldc + cn] = v;
          else      Cb[cm * ldc + cn] = f2b(v);
        }
      }
    }
  }
}

// ---------------- LayerNorm(1024) + relu; split into s (B,N,512) coalesced and
// cT (B,512,320pad) via LDS block-transpose (coalesced 16B chunks along nn) ----------------
__global__ __launch_bounds__(256)
void ln_kernel(const u16* __restrict__ apre, const float* __restrict__ lw, const float* __restrict__ lb,
               u16* __restrict__ s, u16* __restrict__ cT)
{
  __shared__ u16 tile[40][520];   // pitch 520: rows 16B-aligned
  const int bh = blockIdx.x;      // b*4 + h
  const int b = bh >> 2, h = bh & 3;
  const int z = blockIdx.y;
  const int dd0 = z ? 40 : 0;
  const int ndd = z ? 35 : 40;    // z=0: dd 0..39 (segs 0..4), z=1: dd 40..74 (+pad 75..79, segs 5..9)
  const int segbase = z ? 5 : 0;
  const int tid = threadIdx.x, w = tid >> 6, lane = tid & 63;
  const int r0 = b*300 + h*75 + dd0;
  for (int dl = w; dl < ndd; dl += 4){
    const int r = r0 + dl;
    const u16* row = apre + (size_t)r*1024 + lane*8;
    const bh8 vc = *(const bh8*)row;          // c-half cols lane*8..+7
    const bh8 vs = *(const bh8*)(row + 512);  // s-half
    float fc[8], fs[8];
    float sm = 0.f, sq = 0.f;
    #pragma unroll
    for (int j = 0; j < 8; j++){
      fc[j] = b2f((u16)vc[j]); fs[j] = b2f((u16)vs[j]);
      sm += fc[j] + fs[j];
      sq += fc[j]*fc[j] + fs[j]*fs[j];
    }
    #pragma unroll
    for (int o = 32; o; o >>= 1){ sm += __shfl_xor(sm, o); sq += __shfl_xor(sq, o); }
    const float mean = sm * (1.f/1024.f);
    const float rstd = rsqrtf(sq*(1.f/1024.f) - mean*mean + 1e-5f);
    bh8 oc, os;
    #pragma unroll
    for (int j = 0; j < 8; j++){
      const int c = lane*8 + j;
      const float y1 = (fc[j]-mean)*rstd*lw[c] + lb[c];
      oc[j] = (short)f2b(fmaxf(y1, 0.f));
      const float y2 = (fs[j]-mean)*rstd*lw[512+c] + lb[512+c];
      os[j] = (short)f2b(fmaxf(y2, 0.f));
    }
    *(bh8*)&tile[dl][lane*8] = oc;
    *(bh8*)&s[(size_t)r*512 + lane*8] = os;
  }
  __syncthreads();
  for (int i = tid; i < 2560; i += 256){
    const int c = i / 5, sg = i - (i/5)*5;
    const int seg = segbase + sg;
    bh8 ov;
    #pragma unroll
    for (int j = 0; j < 8; j++){
      const int dl = seg*8 + j - dd0;
      ov[j] = (short)((dl >= 0 && dl < ndd) ? tile[dl][c] : (u16)0);
    }
    *(bh8*)&cT[((size_t)b*512 + c)*320 + h*80 + seg*8] = ov;
  }
}

// ---------------- attn ctx: out[e][d] = softmax_d( scale * sum_n k[n,d] v[n,e] ), stored transposed ----------------
template<int D, int DREAL, int OS>
__global__ __launch_bounds__(256)
void ctx_kernel(const u16* __restrict__ kva, const u16* __restrict__ kvb,
                u16* __restrict__ outp, int K, int RS, int VOFF, float scale)
{
  constexpr int NT = D/16, MT = D/16, MTL = (MT+3)/4, SEG = D/8;
  __shared__ u16 vT[D][40];
  __shared__ u16 kT[D][40];
  const int h = blockIdx.x, b = blockIdx.y, iq = blockIdx.z;
  const int Hn = gridDim.x;
  const u16* base = (iq ? kvb : kva) + (size_t)b*K*RS + h*D;
  u16* out = outp + (((size_t)iq*64 + b)*Hn + h)*(size_t)(D*OS);
  const int tid = threadIdx.x, w = tid >> 6, lane = tid & 63, l15 = lane & 15, lg = lane >> 4;
  f4 acc[MTL][NT] = {};
  for (int k0 = 0; k0 < K; k0 += 32) {
    __syncthreads();
    for (int sI = tid; sI < 32*SEG; sI += 256) {
      const int nn = sI / SEG, dseg = sI - (sI/SEG)*SEG;
      bh8 kk = {}, vv = {};
      const int krow = k0 + nn;
      if (krow < K) {
        const u16* p = base + (size_t)krow*RS + dseg*8;
        kk = *(const bh8*)p;
        vv = *(const bh8*)(p + VOFF);
      }
      #pragma unroll
      for (int j = 0; j < 8; j++){
        kT[dseg*8+j][nn] = (u16)kk[j];
        vT[dseg*8+j][nn] = (u16)vv[j];
      }
    }
    __syncthreads();
    #pragma unroll
    for (int ii = 0; ii < MTL; ii++){
      const int mt = w + ii*4;
      if (MT % 4 != 0 && mt >= MT) break;
      const bh8 a = *(const bh8*)&vT[mt*16 + l15][lg*8];
      #pragma unroll
      for (int nt = 0; nt < NT; nt++){
        const bh8 bb = *(const bh8*)&kT[nt*16 + l15][lg*8];
        acc[ii][nt] = __builtin_amdgcn_mfma_f32_16x16x32_bf16(a, bb, acc[ii][nt], 0, 0, 0);
      }
    }
  }
  #pragma unroll
  for (int ii = 0; ii < MTL; ii++){
    const int mt = w + ii*4;
    if (MT % 4 != 0 && mt >= MT) continue;
    #pragma unroll
    for (int r = 0; r < 4; r++){
      const int e = mt*16 + lg*4 + r;
      float xs[NT]; float mx = -1e30f;
      #pragma unroll
      for (int nt = 0; nt < NT; nt++){
        float x = acc[ii][nt][r] * scale;
        if (DREAL != D && (nt*16 + l15) >= DREAL) x = -1e30f;
        xs[nt] = x; mx = fmaxf(mx, x);
      }
      mx = fmaxf(mx, __shfl_xor(mx,1)); mx = fmaxf(mx, __shfl_xor(mx,2));
      mx = fmaxf(mx, __shfl_xor(mx,4)); mx = fmaxf(mx, __shfl_xor(mx,8));
      float smv = 0.f;
      #pragma unroll
      for (int nt = 0; nt < NT; nt++){
        const float p = (xs[nt] > -1e29f) ? __expf(xs[nt]-mx) : 0.f;
        xs[nt] = p; smv += p;
      }
      smv += __shfl_xor(smv,1); smv += __shfl_xor(smv,2);
      smv += __shfl_xor(smv,4); smv += __shfl_xor(smv,8);
      const float inv = 1.f / smv;
      #pragma unroll
      for (int nt = 0; nt < NT; nt++)
        out[(size_t)e*OS + nt*16 + l15] = f2b(xs[nt]*inv);
      if (OS > D) out[(size_t)e*OS + D + l15] = 0;
    }
  }
}

// ---------------- spatial out: merge[:, :512] = q1@c2 + q2@c1 ----------------
__global__ __launch_bounds__(256)
void sp_out_kernel(const u16* __restrict__ s1, const u16* __restrict__ s2,
                   const u16* __restrict__ csT, u16* __restrict__ merge)
{
  const int h = blockIdx.x, b = blockIdx.y;
  const int tid = threadIdx.x, w = tid >> 6, lane = tid & 63, l15 = lane & 15, lg = lane >> 4;
  const u16* c1 = csT + (((size_t)b)*8 + h)*4096;
  const u16* c2 = csT + (((size_t)64 + b)*8 + h)*4096;
  for (int mt = w; mt < 19; mt += 4) {
    const int m = mt*16 + l15;
    const bool mv = (m < 300);
    const u16* q1 = s1 + ((size_t)b*300 + m)*512 + h*64;
    const u16* q2 = s2 + ((size_t)b*300 + m)*512 + h*64;
    f4 acc[4] = {};
    #pragma unroll
    for (int kc = 0; kc < 2; kc++){
      bh8 a1 = {}, a2 = {};
      if (mv){ a1 = *(const bh8*)(q1 + kc*32 + lg*8); a2 = *(const bh8*)(q2 + kc*32 + lg*8); }
      #pragma unroll
      for (int nt = 0; nt < 4; nt++){
        const bh8 b2v = *(const bh8*)&c2[(size_t)(nt*16+l15)*64 + kc*32 + lg*8];
        acc[nt] = __builtin_amdgcn_mfma_f32_16x16x32_bf16(a1, b2v, acc[nt], 0, 0, 0);
        const bh8 b1v = *(const bh8*)&c1[(size_t)(nt*16+l15)*64 + kc*32 + lg*8];
        acc[nt] = __builtin_amdgcn_mfma_f32_16x16x32_bf16(a2, b1v, acc[nt], 0, 0, 0);
      }
    }
    #pragma unroll
    for (int nt = 0; nt < 4; nt++)
      #pragma unroll
      for (int r = 0; r < 4; r++){
        const int mm = mt*16 + lg*4 + r;
        if (mm < 300)
          merge[((size_t)b*300 + mm)*1024 + h*64 + nt*16 + l15] = f2b(acc[nt][r]);
      }
  }
}

// ---------------- channel out (transposed): merge[:, 512:] = (q1c@c2c + q2c@c1c)^T ----------------
__global__ __launch_bounds__(256)
void ch_out_kernel(const u16* __restrict__ cT1, const u16* __restrict__ cT2,
                   const u16* __restrict__ ccT, u16* __restrict__ merge)
{
  const int cb = blockIdx.x, h = blockIdx.y, b = blockIdx.z;
  const int tid = threadIdx.x, w = tid >> 6, lane = tid & 63, l15 = lane & 15, lg = lane >> 4;
  const int chbase = cb*128 + w*32;
  f4 acc[5][2] = {};
  #pragma unroll
  for (int oi = 0; oi < 2; oi++){
    const u16* Am = ccT + (((size_t)((oi==0)?1:0)*64 + b)*4 + h)*(size_t)(80*96);
    const u16* qb = (oi==0) ? cT1 : cT2;
    #pragma unroll
    for (int kc = 0; kc < 3; kc++){
      bh8 bf[2];
      #pragma unroll
      for (int nf = 0; nf < 2; nf++){
        const int ch = chbase + nf*16 + l15;
        bf[nf] = *(const bh8*)&qb[((size_t)b*512 + ch)*320 + h*80 + kc*32 + lg*8];
      }
      #pragma unroll
      for (int mt = 0; mt < 5; mt++){
        const bh8 a = *(const bh8*)&Am[(size_t)(mt*16+l15)*96 + kc*32 + lg*8];
        #pragma unroll
        for (int nf = 0; nf < 2; nf++)
          acc[mt][nf] = __builtin_amdgcn_mfma_f32_16x16x32_bf16(a, bf[nf], acc[mt][nf], 0, 0, 0);
      }
    }
  }
  #pragma unroll
  for (int mt = 0; mt < 5; mt++)
    #pragma unroll
    for (int nf = 0; nf < 2; nf++)
      #pragma unroll
      for (int r = 0; r < 4; r++){
        const int e = mt*16 + lg*4 + r;
        if (e < 75)
          merge[((size_t)b*300 + h*75 + e)*1024 + 512 + chbase + nf*16 + l15] = f2b(acc[mt][nf][r]);
      }
}

// ---------------- depthwise 3x3 + bias + leaky(0.01), channels-last, tap-major bf16 weights ----------------
__global__ __launch_bounds__(256)
void dw_kernel(const u16* __restrict__ e1, const u16* __restrict__ dwt,
               const float* __restrict__ bias, u16* __restrict__ d1)
{
  const int idx = blockIdx.x*256 + threadIdx.x;
  const int cg = idx & 63;
  const int sp = (idx >> 6) % 300;
  const int b  = idx / (64*300);
  const int c0 = cg*8;
  const int hh = sp / 15, ww = sp - hh*15;
  float acc[8];
  {
    const float4 b0 = *(const float4*)&bias[c0];
    const float4 b1 = *(const float4*)&bias[c0+4];
    acc[0]=b0.x; acc[1]=b0.y; acc[2]=b0.z; acc[3]=b0.w;
    acc[4]=b1.x; acc[5]=b1.y; acc[6]=b1.z; acc[7]=b1.w;
  }
  #pragma unroll
  for (int dy = -1; dy <= 1; dy++){
    const int h2 = hh + dy; if (h2 < 0 || h2 >= 20) continue;
    #pragma unroll
    for (int dx = -1; dx <= 1; dx++){
      const int w2 = ww + dx; if (w2 < 0 || w2 >= 15) continue;
      const bh8 vv = *(const bh8*)&e1[((size_t)b*300 + h2*15 + w2)*512 + c0];
      const int t = (dy+1)*3 + (dx+1);
      const bh8 wv = *(const bh8*)&dwt[t*512 + c0];
      #pragma unroll
      for (int j = 0; j < 8; j++)
        acc[j] += b2f((u16)vv[j]) * b2f((u16)wv[j]);
    }
  }
  bh8 ov;
  #pragma unroll
  for (int j = 0; j < 8; j++){
    float y = acc[j];
    y = (y >= 0.f) ? y : 0.01f*y;
    ov[j] = (short)f2b(y);
  }
  *(bh8*)&d1[((size_t)b*300 + sp)*512 + c0] = ov;
}

// ---------------- BN: one stats pass (5 sums), analytic finalize, final write ----------------
// st layout (floats): [0]=S_e [512]=Q_e [1024]=S_r [1536]=Q_r [2048]=X(=sum e3*res)
//                     [2560]=a_e [3072]=b_e [3584]=a_o [4096]=b_o
__global__ __launch_bounds__(256)
void stats_k(const float* __restrict__ e3, const float* __restrict__ res, float* __restrict__ st){
  const int tid = threadIdx.x;
  const int c0 = tid*2;
  const size_t r0 = (size_t)blockIdx.x * 128;
  float se0=0,se1=0,qe0=0,qe1=0,sr0=0,sr1=0,qr0=0,qr1=0,x0=0,x1=0;
  for (int rr = 0; rr < 128; rr++){
    const size_t o2 = (r0+rr)*512 + c0;
    const float2 ev = *(const float2*)&e3[o2];
    const float2 rv = *(const float2*)&res[o2];
    se0 += ev.x; se1 += ev.y; qe0 += ev.x*ev.x; qe1 += ev.y*ev.y;
    sr0 += rv.x; sr1 += rv.y; qr0 += rv.x*rv.x; qr1 += rv.y*rv.y;
    x0  += ev.x*rv.x; x1 += ev.y*rv.y;
  }
  atomicAdd(&st[c0], se0);      atomicAdd(&st[c0+1], se1);
  atomicAdd(&st[512+c0], qe0);  atomicAdd(&st[512+c0+1], qe1);
  atomicAdd(&st[1024+c0], sr0); atomicAdd(&st[1024+c0+1], sr1);
  atomicAdd(&st[1536+c0], qr0); atomicAdd(&st[1536+c0+1], qr1);
  atomicAdd(&st[2048+c0], x0);  atomicAdd(&st[2048+c0+1], x1);
}
__global__ void fin_k(float* st, const float* __restrict__ we, const float* __restrict__ be,
                      const float* __restrict__ wo, const float* __restrict__ bo){
  const int c = threadIdx.x;
  const float Nf = 19200.f, iN = 1.f/19200.f;
  const float Se = st[c], Qe = st[512+c], Sr = st[1024+c], Qr = st[1536+c], X = st[2048+c];
  const float me = Se*iN;
  const float ve = Qe*iN - me*me;
  const float ae = we[c]*rsqrtf(ve + 1e-5f);
  const float bev = be[c] - me*ae;
  const float So = Sr + ae*Se + Nf*bev;
  const float Qo = Qr + ae*ae*Qe + Nf*bev*bev + 2.f*ae*X + 2.f*bev*Sr + 2.f*ae*bev*Se;
  const float mo = So*iN;
  const float vo = Qo*iN - mo*mo;
  const float ao = wo[c]*rsqrtf(vo + 1e-5f);
  const float bov = bo[c] - mo*ao;
  st[2560+c] = ae; st[3072+c] = bev; st[3584+c] = ao; st[4096+c] = bov;
}
__global__ __launch_bounds__(256)
void final_kernel(const float* __restrict__ res, const float* __restrict__ e3,
                  const float* __restrict__ st, float* __restrict__ outp)
{
  __shared__ float tile[64][65];
  const int spt = blockIdx.x, cht = blockIdx.y, b = blockIdx.z;
  const int tid = threadIdx.x;
  const int sp0 = spt*64, ch0 = cht*64;
  for (int idx = tid; idx < 4096; idx += 256){
    const int cl = idx & 63, sl = idx >> 6;
    const int sp = sp0 + sl;
    float v = 0.f;
    if (sp < 300){
      const size_t off = ((size_t)b*300 + sp)*512 + ch0 + cl;
      const int c = ch0 + cl;
      const float e = e3[off]*st[2560+c] + st[3072+c];
      v = (res[off] + e)*st[3584+c] + st[4096+c];
    }
    tile[sl][cl] = v;
  }
  __syncthreads();
  for (int idx = tid; idx < 4096; idx += 256){
    const int sl = idx & 63, cl = idx >> 6;
    const int sp = sp0 + sl;
    if (sp < 300)
      outp[((size_t)b*512 + ch0 + cl)*300 + sp] = tile[sl][cl];
  }
}

// ---------------- host ----------------
extern "C" void kernel_launch(void* const* d_in, const int* in_sizes, int n_in,
                              void* d_out, int out_size, void* d_ws, size_t ws_size,
                              hipStream_t stream)
{
  const float* x1    = (const float*)d_in[0];
  const float* x2    = (const float*)d_in[1];
  const float* cp1_w = (const float*)d_in[2];
  const float* cp1_b = (const float*)d_in[3];
  const float* ln1_w = (const float*)d_in[4];
  const float* ln1_b = (const float*)d_in[5];
  const float* cp2_w = (const float*)d_in[6];
  const float* cp2_b = (const float*)d_in[7];
  const float* ln2_w = (const float*)d_in[8];
  const float* ln2_b = (const float*)d_in[9];
  const float* skv1w = (const float*)d_in[10];
  const float* skv2w = (const float*)d_in[11];
  const float* ckv1w = (const float*)d_in[12];
  const float* ckv2w = (const float*)d_in[13];
  const float* resw  = (const float*)d_in[14];
  const float* ce1w  = (const float*)d_in[15];
  const float* ce1b  = (const float*)d_in[16];
  const float* dww   = (const float*)d_in[17];
  const float* dwb   = (const float*)d_in[18];
  const float* ce3w  = (const float*)d_in[19];
  const float* ce3b  = (const float*)d_in[20];
  const float* bnew  = (const float*)d_in[21];
  const float* bneb  = (const float*)d_in[22];
  const float* bnow  = (const float*)d_in[23];
  const float* bnob  = (const float*)d_in[24];
  float* out = (float*)d_out;
  char* ws = (char*)d_ws;

  const size_t SZ_T    = (size_t)19200*512*2;
  const size_t SZ_APRE = (size_t)19200*1024*2;
  const size_t SZ_CKV  = (size_t)32768*640*2;
  const size_t SZ_CT   = (size_t)64*512*320*2;
  const size_t SZ_F32  = (size_t)19200*512*4;

  size_t off = 0;
  auto AL = [&](size_t sz){ size_t r = off; off += (sz + 255) & ~(size_t)255; return r; };
  const size_t oR0 = AL(2*SZ_T);             // t1,t2 -> merge
  const size_t oR1 = AL(2*SZ_CKV);           // apre1,apre2 -> kv1,kv2 -> ckv1,ckv2
  const size_t oR2 = AL(2*SZ_T);             // s1,s2 -> e1,d1
  const size_t oR3 = AL(2*SZ_CT + 4096);     // cT1,cT2 -> e3(f32)
  const size_t oR4 = AL(SZ_F32);             // res f32
  const size_t oR5 = AL((size_t)2*64*8*64*64*2);  // c_sT
  const size_t oR6 = AL((size_t)2*64*4*80*96*2);  // c_cT
  const size_t oWcp1  = AL((size_t)1024*512*2);
  const size_t oWcp2  = AL((size_t)1024*512*2);
  const size_t oWskv1 = AL((size_t)1024*512*2);
  const size_t oWskv2 = AL((size_t)1024*512*2);
  const size_t oWckv1 = AL((size_t)640*320*2);
  const size_t oWckv2 = AL((size_t)640*320*2);
  const size_t oWresce = AL((size_t)1024*1024*2);  // [res(512) | ce1(512)] x K=1024
  const size_t oWce3  = AL((size_t)512*512*2);
  const size_t oWdw   = AL((size_t)9*512*2);
  const size_t oST    = AL(20480);
  (void)ws_size; (void)in_sizes; (void)n_in; (void)out_size;

  u16* t1    = (u16*)(ws + oR0);
  u16* merge = (u16*)(ws + oR0);
  u16* apre1 = (u16*)(ws + oR1);
  u16* ckv1  = (u16*)(ws + oR1);
  u16* s1    = (u16*)(ws + oR2);
  u16* s2    = (u16*)(ws + oR2 + SZ_T);
  u16* e1    = s1;
  u16* d1    = s2;
  u16* cT1   = (u16*)(ws + oR3);
  u16* cT2   = (u16*)(ws + oR3 + SZ_CT);
  u16* slack = (u16*)(ws + oR3 + 2*SZ_CT);
  float* e3  = (float*)(ws + oR3);
  float* resb = (float*)(ws + oR4);
  u16* csT   = (u16*)(ws + oR5);
  u16* ccT   = (u16*)(ws + oR6);
  u16* wcp1  = (u16*)(ws + oWcp1);
  u16* wcp2  = (u16*)(ws + oWcp2);
  u16* wskv1 = (u16*)(ws + oWskv1);
  u16* wskv2 = (u16*)(ws + oWskv2);
  u16* wckv1 = (u16*)(ws + oWckv1);
  u16* wckv2 = (u16*)(ws + oWckv2);
  u16* wresce = (u16*)(ws + oWresce);
  u16* wce3  = (u16*)(ws + oWce3);
  u16* wdw   = (u16*)(ws + oWdw);
  float* st  = (float*)(ws + oST);

  u16* t2    = t1 + 19200*512;        // contiguous after t1
  u16* kv1   = apre1;
  u16* ckv2  = ckv1 + (size_t)32768*640;

  hipMemsetAsync(st, 0, 10240, stream);
  pad_zero<<<8,256,0,stream>>>(slack);
  pack_plain<<<2048,256,0,stream>>>(cp1_w, wcp1, 524288);
  pack_plain<<<2048,256,0,stream>>>(cp2_w, wcp2, 524288);
  pack_plain<<<2048,256,0,stream>>>(skv1w, wskv1, 524288);
  pack_plain<<<2048,256,0,stream>>>(skv2w, wskv2, 524288);
  pack_ckv_k<<<800,256,0,stream>>>(ckv1w, wckv1);
  pack_ckv_k<<<800,256,0,stream>>>(ckv2w, wckv2);
  pack_plain<<<2048,256,0,stream>>>(resw, wresce, 524288);
  pack_plain<<<2048,256,0,stream>>>(ce1w, wresce + 524288, 524288);
  pack_plain<<<1024,256,0,stream>>>(ce3w, wce3, 262144);
  pack_dw<<<18,256,0,stream>>>(dww, wdw);

  transpose_k<<<dim3(10,16,64),256,0,stream>>>(x1, t1);
  transpose_k<<<dim3(10,16,64),256,0,stream>>>(x2, t2);

  // cp1+cp2 batched: A = [t1;t2] (38400,512), weight/bias switch at row 19200
  gemm_k<0,1><<<dim3(8,150),512,0,stream>>>(t1,512, wcp1,wcp2,512, 19200L,
                                            apre1,nullptr,1024, cp1_b,cp2_b, 512);

  ln_kernel<<<dim3(256,2),256,0,stream>>>(apre1, ln1_w, ln1_b, s1, cT1);
  ln_kernel<<<dim3(256,2),256,0,stream>>>(apre1 + (size_t)19200*1024, ln2_w, ln2_b, s2, cT2);

  // skv1+skv2 batched: A = [s1;s2], out = [kv1;kv2] (contiguous)
  gemm_k<0,0><<<dim3(8,150),512,0,stream>>>(s1,512, wskv1,wskv2,512, 19200L,
                                            kv1,nullptr,1024, nullptr,nullptr, 512);

  ctx_kernel<64,64,64><<<dim3(8,64,2),256,0,stream>>>(kv1, kv1 + (size_t)19200*1024, csT, 300, 1024, 512, 0.125f);

  // ckv1+ckv2 batched: A = [cT1;cT2] (65536,320), out = [ckv1;ckv2]
  gemm_k<0,0><<<dim3(5,256),512,0,stream>>>(cT1,320, wckv1,wckv2,320, 32768L,
                                            ckv1,nullptr,640, nullptr,nullptr, 320);

  ctx_kernel<80,75,96><<<dim3(4,64,2),256,0,stream>>>(ckv1, ckv2, ccT, 512, 640, 320, 0.115470054f);

  sp_out_kernel<<<dim3(8,64),256,0,stream>>>(s1, s2, csT, merge);
  ch_out_kernel<<<dim3(4,4,64),256,0,stream>>>(cT1, cT2, ccT, merge);

  // merged res (f32, cols 0..511) + ce1 (bf16+bias, cols 512..1023)
  gemm_k<2,0><<<dim3(8,75),512,0,stream>>>(merge,1024, wresce,nullptr,1024, (long)1<<40,
                                           e1, resb, 512, ce1b,nullptr, 1024);

  dw_kernel<<<4800,256,0,stream>>>(e1, wdw, dwb, d1);

  gemm_k<1,1><<<dim3(4,75),512,0,stream>>>(d1,512, wce3,nullptr,512, (long)1<<40,
                                           nullptr,e3,512, ce3b,nullptr, 512);

  stats_k<<<150,256,0,stream>>>(e3, resb, st);
  fin_k<<<1,512,0,stream>>>(st, bnew, bneb, bnow, bnob);
  final_kernel<<<dim3(5,8,64),256,0,stream>>>(resb, e3, st, out);
}